// Round 2
// baseline (7060.070 us; speedup 1.0000x reference)
//
#include <hip/hip_runtime.h>
#include <hip/hip_bf16.h>
#include <math.h>

// ---------------------------------------------------------------------------
// Problem constants (from reference)
// ---------------------------------------------------------------------------
#define N_NODES  200000
#define N_EDGES  800000
#define N_GRAPHS 2048
#define N_SUB    32768
#define E_SUB    131072
#define F_IN     38
#define H0       256
#define H1       128
#define H2       64
#define BN_EPS   1e-5f

typedef __hip_bfloat16 bf16;

static __host__ __device__ inline int cdiv(int a, int b) { return (a + b - 1) / b; }

__device__ inline float ldf(const float* p, size_t i) { return p[i]; }
__device__ inline float ldf(const bf16* p, size_t i)  { return __bfloat162float(p[i]); }
__device__ inline void  stf(float* p, size_t i, float v) { p[i] = v; }
__device__ inline void  stf(bf16* p, size_t i, float v)  { p[i] = __float2bfloat16(v); }

// ---------------------------------------------------------------------------
// Zero fill (graph-capture-safe replacement for hipMemsetAsync)
// ---------------------------------------------------------------------------
__global__ void k_zero(float* __restrict__ p, int n) {
    int i = blockIdx.x * 256 + threadIdx.x;
    if (i < n) p[i] = 0.f;
}

// ---------------------------------------------------------------------------
// Graph preprocessing: degree, CSR build
// ---------------------------------------------------------------------------
__global__ void k_count(const int* __restrict__ dst, int* __restrict__ cnt, int e) {
    int i = blockIdx.x * 256 + threadIdx.x;
    if (i < e) atomicAdd(&cnt[dst[i]], 1);
}

__global__ void k_dinv(const int* __restrict__ cnt, float* __restrict__ dinv, int n) {
    int i = blockIdx.x * 256 + threadIdx.x;
    if (i < n) dinv[i] = rsqrtf(1.0f + (float)cnt[i]);
}

__global__ void k_scan_sum(const int* __restrict__ cnt, int* __restrict__ bsum, int n) {
    __shared__ int tmp[256];
    int t = threadIdx.x;
    int i = blockIdx.x * 256 + t;
    tmp[t] = (i < n) ? cnt[i] : 0;
    __syncthreads();
    for (int off = 128; off > 0; off >>= 1) {
        if (t < off) tmp[t] += tmp[t + off];
        __syncthreads();
    }
    if (t == 0) bsum[blockIdx.x] = tmp[0];
}

__global__ void k_scan_top(int* __restrict__ bsum, int nb) {
    __shared__ int tmp[1024];
    int t = threadIdx.x;
    int v = (t < nb) ? bsum[t] : 0;
    tmp[t] = v;
    __syncthreads();
    for (int off = 1; off < 1024; off <<= 1) {
        int a = (t >= off) ? tmp[t - off] : 0;
        __syncthreads();
        tmp[t] += a;
        __syncthreads();
    }
    if (t < nb) bsum[t] = tmp[t] - v;  // exclusive
}

__global__ void k_scan_apply(const int* __restrict__ cnt, const int* __restrict__ bsum,
                             int* __restrict__ rowptr, int n) {
    __shared__ int tmp[256];
    int t = threadIdx.x;
    int i = blockIdx.x * 256 + t;
    int v = (i < n) ? cnt[i] : 0;
    tmp[t] = v;
    __syncthreads();
    for (int off = 1; off < 256; off <<= 1) {
        int a = (t >= off) ? tmp[t - off] : 0;
        __syncthreads();
        tmp[t] += a;
        __syncthreads();
    }
    int excl = tmp[t] - v + bsum[blockIdx.x];
    if (i < n) rowptr[i] = excl;
    if (i == n - 1) rowptr[n] = excl + v;
}

__global__ void k_fill(const int* __restrict__ src, const int* __restrict__ dst,
                       const float* __restrict__ dinv, const int* __restrict__ rowptr,
                       int* __restrict__ cursor, int* __restrict__ col,
                       float* __restrict__ coef, int e) {
    int i = blockIdx.x * 256 + threadIdx.x;
    if (i < e) {
        int d = dst[i], s = src[i];
        int p = rowptr[d] + atomicAdd(&cursor[d], 1);
        col[p] = s;
        coef[p] = dinv[s] * dinv[d];
    }
}

// ---------------------------------------------------------------------------
// Aggregate-first gather:  Y[i,:] = sum_j coef_ij * f(h[src_j,:]) + dinv_i^2 * f(h[i,:])
//   f = identity (mode 0), global BN (mode 1: mu[c], sc[c]),
//       per-segment BN (mode 2: mu[seg[s]*M+c], sc[...])
// Block (64,4): 4 nodes/block, lane covers cols l, l+64, l+128, l+192.
// ---------------------------------------------------------------------------
template <typename TI, typename TO>
__global__ __launch_bounds__(256) void k_gather(
    const TI* __restrict__ h, const float* __restrict__ dinv,
    const int* __restrict__ rowptr, const int* __restrict__ col,
    const float* __restrict__ coef,
    TO* __restrict__ o, int n, int M, int mode,
    const float* __restrict__ mu, const float* __restrict__ sc,
    const int* __restrict__ seg)
{
    int node = blockIdx.x * 4 + threadIdx.y;
    if (node >= n) return;
    int l = threadIdx.x;
    int nj = (M + 63) >> 6;

    float gmu[4], gsc[4];
#pragma unroll
    for (int j = 0; j < 4; ++j) {
        int c = l + 64 * j;
        bool val = (j < nj) && (c < M);
        gmu[j] = (val && mode == 1) ? mu[c] : 0.f;
        gsc[j] = (val && mode == 1) ? sc[c] : 1.f;
    }

    float acc[4] = {0.f, 0.f, 0.f, 0.f};
    float di = dinv[node];

    // self loop
    {
        int s = node;
        float cf = di * di;
        int g = (mode == 2) ? seg[s] : 0;
#pragma unroll
        for (int j = 0; j < 4; ++j) {
            int c = l + 64 * j;
            if (j < nj && c < M) {
                float v = ldf(h, (size_t)s * M + c);
                if (mode == 1) v = (v - gmu[j]) * gsc[j];
                else if (mode == 2) v = (v - mu[(size_t)g * M + c]) * sc[(size_t)g * M + c];
                acc[j] += cf * v;
            }
        }
    }
    int pe = rowptr[node + 1];
    for (int p = rowptr[node]; p < pe; ++p) {
        int s = col[p];
        float cf = coef[p];
        int g = (mode == 2) ? seg[s] : 0;
#pragma unroll
        for (int j = 0; j < 4; ++j) {
            int c = l + 64 * j;
            if (j < nj && c < M) {
                float v = ldf(h, (size_t)s * M + c);
                if (mode == 1) v = (v - gmu[j]) * gsc[j];
                else if (mode == 2) v = (v - mu[(size_t)g * M + c]) * sc[(size_t)g * M + c];
                acc[j] += cf * v;
            }
        }
    }
#pragma unroll
    for (int j = 0; j < 4; ++j) {
        int c = l + 64 * j;
        if (j < nj && c < M) stf(o, (size_t)node * M + c, acc[j]);
    }
}

// ---------------------------------------------------------------------------
// Generic GEMM:  C(n,M) = act( affine(A)(n,K) @ W(K,M) + bias )
//   affine (optional, global): a' = (a - mu[k]) * sc[k]
//   act: 0 none, 1 relu, 2 sigmoid
// Block (64,4): 32 rows/block (8 per row-group), W staged in LDS in K-chunks.
// ---------------------------------------------------------------------------
template <typename TA, typename TC>
__global__ __launch_bounds__(256) void k_gemm(
    const TA* __restrict__ A, const float* __restrict__ W,
    TC* __restrict__ C, int n, int K, int M,
    const float* __restrict__ bias, int act,
    const float* __restrict__ mu, const float* __restrict__ sc)
{
    __shared__ float wlds[32 * 256];
    const int l = threadIdx.x;
    const int wy = threadIdx.y;
    const int tid = wy * 64 + l;
    const int row0 = blockIdx.x * 32 + wy * 8;
    const int nj = (M + 63) >> 6;

    float acc[8][4];
#pragma unroll
    for (int r = 0; r < 8; ++r)
#pragma unroll
        for (int j = 0; j < 4; ++j) acc[r][j] = 0.f;

    bool jval[4];
    int  cidx[4];
#pragma unroll
    for (int j = 0; j < 4; ++j) {
        cidx[j] = l + 64 * j;
        jval[j] = (j < nj) && (cidx[j] < M);
    }

    for (int k0 = 0; k0 < K; k0 += 32) {
        int kt = min(32, K - k0);
        __syncthreads();
        for (int idx = tid; idx < kt * M; idx += 256)
            wlds[idx] = W[(size_t)k0 * M + idx];
        __syncthreads();
        for (int kk = 0; kk < kt; ++kk) {
            int k = k0 + kk;
            float wv[4];
#pragma unroll
            for (int j = 0; j < 4; ++j)
                wv[j] = jval[j] ? wlds[kk * M + cidx[j]] : 0.f;
            float gmu = 0.f, gsc = 1.f;
            if (mu) { gmu = mu[k]; gsc = sc[k]; }
#pragma unroll
            for (int r = 0; r < 8; ++r) {
                int row = row0 + r;
                float a = (row < n) ? ldf(A, (size_t)row * K + k) : 0.f;
                if (mu) a = (a - gmu) * gsc;
#pragma unroll
                for (int j = 0; j < 4; ++j) acc[r][j] += a * wv[j];
            }
        }
    }

#pragma unroll
    for (int r = 0; r < 8; ++r) {
        int row = row0 + r;
        if (row >= n) continue;
#pragma unroll
        for (int j = 0; j < 4; ++j) {
            if (!jval[j]) continue;
            float v = acc[r][j];
            if (bias) v += bias[cidx[j]];
            if (act == 1) v = fmaxf(v, 0.f);
            else if (act == 2) v = 1.f / (1.f + expf(-v));
            stf(C, (size_t)row * M + cidx[j], v);
        }
    }
}

// ---------------------------------------------------------------------------
// BatchNorm stats (global, column-wise).  M must divide 256.
// ---------------------------------------------------------------------------
template <typename T>
__global__ void k_bn_stats(const T* __restrict__ x, int n, int M,
                           float* __restrict__ sum, float* __restrict__ sumsq) {
    int t = threadIdx.x;
    int G = 256 / M;
    int c = t % M, g = t / M;
    int r = blockIdx.x * 256 + g;
    int rend = min(n, blockIdx.x * 256 + 256);
    float s = 0.f, q = 0.f;
    for (; r < rend; r += G) {
        float v = ldf(x, (size_t)r * M + c);
        s += v;
        q += v * v;
    }
    atomicAdd(&sum[c], s);
    atomicAdd(&sumsq[c], q);
}

__global__ void k_bn_fin(float* __restrict__ sum, float* __restrict__ sumsq, int n, int M) {
    int c = threadIdx.x;
    if (c < M) {
        float m = sum[c] / (float)n;
        float v = fmaxf(sumsq[c] / (float)n - m * m, 0.f);
        sum[c] = m;
        sumsq[c] = rsqrtf(v + BN_EPS);
    }
}

// ---------------------------------------------------------------------------
// Segment stats (seg sorted => few atomic flushes).  M must divide 256.
// ---------------------------------------------------------------------------
__global__ void k_seg_stats(const float* __restrict__ x, const int* __restrict__ seg,
                            int n, int M, float* __restrict__ ssum, float* __restrict__ ssq) {
    int t = threadIdx.x;
    int G = 256 / M;
    int c = t % M, g = t / M;
    int r = blockIdx.x * 256 + g;
    int rend = min(n, blockIdx.x * 256 + 256);
    float s = 0.f, q = 0.f;
    int cur = -1;
    for (; r < rend; r += G) {
        int sgv = seg[r];
        if (sgv != cur) {
            if (cur >= 0) {
                atomicAdd(&ssum[(size_t)cur * M + c], s);
                atomicAdd(&ssq[(size_t)cur * M + c], q);
            }
            cur = sgv; s = 0.f; q = 0.f;
        }
        float v = x[(size_t)r * M + c];
        s += v;
        q += v * v;
    }
    if (cur >= 0) {
        atomicAdd(&ssum[(size_t)cur * M + c], s);
        atomicAdd(&ssq[(size_t)cur * M + c], q);
    }
}

__global__ void k_seg_cnt(const int* __restrict__ seg, int n, float* __restrict__ cnt) {
    int i = blockIdx.x * 256 + threadIdx.x;
    if (i < n) atomicAdd(&cnt[seg[i]], 1.0f);
}

__global__ void k_seg_fin(float* __restrict__ ssum, float* __restrict__ ssq,
                          const float* __restrict__ cnt, int nseg, int M) {
    int i = blockIdx.x * 256 + threadIdx.x;
    if (i < nseg * M) {
        int g = i / M;
        float c = fmaxf(cnt[g], 1.f);
        float m = ssum[i] / c;
        float v = fmaxf(ssq[i] / c - m * m, 0.f);
        ssum[i] = m;
        ssq[i] = rsqrtf(v + BN_EPS);
    }
}

__global__ void k_pool_fin(const float* __restrict__ ssum, const float* __restrict__ cnt,
                           int nseg, int M, float* __restrict__ o) {
    int i = blockIdx.x * 256 + threadIdx.x;
    if (i < nseg * M) {
        int g = i / M;
        o[i] = ssum[i] / fmaxf(cnt[g], 1.f);
    }
}

// ---------------------------------------------------------------------------
// Row L2 normalize, M = 64 (one wave per row)
// ---------------------------------------------------------------------------
__global__ void k_l2norm(float* __restrict__ x, int n) {
    int row = blockIdx.x * 4 + threadIdx.y;
    if (row >= n) return;
    int l = threadIdx.x;
    float v = x[(size_t)row * 64 + l];
    float ss = v * v;
    for (int o = 32; o > 0; o >>= 1) ss += __shfl_xor(ss, o, 64);
    x[(size_t)row * 64 + l] = v / fmaxf(sqrtf(ss), 1e-12f);
}

// ---------------------------------------------------------------------------
// Host launch
// ---------------------------------------------------------------------------
extern "C" void kernel_launch(void* const* d_in, const int* in_sizes, int n_in,
                              void* d_out, int out_size, void* d_ws, size_t ws_size,
                              hipStream_t stream) {
    const float* x        = (const float*)d_in[0];
    const int*   ei       = (const int*)  d_in[1];
    const int*   batch    = (const int*)  d_in[2];
    const float* target_x = (const float*)d_in[3];
    const float* pos_x    = (const float*)d_in[4];
    const int*   pos_ei   = (const int*)  d_in[5];
    const int*   pos_b    = (const int*)  d_in[6];
    const float* neg_x    = (const float*)d_in[7];
    const int*   neg_ei   = (const int*)  d_in[8];
    const int*   neg_b    = (const int*)  d_in[9];
    const float* enc_W0 = (const float*)d_in[10]; const float* enc_b0 = (const float*)d_in[11];
    const float* enc_W1 = (const float*)d_in[12]; const float* enc_b1 = (const float*)d_in[13];
    const float* enc_W2 = (const float*)d_in[14]; const float* enc_b2 = (const float*)d_in[15];
    const float* dec_W0 = (const float*)d_in[16];
    const float* dec_W1 = (const float*)d_in[17];
    const float* dec_W2 = (const float*)d_in[18];
    const float* node_W0 = (const float*)d_in[19]; const float* node_b0 = (const float*)d_in[20];
    const float* node_W1 = (const float*)d_in[21]; const float* node_b1 = (const float*)d_in[22];
    const float* node_W2 = (const float*)d_in[23]; const float* node_b2 = (const float*)d_in[24];
    const float* sub_W0 = (const float*)d_in[25]; const float* sub_b0 = (const float*)d_in[26];
    const float* sub_W1 = (const float*)d_in[27]; const float* sub_b1 = (const float*)d_in[28];
    const float* cls_W0 = (const float*)d_in[29]; const float* cls_b0 = (const float*)d_in[30];
    const float* cls_W1 = (const float*)d_in[31]; const float* cls_b1 = (const float*)d_in[32];
    const float* cls_W2 = (const float*)d_in[33]; const float* cls_b2 = (const float*)d_in[34];

    float* out = (float*)d_out;
    const size_t OFF_XREC  = 0;
    const size_t OFF_ZPOOL = (size_t)N_NODES * F_IN;
    const size_t OFF_TZ    = OFF_ZPOOL + (size_t)N_GRAPHS * H2;
    const size_t OFF_PPOOL = OFF_TZ    + (size_t)N_GRAPHS * H2;
    const size_t OFF_NPOOL = OFF_PPOOL + (size_t)N_GRAPHS * H2;
    const size_t OFF_PRED  = OFF_NPOOL + (size_t)N_GRAPHS * H2;

    // ----- workspace carve-up (by floats; total ~217 MB) -----
    char* wsp = (char*)d_ws;
    auto alloc = [&](size_t nfloats) -> float* {
        float* p = (float*)wsp;
        wsp += ((nfloats + 63) / 64) * 64 * sizeof(float);
        return p;
    };
    float* R1     = alloc((size_t)N_NODES * 128);   // 102.4 MB region (fp32 N*128 / bf16 N*256)
    float* R2     = alloc((size_t)N_NODES * 128);   // 102.4 MB region
    float* dinv   = alloc(N_NODES);
    int*   cnt    = (int*)alloc(N_NODES);
    int*   rowptr = (int*)alloc(N_NODES + 1);
    int*   cursor = (int*)alloc(N_NODES);
    int*   bsum   = (int*)alloc(1024);
    int*   ccol   = (int*)alloc(N_EDGES);
    float* ccoef  = alloc(N_EDGES);
    float* ssum   = alloc(256);
    float* ssumsq = alloc(256);
    float* segsum   = alloc((size_t)N_GRAPHS * 256);
    float* segsumsq = alloc((size_t)N_GRAPHS * 256);
    float* segcnt   = alloc(N_GRAPHS);
    (void)ws_size; (void)in_sizes; (void)n_in; (void)out_size;

    dim3 b64x4(64, 4);
    auto zero = [&](void* p, size_t nfloats) {
        k_zero<<<cdiv((int)nfloats, 256), 256, 0, stream>>>((float*)p, (int)nfloats);
    };

    auto build_graph = [&](const int* eidx, int n, int e) {
        zero(cnt, n);
        k_count<<<cdiv(e, 256), 256, 0, stream>>>(eidx + e, cnt, e);
        k_dinv<<<cdiv(n, 256), 256, 0, stream>>>(cnt, dinv, n);
        int nb = cdiv(n, 256);
        k_scan_sum<<<nb, 256, 0, stream>>>(cnt, bsum, n);
        k_scan_top<<<1, 1024, 0, stream>>>(bsum, nb);
        k_scan_apply<<<nb, 256, 0, stream>>>(cnt, bsum, rowptr, n);
        zero(cursor, n);
        k_fill<<<cdiv(e, 256), 256, 0, stream>>>(eidx, eidx + e, dinv, rowptr, cursor,
                                                 ccol, ccoef, e);
    };

    auto bn_stats = [&](auto* xx, int n, int M) {
        zero(ssum, 256); zero(ssumsq, 256);
        k_bn_stats<<<cdiv(n, 256), 256, 0, stream>>>(xx, n, M, ssum, ssumsq);
        k_bn_fin<<<1, 256, 0, stream>>>(ssum, ssumsq, n, M);
    };

    auto segbn_stats = [&](const float* xx, const int* seg, int n, int M) {
        zero(segsum, (size_t)N_GRAPHS * 256); zero(segsumsq, (size_t)N_GRAPHS * 256);
        k_seg_stats<<<cdiv(n, 256), 256, 0, stream>>>(xx, seg, n, M, segsum, segsumsq);
        k_seg_fin<<<cdiv(N_GRAPHS * M, 256), 256, 0, stream>>>(segsum, segsumsq, segcnt,
                                                               N_GRAPHS, M);
    };

    auto segpool = [&](const float* zz, const int* seg, int n, float* outp) {
        zero(segsum, (size_t)N_GRAPHS * 256); zero(segsumsq, (size_t)N_GRAPHS * 256);
        k_seg_stats<<<cdiv(n, 256), 256, 0, stream>>>(zz, seg, n, H2, segsum, segsumsq);
        k_pool_fin<<<cdiv(N_GRAPHS * H2, 256), 256, 0, stream>>>(segsum, segcnt, N_GRAPHS,
                                                                 H2, outp);
    };

    // ===================== main graph encode (aggregate-first) =====================
    build_graph(ei, N_NODES, N_EDGES);

    // Y0 = A_hat * x  (N x 38, fp32, R2)
    float* Y0 = R2;
    k_gather<float, float><<<cdiv(N_NODES, 4), b64x4, 0, stream>>>(
        x, dinv, rowptr, ccol, ccoef, Y0, N_NODES, F_IN, 0, nullptr, nullptr, nullptr);
    // a0 = relu(Y0 @ W0 + b0)  (N x 256, bf16, R1)
    bf16* a0 = (bf16*)R1;
    k_gemm<float, bf16><<<cdiv(N_NODES, 32), b64x4, 0, stream>>>(
        Y0, enc_W0, a0, N_NODES, F_IN, H0, enc_b0, 1, nullptr, nullptr);
    bn_stats(a0, N_NODES, H0);
    // Y1 = A_hat * bn(a0)  (N x 256, bf16, R2)
    bf16* Y1 = (bf16*)R2;
    k_gather<bf16, bf16><<<cdiv(N_NODES, 4), b64x4, 0, stream>>>(
        a0, dinv, rowptr, ccol, ccoef, Y1, N_NODES, H0, 1, ssum, ssumsq, nullptr);
    // a1 = relu(Y1 @ W1 + b1)  (N x 128, fp32, R1)
    float* a1 = R1;
    k_gemm<bf16, float><<<cdiv(N_NODES, 32), b64x4, 0, stream>>>(
        Y1, enc_W1, a1, N_NODES, H0, H1, enc_b1, 1, nullptr, nullptr);
    bn_stats(a1, N_NODES, H1);
    // Y2 = A_hat * bn(a1)  (N x 128, fp32, R2)
    float* Y2 = R2;
    k_gather<float, float><<<cdiv(N_NODES, 4), b64x4, 0, stream>>>(
        a1, dinv, rowptr, ccol, ccoef, Y2, N_NODES, H1, 1, ssum, ssumsq, nullptr);
    // z = l2norm(Y2 @ W2 + b2)  (N x 64, fp32, R1)
    float* z = R1;
    k_gemm<float, float><<<cdiv(N_NODES, 32), b64x4, 0, stream>>>(
        Y2, enc_W2, z, N_NODES, H1, H2, enc_b2, 0, nullptr, nullptr);
    k_l2norm<<<cdiv(N_NODES, 4), b64x4, 0, stream>>>(z, N_NODES);

    // z_pool
    zero(segcnt, N_GRAPHS);
    k_seg_cnt<<<cdiv(N_NODES, 256), 256, 0, stream>>>(batch, N_NODES, segcnt);
    segpool(z, batch, N_NODES, out + OFF_ZPOOL);

    // ===================== decode =====================
    float* r1 = R2;  // N x 128 fp32
    k_gemm<float, float><<<cdiv(N_NODES, 32), b64x4, 0, stream>>>(
        z, dec_W0, r1, N_NODES, H2, H1, nullptr, 1, nullptr, nullptr);
    bf16* r2 = (bf16*)R1;  // N x 256 bf16 (z dead)
    k_gemm<float, bf16><<<cdiv(N_NODES, 32), b64x4, 0, stream>>>(
        r1, dec_W1, r2, N_NODES, H1, H0, nullptr, 1, nullptr, nullptr);
    k_gemm<bf16, float><<<cdiv(N_NODES, 32), b64x4, 0, stream>>>(
        r2, dec_W2, out + OFF_XREC, N_NODES, H0, F_IN, nullptr, 2, nullptr, nullptr);

    // ===================== target node MLP =====================
    float* t0 = R2;  // 2048 x 256
    k_gemm<float, float><<<cdiv(N_GRAPHS, 32), b64x4, 0, stream>>>(
        target_x, node_W0, t0, N_GRAPHS, F_IN, H0, node_b0, 1, nullptr, nullptr);
    bn_stats(t0, N_GRAPHS, H0);
    float* t1 = R1;  // 2048 x 128
    k_gemm<float, float><<<cdiv(N_GRAPHS, 32), b64x4, 0, stream>>>(
        t0, node_W1, t1, N_GRAPHS, H0, H1, node_b1, 1, ssum, ssumsq);
    bn_stats(t1, N_GRAPHS, H1);
    k_gemm<float, float><<<cdiv(N_GRAPHS, 32), b64x4, 0, stream>>>(
        t1, node_W2, out + OFF_TZ, N_GRAPHS, H1, H2, node_b2, 0, ssum, ssumsq);
    k_l2norm<<<cdiv(N_GRAPHS, 4), b64x4, 0, stream>>>(out + OFF_TZ, N_GRAPHS);

    // ===================== subgraph pipelines (all fp32) =====================
    auto sub_phase = [&](const float* sx, const int* sei, const int* sb, float* outp) {
        build_graph(sei, N_SUB, E_SUB);
        zero(segcnt, N_GRAPHS);
        k_seg_cnt<<<cdiv(N_SUB, 256), 256, 0, stream>>>(sb, N_SUB, segcnt);

        float* Ys = R2;
        k_gather<float, float><<<cdiv(N_SUB, 4), b64x4, 0, stream>>>(
            sx, dinv, rowptr, ccol, ccoef, Ys, N_SUB, F_IN, 0, nullptr, nullptr, nullptr);
        float* as0 = R1;  // 32768 x 256
        k_gemm<float, float><<<cdiv(N_SUB, 32), b64x4, 0, stream>>>(
            Ys, sub_W0, as0, N_SUB, F_IN, H0, sub_b0, 1, nullptr, nullptr);
        segbn_stats(as0, sb, N_SUB, H0);
        float* Ys1 = R2;  // 32768 x 256
        k_gather<float, float><<<cdiv(N_SUB, 4), b64x4, 0, stream>>>(
            as0, dinv, rowptr, ccol, ccoef, Ys1, N_SUB, H0, 2, segsum, segsumsq, sb);
        float* as1 = R1;  // 32768 x 128
        k_gemm<float, float><<<cdiv(N_SUB, 32), b64x4, 0, stream>>>(
            Ys1, sub_W1, as1, N_SUB, H0, H1, sub_b1, 1, nullptr, nullptr);
        segbn_stats(as1, sb, N_SUB, H1);
        float* Ys2 = R2;  // 32768 x 128
        k_gather<float, float><<<cdiv(N_SUB, 4), b64x4, 0, stream>>>(
            as1, dinv, rowptr, ccol, ccoef, Ys2, N_SUB, H1, 2, segsum, segsumsq, sb);
        float* zs = R1;  // 32768 x 64
        k_gemm<float, float><<<cdiv(N_SUB, 32), b64x4, 0, stream>>>(
            Ys2, enc_W2, zs, N_SUB, H1, H2, enc_b2, 0, nullptr, nullptr);
        k_l2norm<<<cdiv(N_SUB, 4), b64x4, 0, stream>>>(zs, N_SUB);
        segpool(zs, sb, N_SUB, outp);
    };
    sub_phase(pos_x, pos_ei, pos_b, out + OFF_PPOOL);
    sub_phase(neg_x, neg_ei, neg_b, out + OFF_NPOOL);

    // ===================== classifier on neg_pool =====================
    float* c1 = R2;
    k_gemm<float, float><<<cdiv(N_GRAPHS, 32), b64x4, 0, stream>>>(
        out + OFF_NPOOL, cls_W0, c1, N_GRAPHS, H2, H1, cls_b0, 1, nullptr, nullptr);
    float* c2 = R1;
    k_gemm<float, float><<<cdiv(N_GRAPHS, 32), b64x4, 0, stream>>>(
        c1, cls_W1, c2, N_GRAPHS, H1, 16, cls_b1, 1, nullptr, nullptr);
    k_gemm<float, float><<<cdiv(N_GRAPHS, 32), b64x4, 0, stream>>>(
        c2, cls_W2, out + OFF_PRED, N_GRAPHS, 16, 1, cls_b2, 2, nullptr, nullptr);
}

// Round 3
// 3461.978 us; speedup vs baseline: 2.0393x; 2.0393x over previous
//
#include <hip/hip_runtime.h>
#include <hip/hip_bf16.h>
#include <math.h>

// ---------------------------------------------------------------------------
// Problem constants (from reference)
// ---------------------------------------------------------------------------
#define N_NODES  200000
#define N_EDGES  800000
#define N_GRAPHS 2048
#define N_SUB    32768
#define E_SUB    131072
#define F_IN     38
#define H0       256
#define H1       128
#define H2       64
#define BN_EPS   1e-5f

typedef __hip_bfloat16 bf16;

static __host__ __device__ inline int cdiv(int a, int b) { return (a + b - 1) / b; }

__device__ inline float ldf(const float* p, size_t i) { return p[i]; }
__device__ inline float ldf(const bf16* p, size_t i)  { return __bfloat162float(p[i]); }
__device__ inline void  stf(float* p, size_t i, float v) { p[i] = v; }
__device__ inline void  stf(bf16* p, size_t i, float v)  { p[i] = __float2bfloat16(v); }

__device__ inline float2 ldf2(const float* p, size_t i) { return ((const float2*)p)[i]; }
__device__ inline float2 ldf2(const bf16* p, size_t i) {
    __hip_bfloat162 v = ((const __hip_bfloat162*)p)[i];
    return make_float2(__bfloat162float(v.x), __bfloat162float(v.y));
}
__device__ inline void stf2(float* p, size_t i, float2 v) { ((float2*)p)[i] = v; }
__device__ inline void stf2(bf16* p, size_t i, float2 v) {
    __hip_bfloat162 t;
    t.x = __float2bfloat16(v.x);
    t.y = __float2bfloat16(v.y);
    ((__hip_bfloat162*)p)[i] = t;
}

// ---------------------------------------------------------------------------
// Zero fill (graph-capture-safe replacement for hipMemsetAsync)
// ---------------------------------------------------------------------------
__global__ void k_zero(float* __restrict__ p, int n) {
    int i = blockIdx.x * 256 + threadIdx.x;
    if (i < n) p[i] = 0.f;
}

// ---------------------------------------------------------------------------
// Graph preprocessing: degree, CSR build
// ---------------------------------------------------------------------------
__global__ void k_count(const int* __restrict__ dst, int* __restrict__ cnt, int e) {
    int i = blockIdx.x * 256 + threadIdx.x;
    if (i < e) atomicAdd(&cnt[dst[i]], 1);
}

__global__ void k_dinv(const int* __restrict__ cnt, float* __restrict__ dinv, int n) {
    int i = blockIdx.x * 256 + threadIdx.x;
    if (i < n) dinv[i] = rsqrtf(1.0f + (float)cnt[i]);
}

__global__ void k_scan_sum(const int* __restrict__ cnt, int* __restrict__ bsum, int n) {
    __shared__ int tmp[256];
    int t = threadIdx.x;
    int i = blockIdx.x * 256 + t;
    tmp[t] = (i < n) ? cnt[i] : 0;
    __syncthreads();
    for (int off = 128; off > 0; off >>= 1) {
        if (t < off) tmp[t] += tmp[t + off];
        __syncthreads();
    }
    if (t == 0) bsum[blockIdx.x] = tmp[0];
}

__global__ void k_scan_top(int* __restrict__ bsum, int nb) {
    __shared__ int tmp[1024];
    int t = threadIdx.x;
    int v = (t < nb) ? bsum[t] : 0;
    tmp[t] = v;
    __syncthreads();
    for (int off = 1; off < 1024; off <<= 1) {
        int a = (t >= off) ? tmp[t - off] : 0;
        __syncthreads();
        tmp[t] += a;
        __syncthreads();
    }
    if (t < nb) bsum[t] = tmp[t] - v;  // exclusive
}

__global__ void k_scan_apply(const int* __restrict__ cnt, const int* __restrict__ bsum,
                             int* __restrict__ rowptr, int n) {
    __shared__ int tmp[256];
    int t = threadIdx.x;
    int i = blockIdx.x * 256 + t;
    int v = (i < n) ? cnt[i] : 0;
    tmp[t] = v;
    __syncthreads();
    for (int off = 1; off < 256; off <<= 1) {
        int a = (t >= off) ? tmp[t - off] : 0;
        __syncthreads();
        tmp[t] += a;
        __syncthreads();
    }
    int excl = tmp[t] - v + bsum[blockIdx.x];
    if (i < n) rowptr[i] = excl;
    if (i == n - 1) rowptr[n] = excl + v;
}

__global__ void k_fill(const int* __restrict__ src, const int* __restrict__ dst,
                       const float* __restrict__ dinv, const int* __restrict__ rowptr,
                       int* __restrict__ cursor, int* __restrict__ col,
                       float* __restrict__ coef, int e) {
    int i = blockIdx.x * 256 + threadIdx.x;
    if (i < e) {
        int d = dst[i], s = src[i];
        int p = rowptr[d] + atomicAdd(&cursor[d], 1);
        col[p] = s;
        coef[p] = dinv[s] * dinv[d];
    }
}

// ---------------------------------------------------------------------------
// Aggregate-first gather (vec2):
//   Y[i,:] = sum_j coef_ij * f(h[src_j,:]) + dinv_i^2 * f(h[i,:])
//   f = identity (mode 0), global BN (mode 1), per-segment BN (mode 2)
// Lane covers column PAIRS p = l + 64*jp (jp < NP). M must be even.
// ---------------------------------------------------------------------------
template <typename TI, typename TO, int NP>
__global__ __launch_bounds__(256) void k_gather2(
    const TI* __restrict__ h, const float* __restrict__ dinv,
    const int* __restrict__ rowptr, const int* __restrict__ col,
    const float* __restrict__ coef, TO* __restrict__ o,
    int n, int M2, int mode,
    const float* __restrict__ mu, const float* __restrict__ sc,
    const int* __restrict__ seg)
{
    int node = blockIdx.x * 4 + threadIdx.y;
    if (node >= n) return;
    int l = threadIdx.x;

    int pidx[NP]; bool pval[NP];
    float2 gmu[NP], gsc[NP];
#pragma unroll
    for (int j = 0; j < NP; ++j) {
        pidx[j] = l + 64 * j;
        pval[j] = pidx[j] < M2;
        gmu[j] = make_float2(0.f, 0.f);
        gsc[j] = make_float2(1.f, 1.f);
        if (mode == 1 && pval[j]) {
            gmu[j] = make_float2(mu[2 * pidx[j]], mu[2 * pidx[j] + 1]);
            gsc[j] = make_float2(sc[2 * pidx[j]], sc[2 * pidx[j] + 1]);
        }
    }

    float2 acc[NP];
#pragma unroll
    for (int j = 0; j < NP; ++j) acc[j] = make_float2(0.f, 0.f);

    float di = dinv[node];
    int pb = rowptr[node], pe = rowptr[node + 1];
    for (int p = pb - 1; p < pe; ++p) {
        int s; float cf;
        if (p < pb) { s = node; cf = di * di; }       // self loop
        else        { s = col[p]; cf = coef[p]; }
        int g = (mode == 2) ? seg[s] : 0;
#pragma unroll
        for (int j = 0; j < NP; ++j) {
            if (!pval[j]) continue;
            float2 v = ldf2(h, (size_t)s * M2 + pidx[j]);
            if (mode == 1) {
                v.x = (v.x - gmu[j].x) * gsc[j].x;
                v.y = (v.y - gmu[j].y) * gsc[j].y;
            } else if (mode == 2) {
                size_t c0 = (size_t)g * 2 * M2 + 2 * pidx[j];
                v.x = (v.x - mu[c0]) * sc[c0];
                v.y = (v.y - mu[c0 + 1]) * sc[c0 + 1];
            }
            acc[j].x += cf * v.x;
            acc[j].y += cf * v.y;
        }
    }
#pragma unroll
    for (int j = 0; j < NP; ++j)
        if (pval[j]) stf2(o, (size_t)node * M2 + pidx[j], acc[j]);
}

// ---------------------------------------------------------------------------
// LDS-tiled GEMM:  C(n,M) = act( affine(A)(n,K) @ W(K,M) + bias )
//   affine (optional, global BN): a' = (a - mu[k]) * sc[k], fused at A-staging
//   act: 0 none, 1 relu, 2 sigmoid
// Tile: 64 rows x M cols, BK=32. Block (64,4): wave wy owns rows
// [wy*16, wy*16+16); lane owns cols l + 64*j (j < NJ). A-tile read back as
// broadcast float4 (ds_read_b128, conflict-free); W-tile stride-1 per lane.
// LDS = 8KB (A) + 32KB (W) = 40KB -> 4 blocks/CU.
// ---------------------------------------------------------------------------
template <typename TA, typename TC, int NJ>
__global__ __launch_bounds__(256) void k_gemm(
    const TA* __restrict__ A, const float* __restrict__ W,
    TC* __restrict__ C, int n, int K, int M,
    const float* __restrict__ bias, int act,
    const float* __restrict__ mu, const float* __restrict__ sc)
{
    __shared__ float alds[64 * 32];
    __shared__ float wlds[32 * 256];
    const int l = threadIdx.x;
    const int wy = threadIdx.y;
    const int tid = wy * 64 + l;
    const int row0 = blockIdx.x * 64;

    float acc[16][NJ];
#pragma unroll
    for (int r = 0; r < 16; ++r)
#pragma unroll
        for (int j = 0; j < NJ; ++j) acc[r][j] = 0.f;

    int cidx[NJ]; bool jval[NJ];
#pragma unroll
    for (int j = 0; j < NJ; ++j) {
        cidx[j] = l + 64 * j;
        jval[j] = cidx[j] < M;
    }

    for (int k0 = 0; k0 < K; k0 += 32) {
        int kt = min(32, K - k0);
        __syncthreads();
        // stage A-tile (64 x 32), zero-padded
        for (int i = tid; i < 64 * 32; i += 256) {
            int r = i >> 5, kk = i & 31;
            int row = row0 + r, k = k0 + kk;
            float v = (row < n && k < K) ? ldf(A, (size_t)row * K + k) : 0.f;
            if (mu && k < K) v = (v - mu[k]) * sc[k];
            alds[i] = v;
        }
        // stage W-tile (kt x M); zero-pad remaining rows so padded A*garbage
        // never makes NaN
        for (int i = tid; i < kt * M; i += 256)
            wlds[i] = W[(size_t)k0 * M + i];
        if (kt < 32)
            for (int i = kt * M + tid; i < 32 * M; i += 256) wlds[i] = 0.f;
        __syncthreads();

#pragma unroll 2
        for (int kkg = 0; kkg < 8; ++kkg) {
            float wv[4][NJ];
#pragma unroll
            for (int q = 0; q < 4; ++q)
#pragma unroll
                for (int j = 0; j < NJ; ++j)
                    wv[q][j] = jval[j] ? wlds[(kkg * 4 + q) * M + cidx[j]] : 0.f;
#pragma unroll
            for (int rr = 0; rr < 16; ++rr) {
                const float4* arow = (const float4*)&alds[(wy * 16 + rr) * 32];
                float4 av = arow[kkg];
#pragma unroll
                for (int j = 0; j < NJ; ++j) {
                    acc[rr][j] += av.x * wv[0][j];
                    acc[rr][j] += av.y * wv[1][j];
                    acc[rr][j] += av.z * wv[2][j];
                    acc[rr][j] += av.w * wv[3][j];
                }
            }
        }
    }

#pragma unroll
    for (int rr = 0; rr < 16; ++rr) {
        int row = row0 + wy * 16 + rr;
        if (row >= n) continue;
#pragma unroll
        for (int j = 0; j < NJ; ++j) {
            if (!jval[j]) continue;
            float v = acc[rr][j];
            if (bias) v += bias[cidx[j]];
            if (act == 1) v = fmaxf(v, 0.f);
            else if (act == 2) v = 1.f / (1.f + expf(-v));
            stf(C, (size_t)row * M + cidx[j], v);
        }
    }
}

// ---------------------------------------------------------------------------
// BatchNorm stats (global, column-wise).  M must divide 256.
// ---------------------------------------------------------------------------
template <typename T>
__global__ void k_bn_stats(const T* __restrict__ x, int n, int M,
                           float* __restrict__ sum, float* __restrict__ sumsq) {
    int t = threadIdx.x;
    int G = 256 / M;
    int c = t % M, g = t / M;
    int r = blockIdx.x * 256 + g;
    int rend = min(n, blockIdx.x * 256 + 256);
    float s = 0.f, q = 0.f;
    for (; r < rend; r += G) {
        float v = ldf(x, (size_t)r * M + c);
        s += v;
        q += v * v;
    }
    atomicAdd(&sum[c], s);
    atomicAdd(&sumsq[c], q);
}

__global__ void k_bn_fin(float* __restrict__ sum, float* __restrict__ sumsq, int n, int M) {
    int c = threadIdx.x;
    if (c < M) {
        float m = sum[c] / (float)n;
        float v = fmaxf(sumsq[c] / (float)n - m * m, 0.f);
        sum[c] = m;
        sumsq[c] = rsqrtf(v + BN_EPS);
    }
}

// ---------------------------------------------------------------------------
// Segment stats (seg sorted => few atomic flushes).  M must divide 256.
// ---------------------------------------------------------------------------
__global__ void k_seg_stats(const float* __restrict__ x, const int* __restrict__ seg,
                            int n, int M, float* __restrict__ ssum, float* __restrict__ ssq) {
    int t = threadIdx.x;
    int G = 256 / M;
    int c = t % M, g = t / M;
    int r = blockIdx.x * 256 + g;
    int rend = min(n, blockIdx.x * 256 + 256);
    float s = 0.f, q = 0.f;
    int cur = -1;
    for (; r < rend; r += G) {
        int sgv = seg[r];
        if (sgv != cur) {
            if (cur >= 0) {
                atomicAdd(&ssum[(size_t)cur * M + c], s);
                atomicAdd(&ssq[(size_t)cur * M + c], q);
            }
            cur = sgv; s = 0.f; q = 0.f;
        }
        float v = x[(size_t)r * M + c];
        s += v;
        q += v * v;
    }
    if (cur >= 0) {
        atomicAdd(&ssum[(size_t)cur * M + c], s);
        atomicAdd(&ssq[(size_t)cur * M + c], q);
    }
}

__global__ void k_seg_cnt(const int* __restrict__ seg, int n, float* __restrict__ cnt) {
    int i = blockIdx.x * 256 + threadIdx.x;
    if (i < n) atomicAdd(&cnt[seg[i]], 1.0f);
}

__global__ void k_seg_fin(float* __restrict__ ssum, float* __restrict__ ssq,
                          const float* __restrict__ cnt, int nseg, int M) {
    int i = blockIdx.x * 256 + threadIdx.x;
    if (i < nseg * M) {
        int g = i / M;
        float c = fmaxf(cnt[g], 1.f);
        float m = ssum[i] / c;
        float v = fmaxf(ssq[i] / c - m * m, 0.f);
        ssum[i] = m;
        ssq[i] = rsqrtf(v + BN_EPS);
    }
}

__global__ void k_pool_fin(const float* __restrict__ ssum, const float* __restrict__ cnt,
                           int nseg, int M, float* __restrict__ o) {
    int i = blockIdx.x * 256 + threadIdx.x;
    if (i < nseg * M) {
        int g = i / M;
        o[i] = ssum[i] / fmaxf(cnt[g], 1.f);
    }
}

// ---------------------------------------------------------------------------
// Row L2 normalize, M = 64 (one wave per row)
// ---------------------------------------------------------------------------
__global__ void k_l2norm(float* __restrict__ x, int n) {
    int row = blockIdx.x * 4 + threadIdx.y;
    if (row >= n) return;
    int l = threadIdx.x;
    float v = x[(size_t)row * 64 + l];
    float ss = v * v;
    for (int o = 32; o > 0; o >>= 1) ss += __shfl_xor(ss, o, 64);
    x[(size_t)row * 64 + l] = v / fmaxf(sqrtf(ss), 1e-12f);
}

// ---------------------------------------------------------------------------
// Host-side launch helpers
// ---------------------------------------------------------------------------
template <typename TA, typename TC>
static void launch_gemm(const TA* A, const float* W, TC* C, int n, int K, int M,
                        const float* bias, int act, const float* mu, const float* sc,
                        hipStream_t stream) {
    dim3 b(64, 4);
    int g = cdiv(n, 64);
    int nj = (M + 63) >> 6;
    if (nj >= 4)      k_gemm<TA, TC, 4><<<g, b, 0, stream>>>(A, W, C, n, K, M, bias, act, mu, sc);
    else if (nj == 2) k_gemm<TA, TC, 2><<<g, b, 0, stream>>>(A, W, C, n, K, M, bias, act, mu, sc);
    else              k_gemm<TA, TC, 1><<<g, b, 0, stream>>>(A, W, C, n, K, M, bias, act, mu, sc);
}

template <typename TI, typename TO>
static void launch_gather(const TI* h, const float* dinv, const int* rowptr,
                          const int* col, const float* coef, TO* o, int n, int M,
                          int mode, const float* mu, const float* sc, const int* seg,
                          hipStream_t stream) {
    dim3 b(64, 4);
    int g = cdiv(n, 4);
    int M2 = M >> 1;  // M even for all call sites (38, 256, 128)
    int np = cdiv(M2, 64);
    if (np >= 2) k_gather2<TI, TO, 2><<<g, b, 0, stream>>>(h, dinv, rowptr, col, coef, o,
                                                           n, M2, mode, mu, sc, seg);
    else         k_gather2<TI, TO, 1><<<g, b, 0, stream>>>(h, dinv, rowptr, col, coef, o,
                                                           n, M2, mode, mu, sc, seg);
}

// ---------------------------------------------------------------------------
// Host launch
// ---------------------------------------------------------------------------
extern "C" void kernel_launch(void* const* d_in, const int* in_sizes, int n_in,
                              void* d_out, int out_size, void* d_ws, size_t ws_size,
                              hipStream_t stream) {
    const float* x        = (const float*)d_in[0];
    const int*   ei       = (const int*)  d_in[1];
    const int*   batch    = (const int*)  d_in[2];
    const float* target_x = (const float*)d_in[3];
    const float* pos_x    = (const float*)d_in[4];
    const int*   pos_ei   = (const int*)  d_in[5];
    const int*   pos_b    = (const int*)  d_in[6];
    const float* neg_x    = (const float*)d_in[7];
    const int*   neg_ei   = (const int*)  d_in[8];
    const int*   neg_b    = (const int*)  d_in[9];
    const float* enc_W0 = (const float*)d_in[10]; const float* enc_b0 = (const float*)d_in[11];
    const float* enc_W1 = (const float*)d_in[12]; const float* enc_b1 = (const float*)d_in[13];
    const float* enc_W2 = (const float*)d_in[14]; const float* enc_b2 = (const float*)d_in[15];
    const float* dec_W0 = (const float*)d_in[16];
    const float* dec_W1 = (const float*)d_in[17];
    const float* dec_W2 = (const float*)d_in[18];
    const float* node_W0 = (const float*)d_in[19]; const float* node_b0 = (const float*)d_in[20];
    const float* node_W1 = (const float*)d_in[21]; const float* node_b1 = (const float*)d_in[22];
    const float* node_W2 = (const float*)d_in[23]; const float* node_b2 = (const float*)d_in[24];
    const float* sub_W0 = (const float*)d_in[25]; const float* sub_b0 = (const float*)d_in[26];
    const float* sub_W1 = (const float*)d_in[27]; const float* sub_b1 = (const float*)d_in[28];
    const float* cls_W0 = (const float*)d_in[29]; const float* cls_b0 = (const float*)d_in[30];
    const float* cls_W1 = (const float*)d_in[31]; const float* cls_b1 = (const float*)d_in[32];
    const float* cls_W2 = (const float*)d_in[33]; const float* cls_b2 = (const float*)d_in[34];

    float* out = (float*)d_out;
    const size_t OFF_XREC  = 0;
    const size_t OFF_ZPOOL = (size_t)N_NODES * F_IN;
    const size_t OFF_TZ    = OFF_ZPOOL + (size_t)N_GRAPHS * H2;
    const size_t OFF_PPOOL = OFF_TZ    + (size_t)N_GRAPHS * H2;
    const size_t OFF_NPOOL = OFF_PPOOL + (size_t)N_GRAPHS * H2;
    const size_t OFF_PRED  = OFF_NPOOL + (size_t)N_GRAPHS * H2;

    // ----- workspace carve-up (by floats; total ~217 MB) -----
    char* wsp = (char*)d_ws;
    auto alloc = [&](size_t nfloats) -> float* {
        float* p = (float*)wsp;
        wsp += ((nfloats + 63) / 64) * 64 * sizeof(float);
        return p;
    };
    float* R1     = alloc((size_t)N_NODES * 128);   // fp32 N*128 / bf16 N*256
    float* R2     = alloc((size_t)N_NODES * 128);
    float* dinv   = alloc(N_NODES);
    int*   cnt    = (int*)alloc(N_NODES);
    int*   rowptr = (int*)alloc(N_NODES + 1);
    int*   cursor = (int*)alloc(N_NODES);
    int*   bsum   = (int*)alloc(1024);
    int*   ccol   = (int*)alloc(N_EDGES);
    float* ccoef  = alloc(N_EDGES);
    float* ssum   = alloc(256);
    float* ssumsq = alloc(256);
    float* segsum   = alloc((size_t)N_GRAPHS * 256);
    float* segsumsq = alloc((size_t)N_GRAPHS * 256);
    float* segcnt   = alloc(N_GRAPHS);
    (void)ws_size; (void)in_sizes; (void)n_in; (void)out_size;

    dim3 b64x4(64, 4);
    auto zero = [&](void* p, size_t nfloats) {
        k_zero<<<cdiv((int)nfloats, 256), 256, 0, stream>>>((float*)p, (int)nfloats);
    };

    auto build_graph = [&](const int* eidx, int n, int e) {
        zero(cnt, n);
        k_count<<<cdiv(e, 256), 256, 0, stream>>>(eidx + e, cnt, e);
        k_dinv<<<cdiv(n, 256), 256, 0, stream>>>(cnt, dinv, n);
        int nb = cdiv(n, 256);
        k_scan_sum<<<nb, 256, 0, stream>>>(cnt, bsum, n);
        k_scan_top<<<1, 1024, 0, stream>>>(bsum, nb);
        k_scan_apply<<<nb, 256, 0, stream>>>(cnt, bsum, rowptr, n);
        zero(cursor, n);
        k_fill<<<cdiv(e, 256), 256, 0, stream>>>(eidx, eidx + e, dinv, rowptr, cursor,
                                                 ccol, ccoef, e);
    };

    auto bn_stats = [&](auto* xx, int n, int M) {
        zero(ssum, 256); zero(ssumsq, 256);
        k_bn_stats<<<cdiv(n, 256), 256, 0, stream>>>(xx, n, M, ssum, ssumsq);
        k_bn_fin<<<1, 256, 0, stream>>>(ssum, ssumsq, n, M);
    };

    auto segbn_stats = [&](const float* xx, const int* seg, int n, int M) {
        zero(segsum, (size_t)N_GRAPHS * 256); zero(segsumsq, (size_t)N_GRAPHS * 256);
        k_seg_stats<<<cdiv(n, 256), 256, 0, stream>>>(xx, seg, n, M, segsum, segsumsq);
        k_seg_fin<<<cdiv(N_GRAPHS * M, 256), 256, 0, stream>>>(segsum, segsumsq, segcnt,
                                                               N_GRAPHS, M);
    };

    auto segpool = [&](const float* zz, const int* seg, int n, float* outp) {
        zero(segsum, (size_t)N_GRAPHS * 256); zero(segsumsq, (size_t)N_GRAPHS * 256);
        k_seg_stats<<<cdiv(n, 256), 256, 0, stream>>>(zz, seg, n, H2, segsum, segsumsq);
        k_pool_fin<<<cdiv(N_GRAPHS * H2, 256), 256, 0, stream>>>(segsum, segcnt, N_GRAPHS,
                                                                 H2, outp);
    };

    // ===================== main graph encode (aggregate-first) =====================
    build_graph(ei, N_NODES, N_EDGES);

    // Y0 = A_hat * x  (N x 38, fp32, R2)
    float* Y0 = R2;
    launch_gather<float, float>(x, dinv, rowptr, ccol, ccoef, Y0, N_NODES, F_IN, 0,
                                nullptr, nullptr, nullptr, stream);
    // a0 = relu(Y0 @ W0 + b0)  (N x 256, bf16, R1)
    bf16* a0 = (bf16*)R1;
    launch_gemm<float, bf16>(Y0, enc_W0, a0, N_NODES, F_IN, H0, enc_b0, 1,
                             nullptr, nullptr, stream);
    bn_stats(a0, N_NODES, H0);
    // Y1 = A_hat * bn(a0)  (N x 256, bf16, R2)
    bf16* Y1 = (bf16*)R2;
    launch_gather<bf16, bf16>(a0, dinv, rowptr, ccol, ccoef, Y1, N_NODES, H0, 1,
                              ssum, ssumsq, nullptr, stream);
    // a1 = relu(Y1 @ W1 + b1)  (N x 128, fp32, R1)
    float* a1 = R1;
    launch_gemm<bf16, float>(Y1, enc_W1, a1, N_NODES, H0, H1, enc_b1, 1,
                             nullptr, nullptr, stream);
    bn_stats(a1, N_NODES, H1);
    // Y2 = A_hat * bn(a1)  (N x 128, fp32, R2)
    float* Y2 = R2;
    launch_gather<float, float>(a1, dinv, rowptr, ccol, ccoef, Y2, N_NODES, H1, 1,
                                ssum, ssumsq, nullptr, stream);
    // z = l2norm(Y2 @ W2 + b2)  (N x 64, fp32, R1)
    float* z = R1;
    launch_gemm<float, float>(Y2, enc_W2, z, N_NODES, H1, H2, enc_b2, 0,
                              nullptr, nullptr, stream);
    k_l2norm<<<cdiv(N_NODES, 4), b64x4, 0, stream>>>(z, N_NODES);

    // z_pool
    zero(segcnt, N_GRAPHS);
    k_seg_cnt<<<cdiv(N_NODES, 256), 256, 0, stream>>>(batch, N_NODES, segcnt);
    segpool(z, batch, N_NODES, out + OFF_ZPOOL);

    // ===================== decode =====================
    float* r1 = R2;  // N x 128 fp32
    launch_gemm<float, float>(z, dec_W0, r1, N_NODES, H2, H1, nullptr, 1,
                              nullptr, nullptr, stream);
    bf16* r2 = (bf16*)R1;  // N x 256 bf16 (z dead)
    launch_gemm<float, bf16>(r1, dec_W1, r2, N_NODES, H1, H0, nullptr, 1,
                             nullptr, nullptr, stream);
    launch_gemm<bf16, float>(r2, dec_W2, out + OFF_XREC, N_NODES, H0, F_IN, nullptr, 2,
                             nullptr, nullptr, stream);

    // ===================== target node MLP =====================
    float* t0 = R2;  // 2048 x 256
    launch_gemm<float, float>(target_x, node_W0, t0, N_GRAPHS, F_IN, H0, node_b0, 1,
                              nullptr, nullptr, stream);
    bn_stats(t0, N_GRAPHS, H0);
    float* t1 = R1;  // 2048 x 128
    launch_gemm<float, float>(t0, node_W1, t1, N_GRAPHS, H0, H1, node_b1, 1,
                              ssum, ssumsq, stream);
    bn_stats(t1, N_GRAPHS, H1);
    launch_gemm<float, float>(t1, node_W2, out + OFF_TZ, N_GRAPHS, H1, H2, node_b2, 0,
                              ssum, ssumsq, stream);
    k_l2norm<<<cdiv(N_GRAPHS, 4), b64x4, 0, stream>>>(out + OFF_TZ, N_GRAPHS);

    // ===================== subgraph pipelines (all fp32) =====================
    auto sub_phase = [&](const float* sx, const int* sei, const int* sb, float* outp) {
        build_graph(sei, N_SUB, E_SUB);
        zero(segcnt, N_GRAPHS);
        k_seg_cnt<<<cdiv(N_SUB, 256), 256, 0, stream>>>(sb, N_SUB, segcnt);

        float* Ys = R2;
        launch_gather<float, float>(sx, dinv, rowptr, ccol, ccoef, Ys, N_SUB, F_IN, 0,
                                    nullptr, nullptr, nullptr, stream);
        float* as0 = R1;  // 32768 x 256
        launch_gemm<float, float>(Ys, sub_W0, as0, N_SUB, F_IN, H0, sub_b0, 1,
                                  nullptr, nullptr, stream);
        segbn_stats(as0, sb, N_SUB, H0);
        float* Ys1 = R2;  // 32768 x 256
        launch_gather<float, float>(as0, dinv, rowptr, ccol, ccoef, Ys1, N_SUB, H0, 2,
                                    segsum, segsumsq, sb, stream);
        float* as1 = R1;  // 32768 x 128
        launch_gemm<float, float>(Ys1, sub_W1, as1, N_SUB, H0, H1, sub_b1, 1,
                                  nullptr, nullptr, stream);
        segbn_stats(as1, sb, N_SUB, H1);
        float* Ys2 = R2;  // 32768 x 128
        launch_gather<float, float>(as1, dinv, rowptr, ccol, ccoef, Ys2, N_SUB, H1, 2,
                                    segsum, segsumsq, sb, stream);
        float* zs = R1;  // 32768 x 64
        launch_gemm<float, float>(Ys2, enc_W2, zs, N_SUB, H1, H2, enc_b2, 0,
                                  nullptr, nullptr, stream);
        k_l2norm<<<cdiv(N_SUB, 4), b64x4, 0, stream>>>(zs, N_SUB);
        segpool(zs, sb, N_SUB, outp);
    };
    sub_phase(pos_x, pos_ei, pos_b, out + OFF_PPOOL);
    sub_phase(neg_x, neg_ei, neg_b, out + OFF_NPOOL);

    // ===================== classifier on neg_pool =====================
    float* c1 = R2;
    launch_gemm<float, float>(out + OFF_NPOOL, cls_W0, c1, N_GRAPHS, H2, H1, cls_b0, 1,
                              nullptr, nullptr, stream);
    float* c2 = R1;
    launch_gemm<float, float>(c1, cls_W1, c2, N_GRAPHS, H1, 16, cls_b1, 1,
                              nullptr, nullptr, stream);
    launch_gemm<float, float>(c2, cls_W2, out + OFF_PRED, N_GRAPHS, 16, 1, cls_b2, 2,
                              nullptr, nullptr, stream);
}

// Round 5
// 2684.161 us; speedup vs baseline: 2.6303x; 1.2898x over previous
//
#include <hip/hip_runtime.h>
#include <hip/hip_bf16.h>
#include <math.h>

// ---------------------------------------------------------------------------
// Problem constants (from reference)
// ---------------------------------------------------------------------------
#define N_NODES  200000
#define N_EDGES  800000
#define N_GRAPHS 2048
#define N_SUB    32768
#define E_SUB    131072
#define F_IN     38
#define H0       256
#define H1       128
#define H2       64
#define BN_EPS   1e-5f

typedef __hip_bfloat16 bf16;
typedef __attribute__((ext_vector_type(8))) short short8;
typedef __attribute__((ext_vector_type(4))) float float4v;

static __host__ __device__ inline int cdiv(int a, int b) { return (a + b - 1) / b; }

__device__ inline float ldf(const float* p, size_t i) { return p[i]; }
__device__ inline float ldf(const bf16* p, size_t i)  { return __bfloat162float(p[i]); }
__device__ inline void  stf(float* p, size_t i, float v) { p[i] = v; }
__device__ inline void  stf(bf16* p, size_t i, float v)  { p[i] = __float2bfloat16(v); }

__device__ inline float2 ldf2(const float* p, size_t i) { return ((const float2*)p)[i]; }
__device__ inline float2 ldf2(const bf16* p, size_t i) {
    __hip_bfloat162 v = ((const __hip_bfloat162*)p)[i];
    return make_float2(__bfloat162float(v.x), __bfloat162float(v.y));
}
__device__ inline void stf2(float* p, size_t i, float2 v) { ((float2*)p)[i] = v; }
__device__ inline void stf2(bf16* p, size_t i, float2 v) {
    __hip_bfloat162 t;
    t.x = __float2bfloat16(v.x);
    t.y = __float2bfloat16(v.y);
    ((__hip_bfloat162*)p)[i] = t;
}

// ---------------------------------------------------------------------------
// Zero fill (graph-capture-safe replacement for hipMemsetAsync)
// ---------------------------------------------------------------------------
__global__ void k_zero(float* __restrict__ p, int n) {
    int i = blockIdx.x * 256 + threadIdx.x;
    if (i < n) p[i] = 0.f;
}

// ---------------------------------------------------------------------------
// Graph preprocessing: degree, CSR build
// ---------------------------------------------------------------------------
__global__ void k_count(const int* __restrict__ dst, int* __restrict__ cnt, int e) {
    int i = blockIdx.x * 256 + threadIdx.x;
    if (i < e) atomicAdd(&cnt[dst[i]], 1);
}

__global__ void k_dinv(const int* __restrict__ cnt, float* __restrict__ dinv, int n) {
    int i = blockIdx.x * 256 + threadIdx.x;
    if (i < n) dinv[i] = rsqrtf(1.0f + (float)cnt[i]);
}

__global__ void k_scan_sum(const int* __restrict__ cnt, int* __restrict__ bsum, int n) {
    __shared__ int tmp[256];
    int t = threadIdx.x;
    int i = blockIdx.x * 256 + t;
    tmp[t] = (i < n) ? cnt[i] : 0;
    __syncthreads();
    for (int off = 128; off > 0; off >>= 1) {
        if (t < off) tmp[t] += tmp[t + off];
        __syncthreads();
    }
    if (t == 0) bsum[blockIdx.x] = tmp[0];
}

__global__ void k_scan_top(int* __restrict__ bsum, int nb) {
    __shared__ int tmp[1024];
    int t = threadIdx.x;
    int v = (t < nb) ? bsum[t] : 0;
    tmp[t] = v;
    __syncthreads();
    for (int off = 1; off < 1024; off <<= 1) {
        int a = (t >= off) ? tmp[t - off] : 0;
        __syncthreads();
        tmp[t] += a;
        __syncthreads();
    }
    if (t < nb) bsum[t] = tmp[t] - v;  // exclusive
}

__global__ void k_scan_apply(const int* __restrict__ cnt, const int* __restrict__ bsum,
                             int* __restrict__ rowptr, int n) {
    __shared__ int tmp[256];
    int t = threadIdx.x;
    int i = blockIdx.x * 256 + t;
    int v = (i < n) ? cnt[i] : 0;
    tmp[t] = v;
    __syncthreads();
    for (int off = 1; off < 256; off <<= 1) {
        int a = (t >= off) ? tmp[t - off] : 0;
        __syncthreads();
        tmp[t] += a;
        __syncthreads();
    }
    int excl = tmp[t] - v + bsum[blockIdx.x];
    if (i < n) rowptr[i] = excl;
    if (i == n - 1) rowptr[n] = excl + v;
}

// cursor aliases the (consumed) cnt buffer — re-zeroed before this kernel.
__global__ void k_fill(const int* __restrict__ src, const int* __restrict__ dst,
                       const int* __restrict__ rowptr, int* __restrict__ cursor,
                       int* __restrict__ col, int e) {
    int i = blockIdx.x * 256 + threadIdx.x;
    if (i < e) {
        int d = dst[i];
        int p = rowptr[d] + atomicAdd(&cursor[d], 1);
        col[p] = src[i];
    }
}

// ---------------------------------------------------------------------------
// Aggregate-first gather (vec2):
//   Y[i,:] = sum_j dinv[src_j]*dinv[i] * f(h[src_j,:]) + dinv_i^2 * f(h[i,:])
//   f = identity (mode 0), global BN (mode 1), per-segment BN (mode 2)
// coef computed on the fly from dinv (L2-resident) — no ccoef array.
// Input rows have M2 data pairs; output rows have S2 pairs (pairs in
// [M2,S2) written as ZERO — K-padding for the MFMA consumer, rewritten
// every call because d_ws is re-poisoned).
// ---------------------------------------------------------------------------
template <typename TI, typename TO, int NP>
__global__ __launch_bounds__(256) void k_gather2(
    const TI* __restrict__ h, const float* __restrict__ dinv,
    const int* __restrict__ rowptr, const int* __restrict__ col,
    TO* __restrict__ o, int n, int M2, int S2, int mode,
    const float* __restrict__ mu, const float* __restrict__ sc,
    const int* __restrict__ seg)
{
    int node = blockIdx.x * 4 + threadIdx.y;
    if (node >= n) return;
    int l = threadIdx.x;

    int pidx[NP]; bool pld[NP], pst[NP];
    float2 gmu[NP], gsc[NP];
#pragma unroll
    for (int j = 0; j < NP; ++j) {
        pidx[j] = l + 64 * j;
        pld[j] = pidx[j] < M2;
        pst[j] = pidx[j] < S2;
        gmu[j] = make_float2(0.f, 0.f);
        gsc[j] = make_float2(1.f, 1.f);
        if (mode == 1 && pld[j]) {
            gmu[j] = make_float2(mu[2 * pidx[j]], mu[2 * pidx[j] + 1]);
            gsc[j] = make_float2(sc[2 * pidx[j]], sc[2 * pidx[j] + 1]);
        }
    }

    float2 acc[NP];
#pragma unroll
    for (int j = 0; j < NP; ++j) acc[j] = make_float2(0.f, 0.f);

    float di = dinv[node];
    int pb = rowptr[node], pe = rowptr[node + 1];
    for (int p = pb - 1; p < pe; ++p) {
        int s; float cf;
        if (p < pb) { s = node; cf = di * di; }            // self loop
        else        { s = col[p]; cf = dinv[s] * di; }     // edge
        int g = (mode == 2) ? seg[s] : 0;
#pragma unroll
        for (int j = 0; j < NP; ++j) {
            if (!pld[j]) continue;
            float2 v = ldf2(h, (size_t)s * M2 + pidx[j]);
            if (mode == 1) {
                v.x = (v.x - gmu[j].x) * gsc[j].x;
                v.y = (v.y - gmu[j].y) * gsc[j].y;
            } else if (mode == 2) {
                size_t c0 = (size_t)g * 2 * M2 + 2 * pidx[j];
                v.x = (v.x - mu[c0]) * sc[c0];
                v.y = (v.y - mu[c0 + 1]) * sc[c0 + 1];
            }
            acc[j].x += cf * v.x;
            acc[j].y += cf * v.y;
        }
    }
#pragma unroll
    for (int j = 0; j < NP; ++j)
        if (pst[j]) stf2(o, (size_t)node * S2 + pidx[j], acc[j]);
}

// ---------------------------------------------------------------------------
// W pre-pack into MFMA B-fragment layout (bf16):
//   Wb[((s*Mp) + n)*32 + kk] = W[s*32+kk][n]   (zero-padded k>=K or n>=M)
// ---------------------------------------------------------------------------
__global__ void k_wpack(const float* __restrict__ W, bf16* __restrict__ Wb,
                        int K, int M, int Mp) {
    int S = (K + 31) >> 5;
    int tot = S * Mp * 32;
    for (int i = blockIdx.x * 256 + threadIdx.x; i < tot; i += gridDim.x * 256) {
        int kk = i & 31;
        int rem = i >> 5;
        int ncol = rem % Mp;
        int s = rem / Mp;
        int k = s * 32 + kk;
        float v = (k < K && ncol < M) ? W[(size_t)k * M + ncol] : 0.f;
        Wb[i] = __float2bfloat16(v);
    }
}

// ---------------------------------------------------------------------------
// MFMA GEMM (bf16 in, fp32 accumulate):  C = act( A @ W + bias )
//   A: bf16 row-major n x SA (SA = K padded to mult of 32, pad cols ZERO)
//   Wb: packed per k_wpack (Mp = M padded to mult of 16)
//   C: n x MC (row stride MC), only cols < M written.
// Block (64,4): wave w owns rows [blk*64 + w*16, +16); NT col-tiles of 16.
// No LDS, no barriers. n must be a multiple of 64 (true at all call sites).
// ---------------------------------------------------------------------------
template <typename TC, int NT>
__global__ __launch_bounds__(256) void k_mfma_gemm(
    const bf16* __restrict__ A, const bf16* __restrict__ Wb,
    TC* __restrict__ C, int n, int SA, int Mp, int M, int MC,
    const float* __restrict__ bias, int act)
{
    const int lane = threadIdx.x;
    const int wave = threadIdx.y;
    const int row0 = blockIdx.x * 64 + wave * 16;
    const int qr = lane >> 4;
    const int lc = lane & 15;

    float4v acc[NT];
#pragma unroll
    for (int t = 0; t < NT; ++t) acc[t] = (float4v){0.f, 0.f, 0.f, 0.f};

    const int S = SA >> 5;
    const bf16* arow = A + (size_t)(row0 + lc) * SA + qr * 8;
    const bf16* wrow = Wb + (size_t)lc * 32 + qr * 8;

    for (int s = 0; s < S; ++s) {
        short8 af = *(const short8*)(arow + s * 32);
#pragma unroll
        for (int t = 0; t < NT; ++t) {
            short8 bfr = *(const short8*)(wrow + ((size_t)s * Mp + t * 16) * 32);
            acc[t] = __builtin_amdgcn_mfma_f32_16x16x32_bf16(af, bfr, acc[t], 0, 0, 0);
        }
    }

#pragma unroll
    for (int t = 0; t < NT; ++t) {
        int c = t * 16 + lc;
        if (c >= M) continue;
        float b = bias ? bias[c] : 0.f;
#pragma unroll
        for (int r = 0; r < 4; ++r) {
            int row = row0 + qr * 4 + r;
            float v = acc[t][r] + b;
            if (act == 1) v = fmaxf(v, 0.f);
            else if (act == 2) v = 1.f / (1.f + expf(-v));
            stf(C, (size_t)row * MC + c, v);
        }
    }
}

template <typename TC>
static void launch_mfma(const bf16* A, const bf16* Wb, TC* C, int n, int SA,
                        int Mp, int M, int MC, const float* bias, int act,
                        hipStream_t stream) {
    dim3 b(64, 4);
    int g = n / 64;
    if (Mp == 256)      k_mfma_gemm<TC, 16><<<g, b, 0, stream>>>(A, Wb, C, n, SA, Mp, M, MC, bias, act);
    else if (Mp == 128) k_mfma_gemm<TC, 8><<<g, b, 0, stream>>>(A, Wb, C, n, SA, Mp, M, MC, bias, act);
    else if (Mp == 64)  k_mfma_gemm<TC, 4><<<g, b, 0, stream>>>(A, Wb, C, n, SA, Mp, M, MC, bias, act);
    else                k_mfma_gemm<TC, 3><<<g, b, 0, stream>>>(A, Wb, C, n, SA, Mp, M, MC, bias, act);
}

// ---------------------------------------------------------------------------
// LDS-tiled fp32 vector GEMM (sub-pipeline / t-MLP / classifier)
// ---------------------------------------------------------------------------
template <typename TA, typename TC, int NJ>
__global__ __launch_bounds__(256) void k_gemm(
    const TA* __restrict__ A, const float* __restrict__ W,
    TC* __restrict__ C, int n, int K, int M,
    const float* __restrict__ bias, int act,
    const float* __restrict__ mu, const float* __restrict__ sc)
{
    __shared__ float alds[64 * 32];
    __shared__ float wlds[32 * 256];
    const int l = threadIdx.x;
    const int wy = threadIdx.y;
    const int tid = wy * 64 + l;
    const int row0 = blockIdx.x * 64;

    float acc[16][NJ];
#pragma unroll
    for (int r = 0; r < 16; ++r)
#pragma unroll
        for (int j = 0; j < NJ; ++j) acc[r][j] = 0.f;

    int cidx[NJ]; bool jval[NJ];
#pragma unroll
    for (int j = 0; j < NJ; ++j) {
        cidx[j] = l + 64 * j;
        jval[j] = cidx[j] < M;
    }

    for (int k0 = 0; k0 < K; k0 += 32) {
        int kt = min(32, K - k0);
        __syncthreads();
        for (int i = tid; i < 64 * 32; i += 256) {
            int r = i >> 5, kk = i & 31;
            int row = row0 + r, k = k0 + kk;
            float v = (row < n && k < K) ? ldf(A, (size_t)row * K + k) : 0.f;
            if (mu && k < K) v = (v - mu[k]) * sc[k];
            alds[i] = v;
        }
        for (int i = tid; i < kt * M; i += 256)
            wlds[i] = W[(size_t)k0 * M + i];
        if (kt < 32)
            for (int i = kt * M + tid; i < 32 * M; i += 256) wlds[i] = 0.f;
        __syncthreads();

#pragma unroll 2
        for (int kkg = 0; kkg < 8; ++kkg) {
            float wv[4][NJ];
#pragma unroll
            for (int q = 0; q < 4; ++q)
#pragma unroll
                for (int j = 0; j < NJ; ++j)
                    wv[q][j] = jval[j] ? wlds[(kkg * 4 + q) * M + cidx[j]] : 0.f;
#pragma unroll
            for (int rr = 0; rr < 16; ++rr) {
                const float4* arow = (const float4*)&alds[(wy * 16 + rr) * 32];
                float4 av = arow[kkg];
#pragma unroll
                for (int j = 0; j < NJ; ++j) {
                    acc[rr][j] += av.x * wv[0][j];
                    acc[rr][j] += av.y * wv[1][j];
                    acc[rr][j] += av.z * wv[2][j];
                    acc[rr][j] += av.w * wv[3][j];
                }
            }
        }
    }

#pragma unroll
    for (int rr = 0; rr < 16; ++rr) {
        int row = row0 + wy * 16 + rr;
        if (row >= n) continue;
#pragma unroll
        for (int j = 0; j < NJ; ++j) {
            if (!jval[j]) continue;
            float v = acc[rr][j];
            if (bias) v += bias[cidx[j]];
            if (act == 1) v = fmaxf(v, 0.f);
            else if (act == 2) v = 1.f / (1.f + expf(-v));
            stf(C, (size_t)row * M + cidx[j], v);
        }
    }
}

// ---------------------------------------------------------------------------
// BatchNorm stats (global, column-wise).  M must divide 256.
// ---------------------------------------------------------------------------
template <typename T>
__global__ void k_bn_stats(const T* __restrict__ x, int n, int M,
                           float* __restrict__ sum, float* __restrict__ sumsq) {
    int t = threadIdx.x;
    int G = 256 / M;
    int c = t % M, g = t / M;
    int r = blockIdx.x * 256 + g;
    int rend = min(n, blockIdx.x * 256 + 256);
    float s = 0.f, q = 0.f;
    for (; r < rend; r += G) {
        float v = ldf(x, (size_t)r * M + c);
        s += v;
        q += v * v;
    }
    atomicAdd(&sum[c], s);
    atomicAdd(&sumsq[c], q);
}

__global__ void k_bn_fin(float* __restrict__ sum, float* __restrict__ sumsq, int n, int M) {
    int c = threadIdx.x;
    if (c < M) {
        float m = sum[c] / (float)n;
        float v = fmaxf(sumsq[c] / (float)n - m * m, 0.f);
        sum[c] = m;
        sumsq[c] = rsqrtf(v + BN_EPS);
    }
}

// ---------------------------------------------------------------------------
// Segment stats (seg sorted => few atomic flushes).  M must divide 256.
// ---------------------------------------------------------------------------
__global__ void k_seg_stats(const float* __restrict__ x, const int* __restrict__ seg,
                            int n, int M, float* __restrict__ ssum, float* __restrict__ ssq) {
    int t = threadIdx.x;
    int G = 256 / M;
    int c = t % M, g = t / M;
    int r = blockIdx.x * 256 + g;
    int rend = min(n, blockIdx.x * 256 + 256);
    float s = 0.f, q = 0.f;
    int cur = -1;
    for (; r < rend; r += G) {
        int sgv = seg[r];
        if (sgv != cur) {
            if (cur >= 0) {
                atomicAdd(&ssum[(size_t)cur * M + c], s);
                atomicAdd(&ssq[(size_t)cur * M + c], q);
            }
            cur = sgv; s = 0.f; q = 0.f;
        }
        float v = x[(size_t)r * M + c];
        s += v;
        q += v * v;
    }
    if (cur >= 0) {
        atomicAdd(&ssum[(size_t)cur * M + c], s);
        atomicAdd(&ssq[(size_t)cur * M + c], q);
    }
}

__global__ void k_seg_cnt(const int* __restrict__ seg, int n, float* __restrict__ cnt) {
    int i = blockIdx.x * 256 + threadIdx.x;
    if (i < n) atomicAdd(&cnt[seg[i]], 1.0f);
}

__global__ void k_seg_fin(float* __restrict__ ssum, float* __restrict__ ssq,
                          const float* __restrict__ cnt, int nseg, int M) {
    int i = blockIdx.x * 256 + threadIdx.x;
    if (i < nseg * M) {
        int g = i / M;
        float c = fmaxf(cnt[g], 1.f);
        float m = ssum[i] / c;
        float v = fmaxf(ssq[i] / c - m * m, 0.f);
        ssum[i] = m;
        ssq[i] = rsqrtf(v + BN_EPS);
    }
}

__global__ void k_pool_fin(const float* __restrict__ ssum, const float* __restrict__ cnt,
                           int nseg, int M, float* __restrict__ o) {
    int i = blockIdx.x * 256 + threadIdx.x;
    if (i < nseg * M) {
        int g = i / M;
        o[i] = ssum[i] / fmaxf(cnt[g], 1.f);
    }
}

// ---------------------------------------------------------------------------
// Row L2 normalize, M = 64; writes fp32 in place + optional bf16 copy
// ---------------------------------------------------------------------------
__global__ void k_l2norm2(float* __restrict__ x, bf16* __restrict__ xb, int n) {
    int row = blockIdx.x * 4 + threadIdx.y;
    if (row >= n) return;
    int l = threadIdx.x;
    float v = x[(size_t)row * 64 + l];
    float ss = v * v;
    for (int o = 32; o > 0; o >>= 1) ss += __shfl_xor(ss, o, 64);
    float r = v / fmaxf(sqrtf(ss), 1e-12f);
    x[(size_t)row * 64 + l] = r;
    if (xb) xb[(size_t)row * 64 + l] = __float2bfloat16(r);
}

// ---------------------------------------------------------------------------
// Host-side launch helpers
// ---------------------------------------------------------------------------
template <typename TA, typename TC>
static void launch_gemm(const TA* A, const float* W, TC* C, int n, int K, int M,
                        const float* bias, int act, const float* mu, const float* sc,
                        hipStream_t stream) {
    dim3 b(64, 4);
    int g = cdiv(n, 64);
    int nj = (M + 63) >> 6;
    if (nj >= 4)      k_gemm<TA, TC, 4><<<g, b, 0, stream>>>(A, W, C, n, K, M, bias, act, mu, sc);
    else if (nj == 2) k_gemm<TA, TC, 2><<<g, b, 0, stream>>>(A, W, C, n, K, M, bias, act, mu, sc);
    else              k_gemm<TA, TC, 1><<<g, b, 0, stream>>>(A, W, C, n, K, M, bias, act, mu, sc);
}

template <typename TI, typename TO>
static void launch_gather(const TI* h, const float* dinv, const int* rowptr,
                          const int* col, TO* o, int n, int M,
                          int Sout, int mode, const float* mu, const float* sc,
                          const int* seg, hipStream_t stream) {
    dim3 b(64, 4);
    int g = cdiv(n, 4);
    int M2 = M >> 1;     // all M even
    int S2 = Sout >> 1;
    int np = cdiv(S2, 64);
    if (np >= 2) k_gather2<TI, TO, 2><<<g, b, 0, stream>>>(h, dinv, rowptr, col, o,
                                                           n, M2, S2, mode, mu, sc, seg);
    else         k_gather2<TI, TO, 1><<<g, b, 0, stream>>>(h, dinv, rowptr, col, o,
                                                           n, M2, S2, mode, mu, sc, seg);
}

// ---------------------------------------------------------------------------
// Host launch
// ---------------------------------------------------------------------------
extern "C" void kernel_launch(void* const* d_in, const int* in_sizes, int n_in,
                              void* d_out, int out_size, void* d_ws, size_t ws_size,
                              hipStream_t stream) {
    const float* x        = (const float*)d_in[0];
    const int*   ei       = (const int*)  d_in[1];
    const int*   batch    = (const int*)  d_in[2];
    const float* target_x = (const float*)d_in[3];
    const float* pos_x    = (const float*)d_in[4];
    const int*   pos_ei   = (const int*)  d_in[5];
    const int*   pos_b    = (const int*)  d_in[6];
    const float* neg_x    = (const float*)d_in[7];
    const int*   neg_ei   = (const int*)  d_in[8];
    const int*   neg_b    = (const int*)  d_in[9];
    const float* enc_W0 = (const float*)d_in[10]; const float* enc_b0 = (const float*)d_in[11];
    const float* enc_W1 = (const float*)d_in[12]; const float* enc_b1 = (const float*)d_in[13];
    const float* enc_W2 = (const float*)d_in[14]; const float* enc_b2 = (const float*)d_in[15];
    const float* dec_W0 = (const float*)d_in[16];
    const float* dec_W1 = (const float*)d_in[17];
    const float* dec_W2 = (const float*)d_in[18];
    const float* node_W0 = (const float*)d_in[19]; const float* node_b0 = (const float*)d_in[20];
    const float* node_W1 = (const float*)d_in[21]; const float* node_b1 = (const float*)d_in[22];
    const float* node_W2 = (const float*)d_in[23]; const float* node_b2 = (const float*)d_in[24];
    const float* sub_W0 = (const float*)d_in[25]; const float* sub_b0 = (const float*)d_in[26];
    const float* sub_W1 = (const float*)d_in[27]; const float* sub_b1 = (const float*)d_in[28];
    const float* cls_W0 = (const float*)d_in[29]; const float* cls_b0 = (const float*)d_in[30];
    const float* cls_W1 = (const float*)d_in[31]; const float* cls_b1 = (const float*)d_in[32];
    const float* cls_W2 = (const float*)d_in[33]; const float* cls_b2 = (const float*)d_in[34];

    float* out = (float*)d_out;
    const size_t OFF_XREC  = 0;
    const size_t OFF_ZPOOL = (size_t)N_NODES * F_IN;
    const size_t OFF_TZ    = OFF_ZPOOL + (size_t)N_GRAPHS * H2;
    const size_t OFF_PPOOL = OFF_TZ    + (size_t)N_GRAPHS * H2;
    const size_t OFF_NPOOL = OFF_PPOOL + (size_t)N_GRAPHS * H2;
    const size_t OFF_PRED  = OFF_NPOOL + (size_t)N_GRAPHS * H2;

    // ----- workspace carve-up (by floats; total ~214.9 MB, below the
    // 218.6 MB footprint that passed post-timing checks in R2/R3) -----
    char* wsp = (char*)d_ws;
    auto alloc = [&](size_t nfloats) -> float* {
        float* p = (float*)wsp;
        wsp += ((nfloats + 63) / 64) * 64 * sizeof(float);
        return p;
    };
    float* R1     = alloc((size_t)N_NODES * 128);   // fp32 N*128 / bf16 N*256
    float* R2     = alloc((size_t)N_NODES * 128);
    float* dinv   = alloc(N_NODES);
    int*   cnt    = (int*)alloc(N_NODES);           // degree, then reused as cursor
    int*   rowptr = (int*)alloc(N_NODES + 1);
    int*   bsum   = (int*)alloc(1024);
    int*   ccol   = (int*)alloc(N_EDGES);
    float* ssum   = alloc(256);
    float* ssumsq = alloc(256);
    float* segsum   = alloc((size_t)N_GRAPHS * 256);
    float* segsumsq = alloc((size_t)N_GRAPHS * 256);
    float* segcnt   = alloc(N_GRAPHS);
    bf16*  wpk      = (bf16*)alloc(64 * 1024);  // 131072-bf16 arena, 110592 used
    (void)ws_size; (void)in_sizes; (void)n_in; (void)out_size;

    // packed-weight arena offsets (bf16 elements): S*Mp*32 each
    bf16* eW0b = wpk;            // K38->S2,  Mp256: 16384
    bf16* eW1b = eW0b + 16384;   // K256->S8, Mp128: 32768
    bf16* eW2b = eW1b + 32768;   // K128->S4, Mp64 :  8192
    bf16* dW0b = eW2b + 8192;    // K64->S2,  Mp128:  8192
    bf16* dW1b = dW0b + 8192;    // K128->S4, Mp256: 32768
    bf16* dW2b = dW1b + 32768;   // K256->S8, Mp48 : 12288

    dim3 b64x4(64, 4);
    auto zero = [&](void* p, size_t nfloats) {
        k_zero<<<cdiv((int)nfloats, 256), 256, 0, stream>>>((float*)p, (int)nfloats);
    };

    // pack all weights (small; once per call)
    k_wpack<<<64, 256, 0, stream>>>(enc_W0, eW0b, F_IN, H0, 256);
    k_wpack<<<64, 256, 0, stream>>>(enc_W1, eW1b, H0, H1, 128);
    k_wpack<<<64, 256, 0, stream>>>(enc_W2, eW2b, H1, H2, 64);
    k_wpack<<<64, 256, 0, stream>>>(dec_W0, dW0b, H2, H1, 128);
    k_wpack<<<64, 256, 0, stream>>>(dec_W1, dW1b, H1, H0, 256);
    k_wpack<<<64, 256, 0, stream>>>(dec_W2, dW2b, H0, F_IN, 48);

    auto build_graph = [&](const int* eidx, int n, int e) {
        zero(cnt, n);
        k_count<<<cdiv(e, 256), 256, 0, stream>>>(eidx + e, cnt, e);
        k_dinv<<<cdiv(n, 256), 256, 0, stream>>>(cnt, dinv, n);
        int nb = cdiv(n, 256);
        k_scan_sum<<<nb, 256, 0, stream>>>(cnt, bsum, n);
        k_scan_top<<<1, 1024, 0, stream>>>(bsum, nb);
        k_scan_apply<<<nb, 256, 0, stream>>>(cnt, bsum, rowptr, n);
        zero(cnt, n);  // cnt now serves as the fill cursor
        k_fill<<<cdiv(e, 256), 256, 0, stream>>>(eidx, eidx + e, rowptr, cnt, ccol, e);
    };

    auto bn_stats = [&](auto* xx, int n, int M) {
        zero(ssum, 256); zero(ssumsq, 256);
        k_bn_stats<<<cdiv(n, 256), 256, 0, stream>>>(xx, n, M, ssum, ssumsq);
        k_bn_fin<<<1, 256, 0, stream>>>(ssum, ssumsq, n, M);
    };

    auto segbn_stats = [&](const float* xx, const int* seg, int n, int M) {
        zero(segsum, (size_t)N_GRAPHS * 256); zero(segsumsq, (size_t)N_GRAPHS * 256);
        k_seg_stats<<<cdiv(n, 256), 256, 0, stream>>>(xx, seg, n, M, segsum, segsumsq);
        k_seg_fin<<<cdiv(N_GRAPHS * M, 256), 256, 0, stream>>>(segsum, segsumsq, segcnt,
                                                               N_GRAPHS, M);
    };

    auto segpool = [&](const float* zz, const int* seg, int n, float* outp) {
        zero(segsum, (size_t)N_GRAPHS * 256); zero(segsumsq, (size_t)N_GRAPHS * 256);
        k_seg_stats<<<cdiv(n, 256), 256, 0, stream>>>(zz, seg, n, H2, segsum, segsumsq);
        k_pool_fin<<<cdiv(N_GRAPHS * H2, 256), 256, 0, stream>>>(segsum, segcnt, N_GRAPHS,
                                                                 H2, outp);
    };

    // ===================== main graph encode (aggregate-first, MFMA) =====================
    build_graph(ei, N_NODES, N_EDGES);

    // Y0 = A_hat * x  (bf16 N x 64, K-padded 38->64 with zeros)
    bf16* Y0 = (bf16*)R2;
    launch_gather<float, bf16>(x, dinv, rowptr, ccol, Y0, N_NODES, F_IN, 64, 0,
                               nullptr, nullptr, nullptr, stream);
    // a0 = relu(Y0 @ W0 + b0)  (bf16 N x 256)
    bf16* a0 = (bf16*)R1;
    launch_mfma<bf16>(Y0, eW0b, a0, N_NODES, 64, 256, H0, H0, enc_b0, 1, stream);
    bn_stats(a0, N_NODES, H0);
    // Y1 = A_hat * bn(a0)  (bf16 N x 256)
    bf16* Y1 = (bf16*)R2;
    launch_gather<bf16, bf16>(a0, dinv, rowptr, ccol, Y1, N_NODES, H0, H0, 1,
                              ssum, ssumsq, nullptr, stream);
    // a1 = relu(Y1 @ W1 + b1)  (bf16 N x 128)
    bf16* a1 = (bf16*)R1;
    launch_mfma<bf16>(Y1, eW1b, a1, N_NODES, 256, 128, H1, H1, enc_b1, 1, stream);
    bn_stats(a1, N_NODES, H1);
    // Y2 = A_hat * bn(a1)  (bf16 N x 128)
    bf16* Y2 = (bf16*)R2;
    launch_gather<bf16, bf16>(a1, dinv, rowptr, ccol, Y2, N_NODES, H1, H1, 1,
                              ssum, ssumsq, nullptr, stream);
    // z = l2norm(Y2 @ W2 + b2)  (fp32 N x 64 in R1, bf16 copy after it)
    float* z  = R1;
    bf16*  zb = (bf16*)(R1 + (size_t)N_NODES * 64);
    launch_mfma<float>(Y2, eW2b, z, N_NODES, 128, 64, H2, H2, enc_b2, 0, stream);
    k_l2norm2<<<cdiv(N_NODES, 4), b64x4, 0, stream>>>(z, zb, N_NODES);

    // z_pool
    zero(segcnt, N_GRAPHS);
    k_seg_cnt<<<cdiv(N_NODES, 256), 256, 0, stream>>>(batch, N_NODES, segcnt);
    segpool(z, batch, N_NODES, out + OFF_ZPOOL);

    // ===================== decode (MFMA) =====================
    bf16* r1 = (bf16*)R2;  // N x 128 bf16 (Y2 dead)
    launch_mfma<bf16>(zb, dW0b, r1, N_NODES, 64, 128, H1, H1, nullptr, 1, stream);
    bf16* r2 = (bf16*)R1;  // N x 256 bf16 (z/zb dead)
    launch_mfma<bf16>(r1, dW1b, r2, N_NODES, 128, 256, H0, H0, nullptr, 1, stream);
    launch_mfma<float>(r2, dW2b, out + OFF_XREC, N_NODES, 256, 48, F_IN, F_IN,
                       nullptr, 2, stream);

    // ===================== target node MLP (fp32 vector) =====================
    float* t0 = R2;  // 2048 x 256
    launch_gemm<float, float>(target_x, node_W0, t0, N_GRAPHS, F_IN, H0, node_b0, 1,
                              nullptr, nullptr, stream);
    bn_stats(t0, N_GRAPHS, H0);
    float* t1 = R1;  // 2048 x 128
    launch_gemm<float, float>(t0, node_W1, t1, N_GRAPHS, H0, H1, node_b1, 1,
                              ssum, ssumsq, stream);
    bn_stats(t1, N_GRAPHS, H1);
    launch_gemm<float, float>(t1, node_W2, out + OFF_TZ, N_GRAPHS, H1, H2, node_b2, 0,
                              ssum, ssumsq, stream);
    k_l2norm2<<<cdiv(N_GRAPHS, 4), b64x4, 0, stream>>>(out + OFF_TZ, nullptr, N_GRAPHS);

    // ===================== subgraph pipelines (fp32 vector, precision-tight) ==========
    auto sub_phase = [&](const float* sx, const int* sei, const int* sb, float* outp) {
        build_graph(sei, N_SUB, E_SUB);
        zero(segcnt, N_GRAPHS);
        k_seg_cnt<<<cdiv(N_SUB, 256), 256, 0, stream>>>(sb, N_SUB, segcnt);

        float* Ys = R2;
        launch_gather<float, float>(sx, dinv, rowptr, ccol, Ys, N_SUB, F_IN, F_IN,
                                    0, nullptr, nullptr, nullptr, stream);
        float* as0 = R1;  // 32768 x 256
        launch_gemm<float, float>(Ys, sub_W0, as0, N_SUB, F_IN, H0, sub_b0, 1,
                                  nullptr, nullptr, stream);
        segbn_stats(as0, sb, N_SUB, H0);
        float* Ys1 = R2;  // 32768 x 256
        launch_gather<float, float>(as0, dinv, rowptr, ccol, Ys1, N_SUB, H0, H0, 2,
                                    segsum, segsumsq, sb, stream);
        float* as1 = R1;  // 32768 x 128
        launch_gemm<float, float>(Ys1, sub_W1, as1, N_SUB, H0, H1, sub_b1, 1,
                                  nullptr, nullptr, stream);
        segbn_stats(as1, sb, N_SUB, H1);
        float* Ys2 = R2;  // 32768 x 128
        launch_gather<float, float>(as1, dinv, rowptr, ccol, Ys2, N_SUB, H1, H1, 2,
                                    segsum, segsumsq, sb, stream);
        float* zs = R1;  // 32768 x 64
        launch_gemm<float, float>(Ys2, enc_W2, zs, N_SUB, H1, H2, enc_b2, 0,
                                  nullptr, nullptr, stream);
        k_l2norm2<<<cdiv(N_SUB, 4), b64x4, 0, stream>>>(zs, nullptr, N_SUB);
        segpool(zs, sb, N_SUB, outp);
    };
    sub_phase(pos_x, pos_ei, pos_b, out + OFF_PPOOL);
    sub_phase(neg_x, neg_ei, neg_b, out + OFF_NPOOL);

    // ===================== classifier on neg_pool (fp32 vector) =====================
    float* c1 = R2;
    launch_gemm<float, float>(out + OFF_NPOOL, cls_W0, c1, N_GRAPHS, H2, H1, cls_b0, 1,
                              nullptr, nullptr, stream);
    float* c2 = R1;
    launch_gemm<float, float>(c1, cls_W1, c2, N_GRAPHS, H1, 16, cls_b1, 1,
                              nullptr, nullptr, stream);
    launch_gemm<float, float>(c2, cls_W2, out + OFF_PRED, N_GRAPHS, 16, 1, cls_b2, 2,
                              nullptr, nullptr, stream);
}

// Round 6
// 2611.367 us; speedup vs baseline: 2.7036x; 1.0279x over previous
//
#include <hip/hip_runtime.h>
#include <hip/hip_bf16.h>
#include <math.h>

// ---------------------------------------------------------------------------
// Problem constants (from reference)
// ---------------------------------------------------------------------------
#define N_NODES  200000
#define N_EDGES  800000
#define N_GRAPHS 2048
#define N_SUB    32768
#define E_SUB    131072
#define F_IN     38
#define H0       256
#define H1       128
#define H2       64
#define BN_EPS   1e-5f

typedef __hip_bfloat16 bf16;
typedef __attribute__((ext_vector_type(8))) short short8;
typedef __attribute__((ext_vector_type(4))) float float4v;

static __host__ __device__ inline int cdiv(int a, int b) { return (a + b - 1) / b; }

__device__ inline float ldf(const float* p, size_t i) { return p[i]; }
__device__ inline float ldf(const bf16* p, size_t i)  { return __bfloat162float(p[i]); }
__device__ inline void  stf(float* p, size_t i, float v) { p[i] = v; }
__device__ inline void  stf(bf16* p, size_t i, float v)  { p[i] = __float2bfloat16(v); }

__device__ inline float2 ldf2(const float* p, size_t i) { return ((const float2*)p)[i]; }
__device__ inline float2 ldf2(const bf16* p, size_t i) {
    __hip_bfloat162 v = ((const __hip_bfloat162*)p)[i];
    return make_float2(__bfloat162float(v.x), __bfloat162float(v.y));
}
__device__ inline void stf2(float* p, size_t i, float2 v) { ((float2*)p)[i] = v; }
__device__ inline void stf2(bf16* p, size_t i, float2 v) {
    __hip_bfloat162 t;
    t.x = __float2bfloat16(v.x);
    t.y = __float2bfloat16(v.y);
    ((__hip_bfloat162*)p)[i] = t;
}

// ---------------------------------------------------------------------------
// Zero fill (graph-capture-safe replacement for hipMemsetAsync)
// ---------------------------------------------------------------------------
__global__ void k_zero(float* __restrict__ p, int n) {
    int i = blockIdx.x * 256 + threadIdx.x;
    if (i < n) p[i] = 0.f;
}

// ---------------------------------------------------------------------------
// Graph preprocessing: degree, CSR build
// ---------------------------------------------------------------------------
__global__ void k_count(const int* __restrict__ dst, int* __restrict__ cnt, int e) {
    int i = blockIdx.x * 256 + threadIdx.x;
    if (i < e) atomicAdd(&cnt[dst[i]], 1);
}

__global__ void k_dinv(const int* __restrict__ cnt, float* __restrict__ dinv, int n) {
    int i = blockIdx.x * 256 + threadIdx.x;
    if (i < n) dinv[i] = rsqrtf(1.0f + (float)cnt[i]);
}

__global__ void k_scan_sum(const int* __restrict__ cnt, int* __restrict__ bsum, int n) {
    __shared__ int tmp[256];
    int t = threadIdx.x;
    int i = blockIdx.x * 256 + t;
    tmp[t] = (i < n) ? cnt[i] : 0;
    __syncthreads();
    for (int off = 128; off > 0; off >>= 1) {
        if (t < off) tmp[t] += tmp[t + off];
        __syncthreads();
    }
    if (t == 0) bsum[blockIdx.x] = tmp[0];
}

__global__ void k_scan_top(int* __restrict__ bsum, int nb) {
    __shared__ int tmp[1024];
    int t = threadIdx.x;
    int v = (t < nb) ? bsum[t] : 0;
    tmp[t] = v;
    __syncthreads();
    for (int off = 1; off < 1024; off <<= 1) {
        int a = (t >= off) ? tmp[t - off] : 0;
        __syncthreads();
        tmp[t] += a;
        __syncthreads();
    }
    if (t < nb) bsum[t] = tmp[t] - v;  // exclusive
}

__global__ void k_scan_apply(const int* __restrict__ cnt, const int* __restrict__ bsum,
                             int* __restrict__ rowptr, int n) {
    __shared__ int tmp[256];
    int t = threadIdx.x;
    int i = blockIdx.x * 256 + t;
    int v = (i < n) ? cnt[i] : 0;
    tmp[t] = v;
    __syncthreads();
    for (int off = 1; off < 256; off <<= 1) {
        int a = (t >= off) ? tmp[t - off] : 0;
        __syncthreads();
        tmp[t] += a;
        __syncthreads();
    }
    int excl = tmp[t] - v + bsum[blockIdx.x];
    if (i < n) rowptr[i] = excl;
    if (i == n - 1) rowptr[n] = excl + v;
}

// cursor aliases the (consumed) cnt buffer — re-zeroed before this kernel.
__global__ void k_fill(const int* __restrict__ src, const int* __restrict__ dst,
                       const int* __restrict__ rowptr, int* __restrict__ cursor,
                       int* __restrict__ col, int e) {
    int i = blockIdx.x * 256 + threadIdx.x;
    if (i < e) {
        int d = dst[i];
        int p = rowptr[d] + atomicAdd(&cursor[d], 1);
        col[p] = src[i];
    }
}

// ---------------------------------------------------------------------------
// Aggregate-first gather (vec2, edge-unrolled x4 for memory-level parallelism):
//   Y[i,:] = sum_j dinv[src_j]*dinv[i] * f(h[src_j,:]) + dinv_i^2 * f(h[i,:])
//   f = identity (mode 0), global BN (mode 1), per-segment BN (mode 2)
// Tail edges masked with cf=0, s=node (in-bounds dummy loads).
// Input rows have M2 data pairs; output rows have S2 pairs (pairs in
// [M2,S2) written as ZERO — K-padding for the MFMA consumer).
// ---------------------------------------------------------------------------
template <typename TI, typename TO, int NP>
__global__ __launch_bounds__(256) void k_gather2(
    const TI* __restrict__ h, const float* __restrict__ dinv,
    const int* __restrict__ rowptr, const int* __restrict__ col,
    TO* __restrict__ o, int n, int M2, int S2, int mode,
    const float* __restrict__ mu, const float* __restrict__ sc,
    const int* __restrict__ seg)
{
    int node = blockIdx.x * 4 + threadIdx.y;
    if (node >= n) return;
    int l = threadIdx.x;

    int pidx[NP]; bool pld[NP], pst[NP];
    float2 gmu[NP], gsc[NP];
#pragma unroll
    for (int j = 0; j < NP; ++j) {
        pidx[j] = l + 64 * j;
        pld[j] = pidx[j] < M2;
        pst[j] = pidx[j] < S2;
        gmu[j] = make_float2(0.f, 0.f);
        gsc[j] = make_float2(1.f, 1.f);
        if (mode == 1 && pld[j]) {
            gmu[j] = make_float2(mu[2 * pidx[j]], mu[2 * pidx[j] + 1]);
            gsc[j] = make_float2(sc[2 * pidx[j]], sc[2 * pidx[j] + 1]);
        }
    }

    float2 acc[NP];
#pragma unroll
    for (int j = 0; j < NP; ++j) acc[j] = make_float2(0.f, 0.f);

    float di = dinv[node];

    // self loop
    {
        int s = node;
        float cf = di * di;
        int g = (mode == 2) ? seg[s] : 0;
#pragma unroll
        for (int j = 0; j < NP; ++j) {
            if (!pld[j]) continue;
            float2 v = ldf2(h, (size_t)s * M2 + pidx[j]);
            if (mode == 1) {
                v.x = (v.x - gmu[j].x) * gsc[j].x;
                v.y = (v.y - gmu[j].y) * gsc[j].y;
            } else if (mode == 2) {
                size_t c0 = (size_t)g * 2 * M2 + 2 * pidx[j];
                v.x = (v.x - mu[c0]) * sc[c0];
                v.y = (v.y - mu[c0 + 1]) * sc[c0 + 1];
            }
            acc[j].x += cf * v.x;
            acc[j].y += cf * v.y;
        }
    }

    int pb = rowptr[node], pe = rowptr[node + 1];
    for (int p = pb; p < pe; p += 4) {
        int   su[4]; float cfu[4]; int gu[4];
#pragma unroll
        for (int u = 0; u < 4; ++u) {
            int q = p + u;
            bool ok = q < pe;
            su[u] = ok ? col[q] : node;           // dummy stays in-bounds
            cfu[u] = ok ? dinv[su[u]] * di : 0.f; // masked contribution
            gu[u] = (mode == 2) ? seg[su[u]] : 0;
        }
        float2 vv[4][NP];
#pragma unroll
        for (int u = 0; u < 4; ++u)
#pragma unroll
            for (int j = 0; j < NP; ++j)
                if (pld[j]) vv[u][j] = ldf2(h, (size_t)su[u] * M2 + pidx[j]);
#pragma unroll
        for (int u = 0; u < 4; ++u) {
#pragma unroll
            for (int j = 0; j < NP; ++j) {
                if (!pld[j]) continue;
                float2 v = vv[u][j];
                if (mode == 1) {
                    v.x = (v.x - gmu[j].x) * gsc[j].x;
                    v.y = (v.y - gmu[j].y) * gsc[j].y;
                } else if (mode == 2) {
                    size_t c0 = (size_t)gu[u] * 2 * M2 + 2 * pidx[j];
                    v.x = (v.x - mu[c0]) * sc[c0];
                    v.y = (v.y - mu[c0 + 1]) * sc[c0 + 1];
                }
                acc[j].x += cfu[u] * v.x;
                acc[j].y += cfu[u] * v.y;
            }
        }
    }
#pragma unroll
    for (int j = 0; j < NP; ++j)
        if (pst[j]) stf2(o, (size_t)node * S2 + pidx[j], acc[j]);
}

// ---------------------------------------------------------------------------
// W pre-pack into MFMA B-fragment layout (bf16):
//   Wb[((s*Mp) + n)*32 + kk] = W[s*32+kk][n]   (zero-padded k>=K or n>=M)
// ---------------------------------------------------------------------------
__global__ void k_wpack(const float* __restrict__ W, bf16* __restrict__ Wb,
                        int K, int M, int Mp) {
    int S = (K + 31) >> 5;
    int tot = S * Mp * 32;
    for (int i = blockIdx.x * 256 + threadIdx.x; i < tot; i += gridDim.x * 256) {
        int kk = i & 31;
        int rem = i >> 5;
        int ncol = rem % Mp;
        int s = rem / Mp;
        int k = s * 32 + kk;
        float v = (k < K && ncol < M) ? W[(size_t)k * M + ncol] : 0.f;
        Wb[i] = __float2bfloat16(v);
    }
}

// ---------------------------------------------------------------------------
// MFMA GEMM (bf16 in, fp32 accumulate):  C = act( A @ W + bias )
//   A: bf16 row-major n x SA (SA = K padded to mult of 32, pad cols ZERO)
//   Wb: packed per k_wpack (Mp = M padded to mult of 16)
//   C: n x MC (row stride MC), only cols < M written.
// Block (64,4): wave w owns rows [blk*64 + w*16, +16); NT col-tiles of 16.
// No LDS, no barriers. n must be a multiple of 64 (true at all call sites).
// ---------------------------------------------------------------------------
template <typename TC, int NT>
__global__ __launch_bounds__(256) void k_mfma_gemm(
    const bf16* __restrict__ A, const bf16* __restrict__ Wb,
    TC* __restrict__ C, int n, int SA, int Mp, int M, int MC,
    const float* __restrict__ bias, int act)
{
    const int lane = threadIdx.x;
    const int wave = threadIdx.y;
    const int row0 = blockIdx.x * 64 + wave * 16;
    const int qr = lane >> 4;
    const int lc = lane & 15;

    float4v acc[NT];
#pragma unroll
    for (int t = 0; t < NT; ++t) acc[t] = (float4v){0.f, 0.f, 0.f, 0.f};

    const int S = SA >> 5;
    const bf16* arow = A + (size_t)(row0 + lc) * SA + qr * 8;
    const bf16* wrow = Wb + (size_t)lc * 32 + qr * 8;

    for (int s = 0; s < S; ++s) {
        short8 af = *(const short8*)(arow + s * 32);
#pragma unroll
        for (int t = 0; t < NT; ++t) {
            short8 bfr = *(const short8*)(wrow + ((size_t)s * Mp + t * 16) * 32);
            acc[t] = __builtin_amdgcn_mfma_f32_16x16x32_bf16(af, bfr, acc[t], 0, 0, 0);
        }
    }

#pragma unroll
    for (int t = 0; t < NT; ++t) {
        int c = t * 16 + lc;
        if (c >= M) continue;
        float b = bias ? bias[c] : 0.f;
#pragma unroll
        for (int r = 0; r < 4; ++r) {
            int row = row0 + qr * 4 + r;
            float v = acc[t][r] + b;
            if (act == 1) v = fmaxf(v, 0.f);
            else if (act == 2) v = 1.f / (1.f + expf(-v));
            stf(C, (size_t)row * MC + c, v);
        }
    }
}

template <typename TC>
static void launch_mfma(const bf16* A, const bf16* Wb, TC* C, int n, int SA,
                        int Mp, int M, int MC, const float* bias, int act,
                        hipStream_t stream) {
    dim3 b(64, 4);
    int g = n / 64;
    if (Mp == 256)      k_mfma_gemm<TC, 16><<<g, b, 0, stream>>>(A, Wb, C, n, SA, Mp, M, MC, bias, act);
    else if (Mp == 128) k_mfma_gemm<TC, 8><<<g, b, 0, stream>>>(A, Wb, C, n, SA, Mp, M, MC, bias, act);
    else if (Mp == 64)  k_mfma_gemm<TC, 4><<<g, b, 0, stream>>>(A, Wb, C, n, SA, Mp, M, MC, bias, act);
    else                k_mfma_gemm<TC, 3><<<g, b, 0, stream>>>(A, Wb, C, n, SA, Mp, M, MC, bias, act);
}

// ---------------------------------------------------------------------------
// LDS-tiled fp32 vector GEMM (t-MLP / classifier — tiny n, precision-tight)
// ---------------------------------------------------------------------------
template <typename TA, typename TC, int NJ>
__global__ __launch_bounds__(256) void k_gemm(
    const TA* __restrict__ A, const float* __restrict__ W,
    TC* __restrict__ C, int n, int K, int M,
    const float* __restrict__ bias, int act,
    const float* __restrict__ mu, const float* __restrict__ sc)
{
    __shared__ float alds[64 * 32];
    __shared__ float wlds[32 * 256];
    const int l = threadIdx.x;
    const int wy = threadIdx.y;
    const int tid = wy * 64 + l;
    const int row0 = blockIdx.x * 64;

    float acc[16][NJ];
#pragma unroll
    for (int r = 0; r < 16; ++r)
#pragma unroll
        for (int j = 0; j < NJ; ++j) acc[r][j] = 0.f;

    int cidx[NJ]; bool jval[NJ];
#pragma unroll
    for (int j = 0; j < NJ; ++j) {
        cidx[j] = l + 64 * j;
        jval[j] = cidx[j] < M;
    }

    for (int k0 = 0; k0 < K; k0 += 32) {
        int kt = min(32, K - k0);
        __syncthreads();
        for (int i = tid; i < 64 * 32; i += 256) {
            int r = i >> 5, kk = i & 31;
            int row = row0 + r, k = k0 + kk;
            float v = (row < n && k < K) ? ldf(A, (size_t)row * K + k) : 0.f;
            if (mu && k < K) v = (v - mu[k]) * sc[k];
            alds[i] = v;
        }
        for (int i = tid; i < kt * M; i += 256)
            wlds[i] = W[(size_t)k0 * M + i];
        if (kt < 32)
            for (int i = kt * M + tid; i < 32 * M; i += 256) wlds[i] = 0.f;
        __syncthreads();

#pragma unroll 2
        for (int kkg = 0; kkg < 8; ++kkg) {
            float wv[4][NJ];
#pragma unroll
            for (int q = 0; q < 4; ++q)
#pragma unroll
                for (int j = 0; j < NJ; ++j)
                    wv[q][j] = jval[j] ? wlds[(kkg * 4 + q) * M + cidx[j]] : 0.f;
#pragma unroll
            for (int rr = 0; rr < 16; ++rr) {
                const float4* arow = (const float4*)&alds[(wy * 16 + rr) * 32];
                float4 av = arow[kkg];
#pragma unroll
                for (int j = 0; j < NJ; ++j) {
                    acc[rr][j] += av.x * wv[0][j];
                    acc[rr][j] += av.y * wv[1][j];
                    acc[rr][j] += av.z * wv[2][j];
                    acc[rr][j] += av.w * wv[3][j];
                }
            }
        }
    }

#pragma unroll
    for (int rr = 0; rr < 16; ++rr) {
        int row = row0 + wy * 16 + rr;
        if (row >= n) continue;
#pragma unroll
        for (int j = 0; j < NJ; ++j) {
            if (!jval[j]) continue;
            float v = acc[rr][j];
            if (bias) v += bias[cidx[j]];
            if (act == 1) v = fmaxf(v, 0.f);
            else if (act == 2) v = 1.f / (1.f + expf(-v));
            stf(C, (size_t)row * M + cidx[j], v);
        }
    }
}

// ---------------------------------------------------------------------------
// BatchNorm stats (global, column-wise).  M must divide 256.
// ---------------------------------------------------------------------------
template <typename T>
__global__ void k_bn_stats(const T* __restrict__ x, int n, int M,
                           float* __restrict__ sum, float* __restrict__ sumsq) {
    int t = threadIdx.x;
    int G = 256 / M;
    int c = t % M, g = t / M;
    int r = blockIdx.x * 256 + g;
    int rend = min(n, blockIdx.x * 256 + 256);
    float s = 0.f, q = 0.f;
    for (; r < rend; r += G) {
        float v = ldf(x, (size_t)r * M + c);
        s += v;
        q += v * v;
    }
    atomicAdd(&sum[c], s);
    atomicAdd(&sumsq[c], q);
}

__global__ void k_bn_fin(float* __restrict__ sum, float* __restrict__ sumsq, int n, int M) {
    int c = threadIdx.x;
    if (c < M) {
        float m = sum[c] / (float)n;
        float v = fmaxf(sumsq[c] / (float)n - m * m, 0.f);
        sum[c] = m;
        sumsq[c] = rsqrtf(v + BN_EPS);
    }
}

// ---------------------------------------------------------------------------
// Segment stats (seg sorted => few atomic flushes).  M must divide 256.
// ---------------------------------------------------------------------------
template <typename T>
__global__ void k_seg_stats(const T* __restrict__ x, const int* __restrict__ seg,
                            int n, int M, float* __restrict__ ssum, float* __restrict__ ssq) {
    int t = threadIdx.x;
    int G = 256 / M;
    int c = t % M, g = t / M;
    int r = blockIdx.x * 256 + g;
    int rend = min(n, blockIdx.x * 256 + 256);
    float s = 0.f, q = 0.f;
    int cur = -1;
    for (; r < rend; r += G) {
        int sgv = seg[r];
        if (sgv != cur) {
            if (cur >= 0) {
                atomicAdd(&ssum[(size_t)cur * M + c], s);
                atomicAdd(&ssq[(size_t)cur * M + c], q);
            }
            cur = sgv; s = 0.f; q = 0.f;
        }
        float v = ldf(x, (size_t)r * M + c);
        s += v;
        q += v * v;
    }
    if (cur >= 0) {
        atomicAdd(&ssum[(size_t)cur * M + c], s);
        atomicAdd(&ssq[(size_t)cur * M + c], q);
    }
}

__global__ void k_seg_cnt(const int* __restrict__ seg, int n, float* __restrict__ cnt) {
    int i = blockIdx.x * 256 + threadIdx.x;
    if (i < n) atomicAdd(&cnt[seg[i]], 1.0f);
}

__global__ void k_seg_fin(float* __restrict__ ssum, float* __restrict__ ssq,
                          const float* __restrict__ cnt, int nseg, int M) {
    int i = blockIdx.x * 256 + threadIdx.x;
    if (i < nseg * M) {
        int g = i / M;
        float c = fmaxf(cnt[g], 1.f);
        float m = ssum[i] / c;
        float v = fmaxf(ssq[i] / c - m * m, 0.f);
        ssum[i] = m;
        ssq[i] = rsqrtf(v + BN_EPS);
    }
}

__global__ void k_pool_fin(const float* __restrict__ ssum, const float* __restrict__ cnt,
                           int nseg, int M, float* __restrict__ o) {
    int i = blockIdx.x * 256 + threadIdx.x;
    if (i < nseg * M) {
        int g = i / M;
        o[i] = ssum[i] / fmaxf(cnt[g], 1.f);
    }
}

// ---------------------------------------------------------------------------
// Row L2 normalize, M = 64; writes fp32 in place + optional bf16 copy
// ---------------------------------------------------------------------------
__global__ void k_l2norm2(float* __restrict__ x, bf16* __restrict__ xb, int n) {
    int row = blockIdx.x * 4 + threadIdx.y;
    if (row >= n) return;
    int l = threadIdx.x;
    float v = x[(size_t)row * 64 + l];
    float ss = v * v;
    for (int o = 32; o > 0; o >>= 1) ss += __shfl_xor(ss, o, 64);
    float r = v / fmaxf(sqrtf(ss), 1e-12f);
    x[(size_t)row * 64 + l] = r;
    if (xb) xb[(size_t)row * 64 + l] = __float2bfloat16(r);
}

// ---------------------------------------------------------------------------
// Host-side launch helpers
// ---------------------------------------------------------------------------
template <typename TA, typename TC>
static void launch_gemm(const TA* A, const float* W, TC* C, int n, int K, int M,
                        const float* bias, int act, const float* mu, const float* sc,
                        hipStream_t stream) {
    dim3 b(64, 4);
    int g = cdiv(n, 64);
    int nj = (M + 63) >> 6;
    if (nj >= 4)      k_gemm<TA, TC, 4><<<g, b, 0, stream>>>(A, W, C, n, K, M, bias, act, mu, sc);
    else if (nj == 2) k_gemm<TA, TC, 2><<<g, b, 0, stream>>>(A, W, C, n, K, M, bias, act, mu, sc);
    else              k_gemm<TA, TC, 1><<<g, b, 0, stream>>>(A, W, C, n, K, M, bias, act, mu, sc);
}

template <typename TI, typename TO>
static void launch_gather(const TI* h, const float* dinv, const int* rowptr,
                          const int* col, TO* o, int n, int M,
                          int Sout, int mode, const float* mu, const float* sc,
                          const int* seg, hipStream_t stream) {
    dim3 b(64, 4);
    int g = cdiv(n, 4);
    int M2 = M >> 1;     // all M even
    int S2 = Sout >> 1;
    int np = cdiv(S2, 64);
    if (np >= 2) k_gather2<TI, TO, 2><<<g, b, 0, stream>>>(h, dinv, rowptr, col, o,
                                                           n, M2, S2, mode, mu, sc, seg);
    else         k_gather2<TI, TO, 1><<<g, b, 0, stream>>>(h, dinv, rowptr, col, o,
                                                           n, M2, S2, mode, mu, sc, seg);
}

// ---------------------------------------------------------------------------
// Host launch
// ---------------------------------------------------------------------------
extern "C" void kernel_launch(void* const* d_in, const int* in_sizes, int n_in,
                              void* d_out, int out_size, void* d_ws, size_t ws_size,
                              hipStream_t stream) {
    const float* x        = (const float*)d_in[0];
    const int*   ei       = (const int*)  d_in[1];
    const int*   batch    = (const int*)  d_in[2];
    const float* target_x = (const float*)d_in[3];
    const float* pos_x    = (const float*)d_in[4];
    const int*   pos_ei   = (const int*)  d_in[5];
    const int*   pos_b    = (const int*)  d_in[6];
    const float* neg_x    = (const float*)d_in[7];
    const int*   neg_ei   = (const int*)  d_in[8];
    const int*   neg_b    = (const int*)  d_in[9];
    const float* enc_W0 = (const float*)d_in[10]; const float* enc_b0 = (const float*)d_in[11];
    const float* enc_W1 = (const float*)d_in[12]; const float* enc_b1 = (const float*)d_in[13];
    const float* enc_W2 = (const float*)d_in[14]; const float* enc_b2 = (const float*)d_in[15];
    const float* dec_W0 = (const float*)d_in[16];
    const float* dec_W1 = (const float*)d_in[17];
    const float* dec_W2 = (const float*)d_in[18];
    const float* node_W0 = (const float*)d_in[19]; const float* node_b0 = (const float*)d_in[20];
    const float* node_W1 = (const float*)d_in[21]; const float* node_b1 = (const float*)d_in[22];
    const float* node_W2 = (const float*)d_in[23]; const float* node_b2 = (const float*)d_in[24];
    const float* sub_W0 = (const float*)d_in[25]; const float* sub_b0 = (const float*)d_in[26];
    const float* sub_W1 = (const float*)d_in[27]; const float* sub_b1 = (const float*)d_in[28];
    const float* cls_W0 = (const float*)d_in[29]; const float* cls_b0 = (const float*)d_in[30];
    const float* cls_W1 = (const float*)d_in[31]; const float* cls_b1 = (const float*)d_in[32];
    const float* cls_W2 = (const float*)d_in[33]; const float* cls_b2 = (const float*)d_in[34];

    float* out = (float*)d_out;
    const size_t OFF_XREC  = 0;
    const size_t OFF_ZPOOL = (size_t)N_NODES * F_IN;
    const size_t OFF_TZ    = OFF_ZPOOL + (size_t)N_GRAPHS * H2;
    const size_t OFF_PPOOL = OFF_TZ    + (size_t)N_GRAPHS * H2;
    const size_t OFF_NPOOL = OFF_PPOOL + (size_t)N_GRAPHS * H2;
    const size_t OFF_PRED  = OFF_NPOOL + (size_t)N_GRAPHS * H2;

    // ----- workspace carve-up (by floats; total ~215 MB, below the
    // 218.6 MB footprint that passed post-timing checks in R2/R3) -----
    char* wsp = (char*)d_ws;
    auto alloc = [&](size_t nfloats) -> float* {
        float* p = (float*)wsp;
        wsp += ((nfloats + 63) / 64) * 64 * sizeof(float);
        return p;
    };
    float* R1     = alloc((size_t)N_NODES * 128);   // fp32 N*128 / bf16 N*256
    float* R2     = alloc((size_t)N_NODES * 128);
    float* dinv   = alloc(N_NODES);
    int*   cnt    = (int*)alloc(N_NODES);           // degree, then reused as cursor
    int*   rowptr = (int*)alloc(N_NODES + 1);
    int*   bsum   = (int*)alloc(1024);
    int*   ccol   = (int*)alloc(N_EDGES);
    float* ssum   = alloc(256);
    float* ssumsq = alloc(256);
    float* segsum   = alloc((size_t)N_GRAPHS * 256);
    float* segsumsq = alloc((size_t)N_GRAPHS * 256);
    float* segcnt   = alloc(N_GRAPHS);
    bf16*  wpk      = (bf16*)alloc(80 * 1024);  // 163840-bf16 arena, 159744 used
    (void)ws_size; (void)in_sizes; (void)n_in; (void)out_size;

    // packed-weight arena offsets (bf16 elements): S*Mp*32 each
    bf16* eW0b = wpk;            // K38->S2,  Mp256: 16384
    bf16* eW1b = eW0b + 16384;   // K256->S8, Mp128: 32768
    bf16* eW2b = eW1b + 32768;   // K128->S4, Mp64 :  8192
    bf16* dW0b = eW2b + 8192;    // K64->S2,  Mp128:  8192
    bf16* dW1b = dW0b + 8192;    // K128->S4, Mp256: 32768
    bf16* dW2b = dW1b + 32768;   // K256->S8, Mp48 : 12288
    bf16* sW0b = dW2b + 12288;   // K38->S2,  Mp256: 16384
    bf16* sW1b = sW0b + 16384;   // K256->S8, Mp128: 32768

    dim3 b64x4(64, 4);
    auto zero = [&](void* p, size_t nfloats) {
        k_zero<<<cdiv((int)nfloats, 256), 256, 0, stream>>>((float*)p, (int)nfloats);
    };

    // pack all weights (small; once per call)
    k_wpack<<<64, 256, 0, stream>>>(enc_W0, eW0b, F_IN, H0, 256);
    k_wpack<<<64, 256, 0, stream>>>(enc_W1, eW1b, H0, H1, 128);
    k_wpack<<<64, 256, 0, stream>>>(enc_W2, eW2b, H1, H2, 64);
    k_wpack<<<64, 256, 0, stream>>>(dec_W0, dW0b, H2, H1, 128);
    k_wpack<<<64, 256, 0, stream>>>(dec_W1, dW1b, H1, H0, 256);
    k_wpack<<<64, 256, 0, stream>>>(dec_W2, dW2b, H0, F_IN, 48);
    k_wpack<<<64, 256, 0, stream>>>(sub_W0, sW0b, F_IN, H0, 256);
    k_wpack<<<64, 256, 0, stream>>>(sub_W1, sW1b, H0, H1, 128);

    auto build_graph = [&](const int* eidx, int n, int e) {
        zero(cnt, n);
        k_count<<<cdiv(e, 256), 256, 0, stream>>>(eidx + e, cnt, e);
        k_dinv<<<cdiv(n, 256), 256, 0, stream>>>(cnt, dinv, n);
        int nb = cdiv(n, 256);
        k_scan_sum<<<nb, 256, 0, stream>>>(cnt, bsum, n);
        k_scan_top<<<1, 1024, 0, stream>>>(bsum, nb);
        k_scan_apply<<<nb, 256, 0, stream>>>(cnt, bsum, rowptr, n);
        zero(cnt, n);  // cnt now serves as the fill cursor
        k_fill<<<cdiv(e, 256), 256, 0, stream>>>(eidx, eidx + e, rowptr, cnt, ccol, e);
    };

    auto bn_stats = [&](auto* xx, int n, int M) {
        zero(ssum, 256); zero(ssumsq, 256);
        k_bn_stats<<<cdiv(n, 256), 256, 0, stream>>>(xx, n, M, ssum, ssumsq);
        k_bn_fin<<<1, 256, 0, stream>>>(ssum, ssumsq, n, M);
    };

    auto segbn_stats = [&](auto* xx, const int* seg, int n, int M) {
        zero(segsum, (size_t)N_GRAPHS * 256); zero(segsumsq, (size_t)N_GRAPHS * 256);
        k_seg_stats<<<cdiv(n, 256), 256, 0, stream>>>(xx, seg, n, M, segsum, segsumsq);
        k_seg_fin<<<cdiv(N_GRAPHS * M, 256), 256, 0, stream>>>(segsum, segsumsq, segcnt,
                                                               N_GRAPHS, M);
    };

    auto segpool = [&](const float* zz, const int* seg, int n, float* outp) {
        zero(segsum, (size_t)N_GRAPHS * 256); zero(segsumsq, (size_t)N_GRAPHS * 256);
        k_seg_stats<<<cdiv(n, 256), 256, 0, stream>>>(zz, seg, n, H2, segsum, segsumsq);
        k_pool_fin<<<cdiv(N_GRAPHS * H2, 256), 256, 0, stream>>>(segsum, segcnt, N_GRAPHS,
                                                                 H2, outp);
    };

    // ===================== main graph encode (aggregate-first, MFMA) =====================
    build_graph(ei, N_NODES, N_EDGES);

    // Y0 = A_hat * x  (bf16 N x 64, K-padded 38->64 with zeros)
    bf16* Y0 = (bf16*)R2;
    launch_gather<float, bf16>(x, dinv, rowptr, ccol, Y0, N_NODES, F_IN, 64, 0,
                               nullptr, nullptr, nullptr, stream);
    // a0 = relu(Y0 @ W0 + b0)  (bf16 N x 256)
    bf16* a0 = (bf16*)R1;
    launch_mfma<bf16>(Y0, eW0b, a0, N_NODES, 64, 256, H0, H0, enc_b0, 1, stream);
    bn_stats(a0, N_NODES, H0);
    // Y1 = A_hat * bn(a0)  (bf16 N x 256)
    bf16* Y1 = (bf16*)R2;
    launch_gather<bf16, bf16>(a0, dinv, rowptr, ccol, Y1, N_NODES, H0, H0, 1,
                              ssum, ssumsq, nullptr, stream);
    // a1 = relu(Y1 @ W1 + b1)  (bf16 N x 128)
    bf16* a1 = (bf16*)R1;
    launch_mfma<bf16>(Y1, eW1b, a1, N_NODES, 256, 128, H1, H1, enc_b1, 1, stream);
    bn_stats(a1, N_NODES, H1);
    // Y2 = A_hat * bn(a1)  (bf16 N x 128)
    bf16* Y2 = (bf16*)R2;
    launch_gather<bf16, bf16>(a1, dinv, rowptr, ccol, Y2, N_NODES, H1, H1, 1,
                              ssum, ssumsq, nullptr, stream);
    // z = l2norm(Y2 @ W2 + b2)  (fp32 N x 64 in R1, bf16 copy after it)
    float* z  = R1;
    bf16*  zb = (bf16*)(R1 + (size_t)N_NODES * 64);
    launch_mfma<float>(Y2, eW2b, z, N_NODES, 128, 64, H2, H2, enc_b2, 0, stream);
    k_l2norm2<<<cdiv(N_NODES, 4), b64x4, 0, stream>>>(z, zb, N_NODES);

    // z_pool
    zero(segcnt, N_GRAPHS);
    k_seg_cnt<<<cdiv(N_NODES, 256), 256, 0, stream>>>(batch, N_NODES, segcnt);
    segpool(z, batch, N_NODES, out + OFF_ZPOOL);

    // ===================== decode (MFMA) =====================
    bf16* r1 = (bf16*)R2;  // N x 128 bf16 (Y2 dead)
    launch_mfma<bf16>(zb, dW0b, r1, N_NODES, 64, 128, H1, H1, nullptr, 1, stream);
    bf16* r2 = (bf16*)R1;  // N x 256 bf16 (z/zb dead)
    launch_mfma<bf16>(r1, dW1b, r2, N_NODES, 128, 256, H0, H0, nullptr, 1, stream);
    launch_mfma<float>(r2, dW2b, out + OFF_XREC, N_NODES, 256, 48, F_IN, F_IN,
                       nullptr, 2, stream);

    // ===================== target node MLP (fp32 vector) =====================
    float* t0 = R2;  // 2048 x 256
    launch_gemm<float, float>(target_x, node_W0, t0, N_GRAPHS, F_IN, H0, node_b0, 1,
                              nullptr, nullptr, stream);
    bn_stats(t0, N_GRAPHS, H0);
    float* t1 = R1;  // 2048 x 128
    launch_gemm<float, float>(t0, node_W1, t1, N_GRAPHS, H0, H1, node_b1, 1,
                              ssum, ssumsq, stream);
    bn_stats(t1, N_GRAPHS, H1);
    launch_gemm<float, float>(t1, node_W2, out + OFF_TZ, N_GRAPHS, H1, H2, node_b2, 0,
                              ssum, ssumsq, stream);
    k_l2norm2<<<cdiv(N_GRAPHS, 4), b64x4, 0, stream>>>(out + OFF_TZ, nullptr, N_GRAPHS);

    // ===================== subgraph pipelines (bf16 MFMA) =====================
    auto sub_phase = [&](const float* sx, const int* sei, const int* sb, float* outp) {
        build_graph(sei, N_SUB, E_SUB);
        zero(segcnt, N_GRAPHS);
        k_seg_cnt<<<cdiv(N_SUB, 256), 256, 0, stream>>>(sb, N_SUB, segcnt);

        // Ys = A_hat * sx  (bf16 32768 x 64, K-padded 38->64)
        bf16* Ys = (bf16*)R2;
        launch_gather<float, bf16>(sx, dinv, rowptr, ccol, Ys, N_SUB, F_IN, 64,
                                   0, nullptr, nullptr, nullptr, stream);
        // as0 = relu(Ys @ sub_W0 + b)  (bf16 32768 x 256)
        bf16* as0 = (bf16*)R1;
        launch_mfma<bf16>(Ys, sW0b, as0, N_SUB, 64, 256, H0, H0, sub_b0, 1, stream);
        segbn_stats(as0, sb, N_SUB, H0);
        // Ys1 = A_hat * segbn(as0)  (bf16 32768 x 256)
        bf16* Ys1 = (bf16*)R2;
        launch_gather<bf16, bf16>(as0, dinv, rowptr, ccol, Ys1, N_SUB, H0, H0, 2,
                                  segsum, segsumsq, sb, stream);
        // as1 = relu(Ys1 @ sub_W1 + b)  (bf16 32768 x 128)
        bf16* as1 = (bf16*)R1;
        launch_mfma<bf16>(Ys1, sW1b, as1, N_SUB, 256, 128, H1, H1, sub_b1, 1, stream);
        segbn_stats(as1, sb, N_SUB, H1);
        // Ys2 = A_hat * segbn(as1)  (bf16 32768 x 128)
        bf16* Ys2 = (bf16*)R2;
        launch_gather<bf16, bf16>(as1, dinv, rowptr, ccol, Ys2, N_SUB, H1, H1, 2,
                                  segsum, segsumsq, sb, stream);
        // zs = l2norm(Ys2 @ enc_W2 + b2)  (fp32 32768 x 64)
        float* zs = R1;
        launch_mfma<float>(Ys2, eW2b, zs, N_SUB, 128, 64, H2, H2, enc_b2, 0, stream);
        k_l2norm2<<<cdiv(N_SUB, 4), b64x4, 0, stream>>>(zs, nullptr, N_SUB);
        segpool(zs, sb, N_SUB, outp);
    };
    sub_phase(pos_x, pos_ei, pos_b, out + OFF_PPOOL);
    sub_phase(neg_x, neg_ei, neg_b, out + OFF_NPOOL);

    // ===================== classifier on neg_pool (fp32 vector) =====================
    float* c1 = R2;
    launch_gemm<float, float>(out + OFF_NPOOL, cls_W0, c1, N_GRAPHS, H2, H1, cls_b0, 1,
                              nullptr, nullptr, stream);
    float* c2 = R1;
    launch_gemm<float, float>(c1, cls_W1, c2, N_GRAPHS, H1, 16, cls_b1, 1,
                              nullptr, nullptr, stream);
    launch_gemm<float, float>(c2, cls_W2, out + OFF_PRED, N_GRAPHS, 16, 1, cls_b2, 2,
                              nullptr, nullptr, stream);
}

// Round 7
// 2166.917 us; speedup vs baseline: 3.2581x; 1.2051x over previous
//
#include <hip/hip_runtime.h>
#include <hip/hip_bf16.h>
#include <math.h>

// ---------------------------------------------------------------------------
// Problem constants (from reference)
// ---------------------------------------------------------------------------
#define N_NODES  200000
#define N_EDGES  800000
#define N_GRAPHS 2048
#define N_SUB    32768
#define E_SUB    131072
#define F_IN     38
#define H0       256
#define H1       128
#define H2       64
#define BN_EPS   1e-5f

typedef __hip_bfloat16 bf16;
typedef __attribute__((ext_vector_type(8))) short short8;
typedef __attribute__((ext_vector_type(4))) float float4v;

static __host__ __device__ inline int cdiv(int a, int b) { return (a + b - 1) / b; }

__device__ inline float ldf(const float* p, size_t i) { return p[i]; }
__device__ inline float ldf(const bf16* p, size_t i)  { return __bfloat162float(p[i]); }
__device__ inline void  stf(float* p, size_t i, float v) { p[i] = v; }
__device__ inline void  stf(bf16* p, size_t i, float v)  { p[i] = __float2bfloat16(v); }

__device__ inline float2 ldf2(const float* p, size_t i) { return ((const float2*)p)[i]; }
__device__ inline float2 ldf2(const bf16* p, size_t i) {
    __hip_bfloat162 v = ((const __hip_bfloat162*)p)[i];
    return make_float2(__bfloat162float(v.x), __bfloat162float(v.y));
}
__device__ inline void stf2(float* p, size_t i, float2 v) { ((float2*)p)[i] = v; }
__device__ inline void stf2(bf16* p, size_t i, float2 v) {
    __hip_bfloat162 t;
    t.x = __float2bfloat16(v.x);
    t.y = __float2bfloat16(v.y);
    ((__hip_bfloat162*)p)[i] = t;
}

// ---------------------------------------------------------------------------
// Zero fill (graph-capture-safe replacement for hipMemsetAsync)
// ---------------------------------------------------------------------------
__global__ void k_zero(float* __restrict__ p, int n) {
    int i = blockIdx.x * 256 + threadIdx.x;
    if (i < n) p[i] = 0.f;
}

// ---------------------------------------------------------------------------
// Graph preprocessing: degree, CSR build
// ---------------------------------------------------------------------------
__global__ void k_count(const int* __restrict__ dst, int* __restrict__ cnt, int e) {
    int i = blockIdx.x * 256 + threadIdx.x;
    if (i < e) atomicAdd(&cnt[dst[i]], 1);
}

__global__ void k_dinv(const int* __restrict__ cnt, float* __restrict__ dinv, int n) {
    int i = blockIdx.x * 256 + threadIdx.x;
    if (i < n) dinv[i] = rsqrtf(1.0f + (float)cnt[i]);
}

__global__ void k_scan_sum(const int* __restrict__ cnt, int* __restrict__ bsum, int n) {
    __shared__ int tmp[256];
    int t = threadIdx.x;
    int i = blockIdx.x * 256 + t;
    tmp[t] = (i < n) ? cnt[i] : 0;
    __syncthreads();
    for (int off = 128; off > 0; off >>= 1) {
        if (t < off) tmp[t] += tmp[t + off];
        __syncthreads();
    }
    if (t == 0) bsum[blockIdx.x] = tmp[0];
}

__global__ void k_scan_top(int* __restrict__ bsum, int nb) {
    __shared__ int tmp[1024];
    int t = threadIdx.x;
    int v = (t < nb) ? bsum[t] : 0;
    tmp[t] = v;
    __syncthreads();
    for (int off = 1; off < 1024; off <<= 1) {
        int a = (t >= off) ? tmp[t - off] : 0;
        __syncthreads();
        tmp[t] += a;
        __syncthreads();
    }
    if (t < nb) bsum[t] = tmp[t] - v;  // exclusive
}

__global__ void k_scan_apply(const int* __restrict__ cnt, const int* __restrict__ bsum,
                             int* __restrict__ rowptr, int n) {
    __shared__ int tmp[256];
    int t = threadIdx.x;
    int i = blockIdx.x * 256 + t;
    int v = (i < n) ? cnt[i] : 0;
    tmp[t] = v;
    __syncthreads();
    for (int off = 1; off < 256; off <<= 1) {
        int a = (t >= off) ? tmp[t - off] : 0;
        __syncthreads();
        tmp[t] += a;
        __syncthreads();
    }
    int excl = tmp[t] - v + bsum[blockIdx.x];
    if (i < n) rowptr[i] = excl;
    if (i == n - 1) rowptr[n] = excl + v;
}

// cursor aliases the (consumed) cnt buffer — re-zeroed before this kernel.
__global__ void k_fill(const int* __restrict__ src, const int* __restrict__ dst,
                       const int* __restrict__ rowptr, int* __restrict__ cursor,
                       int* __restrict__ col, int e) {
    int i = blockIdx.x * 256 + threadIdx.x;
    if (i < e) {
        int d = dst[i];
        int p = rowptr[d] + atomicAdd(&cursor[d], 1);
        col[p] = src[i];
    }
}

// ---------------------------------------------------------------------------
// Gather v3 (pure aggregation + epilogue):
//   o[i,:] = relu?( sum_j dinv[src_j]*dinv[i]*h[src_j,:] + dinv_i^2*h[i,:] + bias )
// 2-stage software pipeline: col[p+1] and dinv[s_nxt] prefetched while the
// current row loads are in flight (breaks the col->dinv->row serial chain).
// PPN = lanes per node (64: 1 node/wave for M2>32; 32: 2 nodes/wave).
// Input rows M2 pairs; output rows S2 pairs; pairs in [M2,S2) written ZERO
// (K-padding for the MFMA consumer, rewritten every call).
// ---------------------------------------------------------------------------
template <typename TI, typename TO, int PPN>
__global__ __launch_bounds__(256) void k_gather3(
    const TI* __restrict__ h, const float* __restrict__ dinv,
    const int* __restrict__ rowptr, const int* __restrict__ col,
    TO* __restrict__ o, int n, int M2, int S2,
    const float* __restrict__ bias, int relu)
{
    const int NPW = 64 / PPN;  // nodes per wave
    int node = blockIdx.x * 4 * NPW + threadIdx.y * NPW + threadIdx.x / PPN;
    int pr = threadIdx.x % PPN;
    if (node >= n) return;
    bool pld = pr < M2, pst = pr < S2;

    float di = dinv[node];
    float2 acc = make_float2(0.f, 0.f);

    // self loop (no index dependency — issues immediately)
    if (pld) {
        float2 v = ldf2(h, (size_t)node * M2 + pr);
        acc.x += di * di * v.x;
        acc.y += di * di * v.y;
    }

    int pb = rowptr[node], pe = rowptr[node + 1];
    int s_cur = 0, s_nxt = 0;
    float d_cur = 0.f;
    if (pb < pe) { s_cur = col[pb]; d_cur = dinv[s_cur]; }
    if (pb + 1 < pe) s_nxt = col[pb + 1];
    for (int p = pb; p < pe; ++p) {
        float2 v = pld ? ldf2(h, (size_t)s_cur * M2 + pr) : make_float2(0.f, 0.f);
        float d_nxt = (p + 1 < pe) ? dinv[s_nxt] : 0.f;   // overlaps row loads
        int s_nx2 = (p + 2 < pe) ? col[p + 2] : 0;        // overlaps row loads
        float cf = d_cur * di;
        acc.x += cf * v.x;
        acc.y += cf * v.y;
        s_cur = s_nxt; d_cur = d_nxt; s_nxt = s_nx2;
    }

    if (pst) {
        float2 r = acc;
        if (bias && pld) { r.x += bias[2 * pr]; r.y += bias[2 * pr + 1]; }
        if (relu) { r.x = fmaxf(r.x, 0.f); r.y = fmaxf(r.y, 0.f); }
        stf2(o, (size_t)node * S2 + pr, r);
    }
}

template <typename TI, typename TO>
static void launch_gather(const TI* h, const float* dinv, const int* rowptr,
                          const int* col, TO* o, int n, int M, int Sout,
                          const float* bias, int relu, hipStream_t stream) {
    dim3 b(64, 4);
    int M2 = M >> 1, S2 = Sout >> 1;
    if (S2 > 32)
        k_gather3<TI, TO, 64><<<cdiv(n, 4), b, 0, stream>>>(h, dinv, rowptr, col, o,
                                                            n, M2, S2, bias, relu);
    else
        k_gather3<TI, TO, 32><<<cdiv(n, 8), b, 0, stream>>>(h, dinv, rowptr, col, o,
                                                            n, M2, S2, bias, relu);
}

// ---------------------------------------------------------------------------
// W pre-pack into MFMA B-fragment layout (bf16):
//   Wb[((s*Mp) + n)*32 + kk] = W[s*32+kk][n]   (zero-padded k>=K or n>=M)
// ---------------------------------------------------------------------------
__global__ void k_wpack(const float* __restrict__ W, bf16* __restrict__ Wb,
                        int K, int M, int Mp) {
    int S = (K + 31) >> 5;
    int tot = S * Mp * 32;
    for (int i = blockIdx.x * 256 + threadIdx.x; i < tot; i += gridDim.x * 256) {
        int kk = i & 31;
        int rem = i >> 5;
        int ncol = rem % Mp;
        int s = rem / Mp;
        int k = s * 32 + kk;
        float v = (k < K && ncol < M) ? W[(size_t)k * M + ncol] : 0.f;
        Wb[i] = __float2bfloat16(v);
    }
}

// ---------------------------------------------------------------------------
// MFMA GEMM (bf16 in, fp32 accumulate):  C = act( bn(A) @ W + bias )
//   BNM template: 0 = none; 1 = global BN (a-mu[k])*sc[k];
//                 2 = per-segment BN with tables mu/sc[seg[row]*SA + k].
//   A: bf16 row-major n x SA (SA mult of 32; BN sites have SA == real K).
//   Wb: packed per k_wpack (Mp = M padded to mult of 16).
// Block (64,4): wave w owns rows [blk*64 + w*16, +16); NT col-tiles of 16.
// No LDS, no barriers. n must be a multiple of 64 (true at all call sites).
// ---------------------------------------------------------------------------
template <typename TC, int NT, int BNM>
__global__ __launch_bounds__(256) void k_mfma_gemm(
    const bf16* __restrict__ A, const bf16* __restrict__ Wb,
    TC* __restrict__ C, int n, int SA, int Mp, int M, int MC,
    const float* __restrict__ bias, int act,
    const float* __restrict__ mu, const float* __restrict__ sc,
    const int* __restrict__ seg)
{
    const int lane = threadIdx.x;
    const int wave = threadIdx.y;
    const int row0 = blockIdx.x * 64 + wave * 16;
    const int qr = lane >> 4;
    const int lc = lane & 15;

    float4v acc[NT];
#pragma unroll
    for (int t = 0; t < NT; ++t) acc[t] = (float4v){0.f, 0.f, 0.f, 0.f};

    size_t bnbase = 0;
    if (BNM == 2) bnbase = (size_t)seg[row0 + lc] * SA;

    const int S = SA >> 5;
    const bf16* arow = A + (size_t)(row0 + lc) * SA + qr * 8;
    const bf16* wrow = Wb + (size_t)lc * 32 + qr * 8;

    for (int s = 0; s < S; ++s) {
        short8 af = *(const short8*)(arow + s * 32);
        if (BNM != 0) {
            int kb = s * 32 + qr * 8;
            const float* mp = mu + bnbase + kb;
            const float* sp = sc + bnbase + kb;
            float4 m0 = *(const float4*)mp, m1 = *(const float4*)(mp + 4);
            float4 s0 = *(const float4*)sp, s1 = *(const float4*)(sp + 4);
            float av[8];
#pragma unroll
            for (int j = 0; j < 8; ++j) {
                short sv = af[j];
                av[j] = __bfloat162float(*reinterpret_cast<const bf16*>(&sv));
            }
            av[0] = (av[0] - m0.x) * s0.x; av[1] = (av[1] - m0.y) * s0.y;
            av[2] = (av[2] - m0.z) * s0.z; av[3] = (av[3] - m0.w) * s0.w;
            av[4] = (av[4] - m1.x) * s1.x; av[5] = (av[5] - m1.y) * s1.y;
            av[6] = (av[6] - m1.z) * s1.z; av[7] = (av[7] - m1.w) * s1.w;
#pragma unroll
            for (int j = 0; j < 8; ++j) {
                bf16 t = __float2bfloat16(av[j]);
                af[j] = *reinterpret_cast<const short*>(&t);
            }
        }
#pragma unroll
        for (int t = 0; t < NT; ++t) {
            short8 bfr = *(const short8*)(wrow + ((size_t)s * Mp + t * 16) * 32);
            acc[t] = __builtin_amdgcn_mfma_f32_16x16x32_bf16(af, bfr, acc[t], 0, 0, 0);
        }
    }

#pragma unroll
    for (int t = 0; t < NT; ++t) {
        int c = t * 16 + lc;
        if (c >= M) continue;
        float b = bias ? bias[c] : 0.f;
#pragma unroll
        for (int r = 0; r < 4; ++r) {
            int row = row0 + qr * 4 + r;
            float v = acc[t][r] + b;
            if (act == 1) v = fmaxf(v, 0.f);
            else if (act == 2) v = 1.f / (1.f + expf(-v));
            stf(C, (size_t)row * MC + c, v);
        }
    }
}

template <typename TC, int BNM>
static void launch_mfma(const bf16* A, const bf16* Wb, TC* C, int n, int SA,
                        int Mp, int M, int MC, const float* bias, int act,
                        const float* mu, const float* sc, const int* seg,
                        hipStream_t stream) {
    dim3 b(64, 4);
    int g = n / 64;
    if (Mp == 256)      k_mfma_gemm<TC, 16, BNM><<<g, b, 0, stream>>>(A, Wb, C, n, SA, Mp, M, MC, bias, act, mu, sc, seg);
    else if (Mp == 128) k_mfma_gemm<TC, 8, BNM><<<g, b, 0, stream>>>(A, Wb, C, n, SA, Mp, M, MC, bias, act, mu, sc, seg);
    else if (Mp == 64)  k_mfma_gemm<TC, 4, BNM><<<g, b, 0, stream>>>(A, Wb, C, n, SA, Mp, M, MC, bias, act, mu, sc, seg);
    else                k_mfma_gemm<TC, 3, BNM><<<g, b, 0, stream>>>(A, Wb, C, n, SA, Mp, M, MC, bias, act, mu, sc, seg);
}

// ---------------------------------------------------------------------------
// LDS-tiled fp32 vector GEMM (t-MLP / classifier — tiny n, precision-tight)
// ---------------------------------------------------------------------------
template <typename TA, typename TC, int NJ>
__global__ __launch_bounds__(256) void k_gemm(
    const TA* __restrict__ A, const float* __restrict__ W,
    TC* __restrict__ C, int n, int K, int M,
    const float* __restrict__ bias, int act,
    const float* __restrict__ mu, const float* __restrict__ sc)
{
    __shared__ float alds[64 * 32];
    __shared__ float wlds[32 * 256];
    const int l = threadIdx.x;
    const int wy = threadIdx.y;
    const int tid = wy * 64 + l;
    const int row0 = blockIdx.x * 64;

    float acc[16][NJ];
#pragma unroll
    for (int r = 0; r < 16; ++r)
#pragma unroll
        for (int j = 0; j < NJ; ++j) acc[r][j] = 0.f;

    int cidx[NJ]; bool jval[NJ];
#pragma unroll
    for (int j = 0; j < NJ; ++j) {
        cidx[j] = l + 64 * j;
        jval[j] = cidx[j] < M;
    }

    for (int k0 = 0; k0 < K; k0 += 32) {
        int kt = min(32, K - k0);
        __syncthreads();
        for (int i = tid; i < 64 * 32; i += 256) {
            int r = i >> 5, kk = i & 31;
            int row = row0 + r, k = k0 + kk;
            float v = (row < n && k < K) ? ldf(A, (size_t)row * K + k) : 0.f;
            if (mu && k < K) v = (v - mu[k]) * sc[k];
            alds[i] = v;
        }
        for (int i = tid; i < kt * M; i += 256)
            wlds[i] = W[(size_t)k0 * M + i];
        if (kt < 32)
            for (int i = kt * M + tid; i < 32 * M; i += 256) wlds[i] = 0.f;
        __syncthreads();

#pragma unroll 2
        for (int kkg = 0; kkg < 8; ++kkg) {
            float wv[4][NJ];
#pragma unroll
            for (int q = 0; q < 4; ++q)
#pragma unroll
                for (int j = 0; j < NJ; ++j)
                    wv[q][j] = jval[j] ? wlds[(kkg * 4 + q) * M + cidx[j]] : 0.f;
#pragma unroll
            for (int rr = 0; rr < 16; ++rr) {
                const float4* arow = (const float4*)&alds[(wy * 16 + rr) * 32];
                float4 av = arow[kkg];
#pragma unroll
                for (int j = 0; j < NJ; ++j) {
                    acc[rr][j] += av.x * wv[0][j];
                    acc[rr][j] += av.y * wv[1][j];
                    acc[rr][j] += av.z * wv[2][j];
                    acc[rr][j] += av.w * wv[3][j];
                }
            }
        }
    }

#pragma unroll
    for (int rr = 0; rr < 16; ++rr) {
        int row = row0 + wy * 16 + rr;
        if (row >= n) continue;
#pragma unroll
        for (int j = 0; j < NJ; ++j) {
            if (!jval[j]) continue;
            float v = acc[rr][j];
            if (bias) v += bias[cidx[j]];
            if (act == 1) v = fmaxf(v, 0.f);
            else if (act == 2) v = 1.f / (1.f + expf(-v));
            stf(C, (size_t)row * M + cidx[j], v);
        }
    }
}

// ---------------------------------------------------------------------------
// BatchNorm stats (global, column-wise).  M must divide 256.
// ---------------------------------------------------------------------------
template <typename T>
__global__ void k_bn_stats(const T* __restrict__ x, int n, int M,
                           float* __restrict__ sum, float* __restrict__ sumsq) {
    int t = threadIdx.x;
    int G = 256 / M;
    int c = t % M, g = t / M;
    int r = blockIdx.x * 256 + g;
    int rend = min(n, blockIdx.x * 256 + 256);
    float s = 0.f, q = 0.f;
    for (; r < rend; r += G) {
        float v = ldf(x, (size_t)r * M + c);
        s += v;
        q += v * v;
    }
    atomicAdd(&sum[c], s);
    atomicAdd(&sumsq[c], q);
}

__global__ void k_bn_fin(float* __restrict__ sum, float* __restrict__ sumsq, int n, int M) {
    int c = threadIdx.x;
    if (c < M) {
        float m = sum[c] / (float)n;
        float v = fmaxf(sumsq[c] / (float)n - m * m, 0.f);
        sum[c] = m;
        sumsq[c] = rsqrtf(v + BN_EPS);
    }
}

// ---------------------------------------------------------------------------
// Segment stats (seg sorted => few atomic flushes).  M must divide 256.
// ---------------------------------------------------------------------------
template <typename T>
__global__ void k_seg_stats(const T* __restrict__ x, const int* __restrict__ seg,
                            int n, int M, float* __restrict__ ssum, float* __restrict__ ssq) {
    int t = threadIdx.x;
    int G = 256 / M;
    int c = t % M, g = t / M;
    int r = blockIdx.x * 256 + g;
    int rend = min(n, blockIdx.x * 256 + 256);
    float s = 0.f, q = 0.f;
    int cur = -1;
    for (; r < rend; r += G) {
        int sgv = seg[r];
        if (sgv != cur) {
            if (cur >= 0) {
                atomicAdd(&ssum[(size_t)cur * M + c], s);
                atomicAdd(&ssq[(size_t)cur * M + c], q);
            }
            cur = sgv; s = 0.f; q = 0.f;
        }
        float v = ldf(x, (size_t)r * M + c);
        s += v;
        q += v * v;
    }
    if (cur >= 0) {
        atomicAdd(&ssum[(size_t)cur * M + c], s);
        atomicAdd(&ssq[(size_t)cur * M + c], q);
    }
}

__global__ void k_seg_cnt(const int* __restrict__ seg, int n, float* __restrict__ cnt) {
    int i = blockIdx.x * 256 + threadIdx.x;
    if (i < n) atomicAdd(&cnt[seg[i]], 1.0f);
}

__global__ void k_seg_fin(float* __restrict__ ssum, float* __restrict__ ssq,
                          const float* __restrict__ cnt, int nseg, int M) {
    int i = blockIdx.x * 256 + threadIdx.x;
    if (i < nseg * M) {
        int g = i / M;
        float c = fmaxf(cnt[g], 1.f);
        float m = ssum[i] / c;
        float v = fmaxf(ssq[i] / c - m * m, 0.f);
        ssum[i] = m;
        ssq[i] = rsqrtf(v + BN_EPS);
    }
}

__global__ void k_pool_fin(const float* __restrict__ ssum, const float* __restrict__ cnt,
                           int nseg, int M, float* __restrict__ o) {
    int i = blockIdx.x * 256 + threadIdx.x;
    if (i < nseg * M) {
        int g = i / M;
        o[i] = ssum[i] / fmaxf(cnt[g], 1.f);
    }
}

// ---------------------------------------------------------------------------
// Row L2 normalize, M = 64; writes fp32 in place + optional bf16 copy
// ---------------------------------------------------------------------------
__global__ void k_l2norm2(float* __restrict__ x, bf16* __restrict__ xb, int n) {
    int row = blockIdx.x * 4 + threadIdx.y;
    if (row >= n) return;
    int l = threadIdx.x;
    float v = x[(size_t)row * 64 + l];
    float ss = v * v;
    for (int o = 32; o > 0; o >>= 1) ss += __shfl_xor(ss, o, 64);
    float r = v / fmaxf(sqrtf(ss), 1e-12f);
    x[(size_t)row * 64 + l] = r;
    if (xb) xb[(size_t)row * 64 + l] = __float2bfloat16(r);
}

// ---------------------------------------------------------------------------
// Host-side vector-GEMM launch helper
// ---------------------------------------------------------------------------
template <typename TA, typename TC>
static void launch_gemm(const TA* A, const float* W, TC* C, int n, int K, int M,
                        const float* bias, int act, const float* mu, const float* sc,
                        hipStream_t stream) {
    dim3 b(64, 4);
    int g = cdiv(n, 64);
    int nj = (M + 63) >> 6;
    if (nj >= 4)      k_gemm<TA, TC, 4><<<g, b, 0, stream>>>(A, W, C, n, K, M, bias, act, mu, sc);
    else if (nj == 2) k_gemm<TA, TC, 2><<<g, b, 0, stream>>>(A, W, C, n, K, M, bias, act, mu, sc);
    else              k_gemm<TA, TC, 1><<<g, b, 0, stream>>>(A, W, C, n, K, M, bias, act, mu, sc);
}

// ---------------------------------------------------------------------------
// Host launch
// ---------------------------------------------------------------------------
extern "C" void kernel_launch(void* const* d_in, const int* in_sizes, int n_in,
                              void* d_out, int out_size, void* d_ws, size_t ws_size,
                              hipStream_t stream) {
    const float* x        = (const float*)d_in[0];
    const int*   ei       = (const int*)  d_in[1];
    const int*   batch    = (const int*)  d_in[2];
    const float* target_x = (const float*)d_in[3];
    const float* pos_x    = (const float*)d_in[4];
    const int*   pos_ei   = (const int*)  d_in[5];
    const int*   pos_b    = (const int*)  d_in[6];
    const float* neg_x    = (const float*)d_in[7];
    const int*   neg_ei   = (const int*)  d_in[8];
    const int*   neg_b    = (const int*)  d_in[9];
    const float* enc_W0 = (const float*)d_in[10]; const float* enc_b0 = (const float*)d_in[11];
    const float* enc_W1 = (const float*)d_in[12]; const float* enc_b1 = (const float*)d_in[13];
    const float* enc_W2 = (const float*)d_in[14]; const float* enc_b2 = (const float*)d_in[15];
    const float* dec_W0 = (const float*)d_in[16];
    const float* dec_W1 = (const float*)d_in[17];
    const float* dec_W2 = (const float*)d_in[18];
    const float* node_W0 = (const float*)d_in[19]; const float* node_b0 = (const float*)d_in[20];
    const float* node_W1 = (const float*)d_in[21]; const float* node_b1 = (const float*)d_in[22];
    const float* node_W2 = (const float*)d_in[23]; const float* node_b2 = (const float*)d_in[24];
    const float* sub_W0 = (const float*)d_in[25]; const float* sub_b0 = (const float*)d_in[26];
    const float* sub_W1 = (const float*)d_in[27]; const float* sub_b1 = (const float*)d_in[28];
    const float* cls_W0 = (const float*)d_in[29]; const float* cls_b0 = (const float*)d_in[30];
    const float* cls_W1 = (const float*)d_in[31]; const float* cls_b1 = (const float*)d_in[32];
    const float* cls_W2 = (const float*)d_in[33]; const float* cls_b2 = (const float*)d_in[34];

    float* out = (float*)d_out;
    const size_t OFF_XREC  = 0;
    const size_t OFF_ZPOOL = (size_t)N_NODES * F_IN;
    const size_t OFF_TZ    = OFF_ZPOOL + (size_t)N_GRAPHS * H2;
    const size_t OFF_PPOOL = OFF_TZ    + (size_t)N_GRAPHS * H2;
    const size_t OFF_NPOOL = OFF_PPOOL + (size_t)N_GRAPHS * H2;
    const size_t OFF_PRED  = OFF_NPOOL + (size_t)N_GRAPHS * H2;

    // ----- workspace carve-up (by floats; total ~215 MB — proven safe) -----
    char* wsp = (char*)d_ws;
    auto alloc = [&](size_t nfloats) -> float* {
        float* p = (float*)wsp;
        wsp += ((nfloats + 63) / 64) * 64 * sizeof(float);
        return p;
    };
    float* R1     = alloc((size_t)N_NODES * 128);   // fp32 N*128 / bf16 N*256
    float* R2     = alloc((size_t)N_NODES * 128);
    float* dinv   = alloc(N_NODES);
    int*   cnt    = (int*)alloc(N_NODES);           // degree, then reused as cursor
    int*   rowptr = (int*)alloc(N_NODES + 1);
    int*   bsum   = (int*)alloc(1024);
    int*   ccol   = (int*)alloc(N_EDGES);
    float* ssum   = alloc(256);
    float* ssumsq = alloc(256);   // contiguous with ssum
    float* segsum   = alloc((size_t)N_GRAPHS * 256);
    float* segsumsq = alloc((size_t)N_GRAPHS * 256); // contiguous with segsum
    float* segcnt   = alloc(N_GRAPHS);
    bf16*  wpk      = (bf16*)alloc(80 * 1024);  // 163840-bf16 arena, 159744 used
    (void)ws_size; (void)in_sizes; (void)n_in; (void)out_size;

    // packed-weight arena offsets (bf16 elements): S*Mp*32 each
    bf16* eW0b = wpk;            // K38->S2,  Mp256: 16384
    bf16* eW1b = eW0b + 16384;   // K256->S8, Mp128: 32768
    bf16* eW2b = eW1b + 32768;   // K128->S4, Mp64 :  8192
    bf16* dW0b = eW2b + 8192;    // K64->S2,  Mp128:  8192
    bf16* dW1b = dW0b + 8192;    // K128->S4, Mp256: 32768
    bf16* dW2b = dW1b + 32768;   // K256->S8, Mp48 : 12288
    bf16* sW0b = dW2b + 12288;   // K38->S2,  Mp256: 16384
    bf16* sW1b = sW0b + 16384;   // K256->S8, Mp128: 32768

    dim3 b64x4(64, 4);
    auto zero = [&](void* p, size_t nfloats) {
        k_zero<<<cdiv((int)nfloats, 256), 256, 0, stream>>>((float*)p, (int)nfloats);
    };

    // pack all weights (small; once per call; BN is fused at GEMM A-load, so
    // packs are plain)
    k_wpack<<<64, 256, 0, stream>>>(enc_W0, eW0b, F_IN, H0, 256);
    k_wpack<<<64, 256, 0, stream>>>(enc_W1, eW1b, H0, H1, 128);
    k_wpack<<<64, 256, 0, stream>>>(enc_W2, eW2b, H1, H2, 64);
    k_wpack<<<64, 256, 0, stream>>>(dec_W0, dW0b, H2, H1, 128);
    k_wpack<<<64, 256, 0, stream>>>(dec_W1, dW1b, H1, H0, 256);
    k_wpack<<<64, 256, 0, stream>>>(dec_W2, dW2b, H0, F_IN, 48);
    k_wpack<<<64, 256, 0, stream>>>(sub_W0, sW0b, F_IN, H0, 256);
    k_wpack<<<64, 256, 0, stream>>>(sub_W1, sW1b, H0, H1, 128);

    auto build_graph = [&](const int* eidx, int n, int e) {
        zero(cnt, n);
        k_count<<<cdiv(e, 256), 256, 0, stream>>>(eidx + e, cnt, e);
        k_dinv<<<cdiv(n, 256), 256, 0, stream>>>(cnt, dinv, n);
        int nb = cdiv(n, 256);
        k_scan_sum<<<nb, 256, 0, stream>>>(cnt, bsum, n);
        k_scan_top<<<1, 1024, 0, stream>>>(bsum, nb);
        k_scan_apply<<<nb, 256, 0, stream>>>(cnt, bsum, rowptr, n);
        zero(cnt, n);  // cnt now serves as the fill cursor
        k_fill<<<cdiv(e, 256), 256, 0, stream>>>(eidx, eidx + e, rowptr, cnt, ccol, e);
    };

    auto bn_stats = [&](auto* xx, int n, int M) {
        zero(ssum, 512);  // ssum+ssumsq contiguous
        k_bn_stats<<<cdiv(n, 256), 256, 0, stream>>>(xx, n, M, ssum, ssumsq);
        k_bn_fin<<<1, 256, 0, stream>>>(ssum, ssumsq, n, M);
    };

    auto segbn_stats = [&](auto* xx, const int* seg, int n, int M) {
        zero(segsum, 2 * (size_t)N_GRAPHS * 256);
        k_seg_stats<<<cdiv(n, 256), 256, 0, stream>>>(xx, seg, n, M, segsum, segsumsq);
        k_seg_fin<<<cdiv(N_GRAPHS * M, 256), 256, 0, stream>>>(segsum, segsumsq, segcnt,
                                                               N_GRAPHS, M);
    };

    auto segpool = [&](const float* zz, const int* seg, int n, float* outp) {
        zero(segsum, 2 * (size_t)N_GRAPHS * 256);
        k_seg_stats<<<cdiv(n, 256), 256, 0, stream>>>(zz, seg, n, H2, segsum, segsumsq);
        k_pool_fin<<<cdiv(N_GRAPHS * H2, 256), 256, 0, stream>>>(segsum, segcnt, N_GRAPHS,
                                                                 H2, outp);
    };

    // ============ main graph encode (GEMM-first, BN fused in GEMM) ============
    build_graph(ei, N_NODES, N_EDGES);

    // Layer 0 (aggregate-first: K=38 < M=256):
    // Y0 = A_hat * x (bf16 N x 64, K-pad 38->64); a0 = relu(Y0@W0 + b0) (bf16 N x 256)
    bf16* Y0 = (bf16*)R2;
    launch_gather<float, bf16>(x, dinv, rowptr, ccol, Y0, N_NODES, F_IN, 64,
                               nullptr, 0, stream);
    bf16* a0 = (bf16*)R1;
    launch_mfma<bf16, 0>(Y0, eW0b, a0, N_NODES, 64, 256, H0, H0, enc_b0, 1,
                         nullptr, nullptr, nullptr, stream);
    bn_stats(a0, N_NODES, H0);

    // Layer 1 (GEMM-first): G1 = bn(a0)@W1 (bf16 N x 128); a1 = relu(A_hat*G1 + b1)
    bf16* G1 = (bf16*)R2;
    launch_mfma<bf16, 1>(a0, eW1b, G1, N_NODES, 256, 128, H1, H1, nullptr, 0,
                         ssum, ssumsq, nullptr, stream);
    bf16* a1 = (bf16*)R1;
    launch_gather<bf16, bf16>(G1, dinv, rowptr, ccol, a1, N_NODES, H1, H1,
                              enc_b1, 1, stream);
    bn_stats(a1, N_NODES, H1);

    // Layer 2 (GEMM-first): G2 = bn(a1)@W2 (bf16 N x 64); z = A_hat*G2 + b2, l2norm
    bf16* G2 = (bf16*)R2;
    launch_mfma<bf16, 1>(a1, eW2b, G2, N_NODES, 128, 64, H2, H2, nullptr, 0,
                         ssum, ssumsq, nullptr, stream);
    float* z  = R1;
    bf16*  zb = (bf16*)(R1 + (size_t)N_NODES * 64);
    launch_gather<bf16, float>(G2, dinv, rowptr, ccol, z, N_NODES, H2, H2,
                               enc_b2, 0, stream);
    k_l2norm2<<<cdiv(N_NODES, 4), b64x4, 0, stream>>>(z, zb, N_NODES);

    // z_pool
    zero(segcnt, N_GRAPHS);
    k_seg_cnt<<<cdiv(N_NODES, 256), 256, 0, stream>>>(batch, N_NODES, segcnt);
    segpool(z, batch, N_NODES, out + OFF_ZPOOL);

    // ===================== decode (MFMA) =====================
    bf16* r1 = (bf16*)R2;  // N x 128 bf16 (G2 dead)
    launch_mfma<bf16, 0>(zb, dW0b, r1, N_NODES, 64, 128, H1, H1, nullptr, 1,
                         nullptr, nullptr, nullptr, stream);
    bf16* r2 = (bf16*)R1;  // N x 256 bf16 (z/zb dead: segpool + r1 done)
    launch_mfma<bf16, 0>(r1, dW1b, r2, N_NODES, 128, 256, H0, H0, nullptr, 1,
                         nullptr, nullptr, nullptr, stream);
    launch_mfma<float, 0>(r2, dW2b, out + OFF_XREC, N_NODES, 256, 48, F_IN, F_IN,
                          nullptr, 2, nullptr, nullptr, nullptr, stream);

    // ===================== target node MLP (fp32 vector) =====================
    float* t0 = R2;  // 2048 x 256
    launch_gemm<float, float>(target_x, node_W0, t0, N_GRAPHS, F_IN, H0, node_b0, 1,
                              nullptr, nullptr, stream);
    bn_stats(t0, N_GRAPHS, H0);
    float* t1 = R1;  // 2048 x 128
    launch_gemm<float, float>(t0, node_W1, t1, N_GRAPHS, H0, H1, node_b1, 1,
                              ssum, ssumsq, stream);
    bn_stats(t1, N_GRAPHS, H1);
    launch_gemm<float, float>(t1, node_W2, out + OFF_TZ, N_GRAPHS, H1, H2, node_b2, 0,
                              ssum, ssumsq, stream);
    k_l2norm2<<<cdiv(N_GRAPHS, 4), b64x4, 0, stream>>>(out + OFF_TZ, nullptr, N_GRAPHS);

    // =========== subgraph pipelines (GEMM-first, segBN fused in GEMM) ===========
    auto sub_phase = [&](const float* sx, const int* sei, const int* sb, float* outp) {
        build_graph(sei, N_SUB, E_SUB);
        zero(segcnt, N_GRAPHS);
        k_seg_cnt<<<cdiv(N_SUB, 256), 256, 0, stream>>>(sb, N_SUB, segcnt);

        // Layer 0: Ys = A_hat*sx (bf16, pad 38->64); as0 = relu(Ys@sW0 + b)
        bf16* Ys = (bf16*)R2;
        launch_gather<float, bf16>(sx, dinv, rowptr, ccol, Ys, N_SUB, F_IN, 64,
                                   nullptr, 0, stream);
        bf16* as0 = (bf16*)R1;  // 32768 x 256
        launch_mfma<bf16, 0>(Ys, sW0b, as0, N_SUB, 64, 256, H0, H0, sub_b0, 1,
                             nullptr, nullptr, nullptr, stream);
        segbn_stats(as0, sb, N_SUB, H0);

        // Layer 1: Gs1 = segbn(as0)@sW1; as1 = relu(A_hat*Gs1 + b1)
        bf16* Gs1 = (bf16*)R2;  // 32768 x 128
        launch_mfma<bf16, 2>(as0, sW1b, Gs1, N_SUB, 256, 128, H1, H1, nullptr, 0,
                             segsum, segsumsq, sb, stream);
        bf16* as1 = (bf16*)R1;  // 32768 x 128
        launch_gather<bf16, bf16>(Gs1, dinv, rowptr, ccol, as1, N_SUB, H1, H1,
                                  sub_b1, 1, stream);
        segbn_stats(as1, sb, N_SUB, H1);

        // Layer 2: Gs2 = segbn(as1)@encW2; zs = A_hat*Gs2 + b2, l2norm
        bf16* Gs2 = (bf16*)R2;  // 32768 x 64
        launch_mfma<bf16, 2>(as1, eW2b, Gs2, N_SUB, 128, 64, H2, H2, nullptr, 0,
                             segsum, segsumsq, sb, stream);
        float* zs = R1;  // 32768 x 64 fp32
        launch_gather<bf16, float>(Gs2, dinv, rowptr, ccol, zs, N_SUB, H2, H2,
                                   enc_b2, 0, stream);
        k_l2norm2<<<cdiv(N_SUB, 4), b64x4, 0, stream>>>(zs, nullptr, N_SUB);
        segpool(zs, sb, N_SUB, outp);
    };
    sub_phase(pos_x, pos_ei, pos_b, out + OFF_PPOOL);
    sub_phase(neg_x, neg_ei, neg_b, out + OFF_NPOOL);

    // ===================== classifier on neg_pool (fp32 vector) =====================
    float* c1 = R2;
    launch_gemm<float, float>(out + OFF_NPOOL, cls_W0, c1, N_GRAPHS, H2, H1, cls_b0, 1,
                              nullptr, nullptr, stream);
    float* c2 = R1;
    launch_gemm<float, float>(c1, cls_W1, c2, N_GRAPHS, H1, 16, cls_b1, 1,
                              nullptr, nullptr, stream);
    launch_gemm<float, float>(c2, cls_W2, out + OFF_PRED, N_GRAPHS, 16, 1, cls_b2, 2,
                              nullptr, nullptr, stream);
}

// Round 8
// 2163.077 us; speedup vs baseline: 3.2639x; 1.0018x over previous
//
#include <hip/hip_runtime.h>
#include <hip/hip_bf16.h>
#include <math.h>

// ---------------------------------------------------------------------------
// Problem constants (from reference)
// ---------------------------------------------------------------------------
#define N_NODES  200000
#define N_EDGES  800000
#define N_GRAPHS 2048
#define N_SUB    32768
#define E_SUB    131072
#define F_IN     38
#define H0       256
#define H1       128
#define H2       64
#define BN_EPS   1e-5f

typedef __hip_bfloat16 bf16;
typedef __attribute__((ext_vector_type(8))) short short8;
typedef __attribute__((ext_vector_type(4))) float float4v;

static __host__ __device__ inline int cdiv(int a, int b) { return (a + b - 1) / b; }

__device__ inline float ldf(const float* p, size_t i) { return p[i]; }
__device__ inline float ldf(const bf16* p, size_t i)  { return __bfloat162float(p[i]); }
__device__ inline void  stf(float* p, size_t i, float v) { p[i] = v; }
__device__ inline void  stf(bf16* p, size_t i, float v)  { p[i] = __float2bfloat16(v); }

__device__ inline float2 ldf2(const float* p, size_t i) { return ((const float2*)p)[i]; }
__device__ inline float2 ldf2(const bf16* p, size_t i) {
    __hip_bfloat162 v = ((const __hip_bfloat162*)p)[i];
    return make_float2(__bfloat162float(v.x), __bfloat162float(v.y));
}
__device__ inline void stf2(float* p, size_t i, float2 v) { ((float2*)p)[i] = v; }
__device__ inline void stf2(bf16* p, size_t i, float2 v) {
    __hip_bfloat162 t;
    t.x = __float2bfloat16(v.x);
    t.y = __float2bfloat16(v.y);
    ((__hip_bfloat162*)p)[i] = t;
}

// ---------------------------------------------------------------------------
// Zero fill (graph-capture-safe replacement for hipMemsetAsync)
// ---------------------------------------------------------------------------
__global__ void k_zero(float* __restrict__ p, int n) {
    int i = blockIdx.x * 256 + threadIdx.x;
    if (i < n) p[i] = 0.f;
}

// ---------------------------------------------------------------------------
// Graph preprocessing: degree, CSR build
// ---------------------------------------------------------------------------
__global__ void k_count(const int* __restrict__ dst, int* __restrict__ cnt, int e) {
    int i = blockIdx.x * 256 + threadIdx.x;
    if (i < e) atomicAdd(&cnt[dst[i]], 1);
}

__global__ void k_dinv(const int* __restrict__ cnt, float* __restrict__ dinv, int n) {
    int i = blockIdx.x * 256 + threadIdx.x;
    if (i < n) dinv[i] = rsqrtf(1.0f + (float)cnt[i]);
}

__global__ void k_scan_sum(const int* __restrict__ cnt, int* __restrict__ bsum, int n) {
    __shared__ int tmp[256];
    int t = threadIdx.x;
    int i = blockIdx.x * 256 + t;
    tmp[t] = (i < n) ? cnt[i] : 0;
    __syncthreads();
    for (int off = 128; off > 0; off >>= 1) {
        if (t < off) tmp[t] += tmp[t + off];
        __syncthreads();
    }
    if (t == 0) bsum[blockIdx.x] = tmp[0];
}

__global__ void k_scan_top(int* __restrict__ bsum, int nb) {
    __shared__ int tmp[1024];
    int t = threadIdx.x;
    int v = (t < nb) ? bsum[t] : 0;
    tmp[t] = v;
    __syncthreads();
    for (int off = 1; off < 1024; off <<= 1) {
        int a = (t >= off) ? tmp[t - off] : 0;
        __syncthreads();
        tmp[t] += a;
        __syncthreads();
    }
    if (t < nb) bsum[t] = tmp[t] - v;  // exclusive
}

__global__ void k_scan_apply(const int* __restrict__ cnt, const int* __restrict__ bsum,
                             int* __restrict__ rowptr, int n) {
    __shared__ int tmp[256];
    int t = threadIdx.x;
    int i = blockIdx.x * 256 + t;
    int v = (i < n) ? cnt[i] : 0;
    tmp[t] = v;
    __syncthreads();
    for (int off = 1; off < 256; off <<= 1) {
        int a = (t >= off) ? tmp[t - off] : 0;
        __syncthreads();
        tmp[t] += a;
        __syncthreads();
    }
    int excl = tmp[t] - v + bsum[blockIdx.x];
    if (i < n) rowptr[i] = excl;
    if (i == n - 1) rowptr[n] = excl + v;
}

// cursor aliases the (consumed) cnt buffer — re-zeroed before this kernel.
__global__ void k_fill(const int* __restrict__ src, const int* __restrict__ dst,
                       const int* __restrict__ rowptr, int* __restrict__ cursor,
                       int* __restrict__ col, int e) {
    int i = blockIdx.x * 256 + threadIdx.x;
    if (i < e) {
        int d = dst[i];
        int p = rowptr[d] + atomicAdd(&cursor[d], 1);
        col[p] = src[i];
    }
}

// ---------------------------------------------------------------------------
// Gather v4 (dual-chain): each lane-group processes TWO consecutive nodes'
// edge lists simultaneously — 2 independent load chains in flight per group
// (R7's single-chain version was latency-bound: load -> wait -> 2 FMA with
// nothing to overlap).  Index/dinv prefetched 1 edge ahead per chain.
// No dummy loads: common-length steady loop + per-chain drain loops.
// PPN = lanes per node row (64 -> whole wave = 2 nodes, uniform branches;
// 32 -> two lane-groups = 4 nodes/wave).
//   o[i,:] = relu?( sum_j dinv[src_j]*dinv[i]*h[src_j,:] + dinv_i^2*h[i,:] + bias )
// Input rows M2 pairs; output rows S2 pairs; pairs in [M2,S2) written ZERO
// (K-padding for the MFMA consumer, rewritten every call).
// ---------------------------------------------------------------------------
template <typename TI, typename TO, int PPN>
__global__ __launch_bounds__(256) void k_gather4(
    const TI* __restrict__ h, const float* __restrict__ dinv,
    const int* __restrict__ rowptr, const int* __restrict__ col,
    TO* __restrict__ o, int n, int M2, int S2,
    const float* __restrict__ bias, int relu)
{
    const int NPW = 64 / PPN;  // lane-groups per wave
    int g0 = threadIdx.x / PPN;
    int pr = threadIdx.x % PPN;
    int nA = (blockIdx.x * 4 + threadIdx.y) * (2 * NPW) + g0 * 2;
    if (nA >= n) return;
    int nB = nA + 1;
    bool okB = nB < n;
    bool pld = pr < M2, pst = pr < S2;

    float diA = dinv[nA];
    float diB = okB ? dinv[nB] : 0.f;
    float2 accA = make_float2(0.f, 0.f), accB = make_float2(0.f, 0.f);

    // self loops (no index dependency — issue immediately)
    if (pld) {
        float2 v = ldf2(h, (size_t)nA * M2 + pr);
        accA.x += diA * diA * v.x;
        accA.y += diA * diA * v.y;
        if (okB) {
            float2 w = ldf2(h, (size_t)nB * M2 + pr);
            accB.x += diB * diB * w.x;
            accB.y += diB * diB * w.y;
        }
    }

    int pA = rowptr[nA], peA = rowptr[nA + 1];
    int pB = okB ? peA : 0;                 // rowptr[nB] == rowptr[nA+1]
    int peB = okB ? rowptr[nB + 1] : 0;

    int sA = 0, sB = 0;
    float dA = 0.f, dB = 0.f;
    if (pA < peA) { sA = col[pA]; dA = dinv[sA]; }
    if (pB < peB) { sB = col[pB]; dB = dinv[sB]; }

    // steady state: both chains active (uniform branch for PPN=64)
    while (pA < peA && pB < peB) {
        float2 vA = pld ? ldf2(h, (size_t)sA * M2 + pr) : make_float2(0.f, 0.f);
        float2 vB = pld ? ldf2(h, (size_t)sB * M2 + pr) : make_float2(0.f, 0.f);
        int sA2 = (pA + 1 < peA) ? col[pA + 1] : 0;
        int sB2 = (pB + 1 < peB) ? col[pB + 1] : 0;
        float dA2 = (pA + 1 < peA) ? dinv[sA2] : 0.f;
        float dB2 = (pB + 1 < peB) ? dinv[sB2] : 0.f;
        float cfA = dA * diA, cfB = dB * diB;
        accA.x += cfA * vA.x; accA.y += cfA * vA.y;
        accB.x += cfB * vB.x; accB.y += cfB * vB.y;
        sA = sA2; dA = dA2; sB = sB2; dB = dB2;
        ++pA; ++pB;
    }
    // drain chain A
    while (pA < peA) {
        float2 vA = pld ? ldf2(h, (size_t)sA * M2 + pr) : make_float2(0.f, 0.f);
        int sA2 = (pA + 1 < peA) ? col[pA + 1] : 0;
        float dA2 = (pA + 1 < peA) ? dinv[sA2] : 0.f;
        float cfA = dA * diA;
        accA.x += cfA * vA.x; accA.y += cfA * vA.y;
        sA = sA2; dA = dA2; ++pA;
    }
    // drain chain B
    while (pB < peB) {
        float2 vB = pld ? ldf2(h, (size_t)sB * M2 + pr) : make_float2(0.f, 0.f);
        int sB2 = (pB + 1 < peB) ? col[pB + 1] : 0;
        float dB2 = (pB + 1 < peB) ? dinv[sB2] : 0.f;
        float cfB = dB * diB;
        accB.x += cfB * vB.x; accB.y += cfB * vB.y;
        sB = sB2; dB = dB2; ++pB;
    }

    if (pst) {
        float2 rA = accA;
        if (bias && pld) { rA.x += bias[2 * pr]; rA.y += bias[2 * pr + 1]; }
        if (relu) { rA.x = fmaxf(rA.x, 0.f); rA.y = fmaxf(rA.y, 0.f); }
        stf2(o, (size_t)nA * S2 + pr, rA);
        if (okB) {
            float2 rB = accB;
            if (bias && pld) { rB.x += bias[2 * pr]; rB.y += bias[2 * pr + 1]; }
            if (relu) { rB.x = fmaxf(rB.x, 0.f); rB.y = fmaxf(rB.y, 0.f); }
            stf2(o, (size_t)nB * S2 + pr, rB);
        }
    }
}

template <typename TI, typename TO>
static void launch_gather(const TI* h, const float* dinv, const int* rowptr,
                          const int* col, TO* o, int n, int M, int Sout,
                          const float* bias, int relu, hipStream_t stream) {
    dim3 b(64, 4);
    int M2 = M >> 1, S2 = Sout >> 1;
    if (S2 > 32)
        k_gather4<TI, TO, 64><<<cdiv(n, 8), b, 0, stream>>>(h, dinv, rowptr, col, o,
                                                            n, M2, S2, bias, relu);
    else
        k_gather4<TI, TO, 32><<<cdiv(n, 16), b, 0, stream>>>(h, dinv, rowptr, col, o,
                                                             n, M2, S2, bias, relu);
}

// ---------------------------------------------------------------------------
// W pre-pack into MFMA B-fragment layout (bf16):
//   Wb[((s*Mp) + n)*32 + kk] = W[s*32+kk][n]   (zero-padded k>=K or n>=M)
// ---------------------------------------------------------------------------
__global__ void k_wpack(const float* __restrict__ W, bf16* __restrict__ Wb,
                        int K, int M, int Mp) {
    int S = (K + 31) >> 5;
    int tot = S * Mp * 32;
    for (int i = blockIdx.x * 256 + threadIdx.x; i < tot; i += gridDim.x * 256) {
        int kk = i & 31;
        int rem = i >> 5;
        int ncol = rem % Mp;
        int s = rem / Mp;
        int k = s * 32 + kk;
        float v = (k < K && ncol < M) ? W[(size_t)k * M + ncol] : 0.f;
        Wb[i] = __float2bfloat16(v);
    }
}

// ---------------------------------------------------------------------------
// MFMA GEMM (bf16 in, fp32 accumulate):  C = act( bn(A) @ W + bias )
//   BNM template: 0 = none; 1 = global BN (a-mu[k])*sc[k];
//                 2 = per-segment BN with tables mu/sc[seg[row]*SA + k].
//   A: bf16 row-major n x SA (SA mult of 32; BN sites have SA == real K).
//   Wb: packed per k_wpack (Mp = M padded to mult of 16).
// Block (64,4): wave w owns rows [blk*64 + w*16, +16); NT col-tiles of 16.
// No LDS, no barriers. n must be a multiple of 64 (true at all call sites).
// ---------------------------------------------------------------------------
template <typename TC, int NT, int BNM>
__global__ __launch_bounds__(256) void k_mfma_gemm(
    const bf16* __restrict__ A, const bf16* __restrict__ Wb,
    TC* __restrict__ C, int n, int SA, int Mp, int M, int MC,
    const float* __restrict__ bias, int act,
    const float* __restrict__ mu, const float* __restrict__ sc,
    const int* __restrict__ seg)
{
    const int lane = threadIdx.x;
    const int wave = threadIdx.y;
    const int row0 = blockIdx.x * 64 + wave * 16;
    const int qr = lane >> 4;
    const int lc = lane & 15;

    float4v acc[NT];
#pragma unroll
    for (int t = 0; t < NT; ++t) acc[t] = (float4v){0.f, 0.f, 0.f, 0.f};

    size_t bnbase = 0;
    if (BNM == 2) bnbase = (size_t)seg[row0 + lc] * SA;

    const int S = SA >> 5;
    const bf16* arow = A + (size_t)(row0 + lc) * SA + qr * 8;
    const bf16* wrow = Wb + (size_t)lc * 32 + qr * 8;

    for (int s = 0; s < S; ++s) {
        short8 af = *(const short8*)(arow + s * 32);
        if (BNM != 0) {
            int kb = s * 32 + qr * 8;
            const float* mp = mu + bnbase + kb;
            const float* sp = sc + bnbase + kb;
            float4 m0 = *(const float4*)mp, m1 = *(const float4*)(mp + 4);
            float4 s0 = *(const float4*)sp, s1 = *(const float4*)(sp + 4);
            float av[8];
#pragma unroll
            for (int j = 0; j < 8; ++j) {
                short sv = af[j];
                av[j] = __bfloat162float(*reinterpret_cast<const bf16*>(&sv));
            }
            av[0] = (av[0] - m0.x) * s0.x; av[1] = (av[1] - m0.y) * s0.y;
            av[2] = (av[2] - m0.z) * s0.z; av[3] = (av[3] - m0.w) * s0.w;
            av[4] = (av[4] - m1.x) * s1.x; av[5] = (av[5] - m1.y) * s1.y;
            av[6] = (av[6] - m1.z) * s1.z; av[7] = (av[7] - m1.w) * s1.w;
#pragma unroll
            for (int j = 0; j < 8; ++j) {
                bf16 t = __float2bfloat16(av[j]);
                af[j] = *reinterpret_cast<const short*>(&t);
            }
        }
#pragma unroll
        for (int t = 0; t < NT; ++t) {
            short8 bfr = *(const short8*)(wrow + ((size_t)s * Mp + t * 16) * 32);
            acc[t] = __builtin_amdgcn_mfma_f32_16x16x32_bf16(af, bfr, acc[t], 0, 0, 0);
        }
    }

#pragma unroll
    for (int t = 0; t < NT; ++t) {
        int c = t * 16 + lc;
        if (c >= M) continue;
        float b = bias ? bias[c] : 0.f;
#pragma unroll
        for (int r = 0; r < 4; ++r) {
            int row = row0 + qr * 4 + r;
            float v = acc[t][r] + b;
            if (act == 1) v = fmaxf(v, 0.f);
            else if (act == 2) v = 1.f / (1.f + expf(-v));
            stf(C, (size_t)row * MC + c, v);
        }
    }
}

template <typename TC, int BNM>
static void launch_mfma(const bf16* A, const bf16* Wb, TC* C, int n, int SA,
                        int Mp, int M, int MC, const float* bias, int act,
                        const float* mu, const float* sc, const int* seg,
                        hipStream_t stream) {
    dim3 b(64, 4);
    int g = n / 64;
    if (Mp == 256)      k_mfma_gemm<TC, 16, BNM><<<g, b, 0, stream>>>(A, Wb, C, n, SA, Mp, M, MC, bias, act, mu, sc, seg);
    else if (Mp == 128) k_mfma_gemm<TC, 8, BNM><<<g, b, 0, stream>>>(A, Wb, C, n, SA, Mp, M, MC, bias, act, mu, sc, seg);
    else if (Mp == 64)  k_mfma_gemm<TC, 4, BNM><<<g, b, 0, stream>>>(A, Wb, C, n, SA, Mp, M, MC, bias, act, mu, sc, seg);
    else                k_mfma_gemm<TC, 3, BNM><<<g, b, 0, stream>>>(A, Wb, C, n, SA, Mp, M, MC, bias, act, mu, sc, seg);
}

// ---------------------------------------------------------------------------
// LDS-tiled fp32 vector GEMM (t-MLP / classifier — tiny n, precision-tight)
// ---------------------------------------------------------------------------
template <typename TA, typename TC, int NJ>
__global__ __launch_bounds__(256) void k_gemm(
    const TA* __restrict__ A, const float* __restrict__ W,
    TC* __restrict__ C, int n, int K, int M,
    const float* __restrict__ bias, int act,
    const float* __restrict__ mu, const float* __restrict__ sc)
{
    __shared__ float alds[64 * 32];
    __shared__ float wlds[32 * 256];
    const int l = threadIdx.x;
    const int wy = threadIdx.y;
    const int tid = wy * 64 + l;
    const int row0 = blockIdx.x * 64;

    float acc[16][NJ];
#pragma unroll
    for (int r = 0; r < 16; ++r)
#pragma unroll
        for (int j = 0; j < NJ; ++j) acc[r][j] = 0.f;

    int cidx[NJ]; bool jval[NJ];
#pragma unroll
    for (int j = 0; j < NJ; ++j) {
        cidx[j] = l + 64 * j;
        jval[j] = cidx[j] < M;
    }

    for (int k0 = 0; k0 < K; k0 += 32) {
        int kt = min(32, K - k0);
        __syncthreads();
        for (int i = tid; i < 64 * 32; i += 256) {
            int r = i >> 5, kk = i & 31;
            int row = row0 + r, k = k0 + kk;
            float v = (row < n && k < K) ? ldf(A, (size_t)row * K + k) : 0.f;
            if (mu && k < K) v = (v - mu[k]) * sc[k];
            alds[i] = v;
        }
        for (int i = tid; i < kt * M; i += 256)
            wlds[i] = W[(size_t)k0 * M + i];
        if (kt < 32)
            for (int i = kt * M + tid; i < 32 * M; i += 256) wlds[i] = 0.f;
        __syncthreads();

#pragma unroll 2
        for (int kkg = 0; kkg < 8; ++kkg) {
            float wv[4][NJ];
#pragma unroll
            for (int q = 0; q < 4; ++q)
#pragma unroll
                for (int j = 0; j < NJ; ++j)
                    wv[q][j] = jval[j] ? wlds[(kkg * 4 + q) * M + cidx[j]] : 0.f;
#pragma unroll
            for (int rr = 0; rr < 16; ++rr) {
                const float4* arow = (const float4*)&alds[(wy * 16 + rr) * 32];
                float4 av = arow[kkg];
#pragma unroll
                for (int j = 0; j < NJ; ++j) {
                    acc[rr][j] += av.x * wv[0][j];
                    acc[rr][j] += av.y * wv[1][j];
                    acc[rr][j] += av.z * wv[2][j];
                    acc[rr][j] += av.w * wv[3][j];
                }
            }
        }
    }

#pragma unroll
    for (int rr = 0; rr < 16; ++rr) {
        int row = row0 + wy * 16 + rr;
        if (row >= n) continue;
#pragma unroll
        for (int j = 0; j < NJ; ++j) {
            if (!jval[j]) continue;
            float v = acc[rr][j];
            if (bias) v += bias[cidx[j]];
            if (act == 1) v = fmaxf(v, 0.f);
            else if (act == 2) v = 1.f / (1.f + expf(-v));
            stf(C, (size_t)row * M + cidx[j], v);
        }
    }
}

// ---------------------------------------------------------------------------
// BatchNorm stats (global, column-wise).  M must divide 256.
// ---------------------------------------------------------------------------
template <typename T>
__global__ void k_bn_stats(const T* __restrict__ x, int n, int M,
                           float* __restrict__ sum, float* __restrict__ sumsq) {
    int t = threadIdx.x;
    int G = 256 / M;
    int c = t % M, g = t / M;
    int r = blockIdx.x * 256 + g;
    int rend = min(n, blockIdx.x * 256 + 256);
    float s = 0.f, q = 0.f;
    for (; r < rend; r += G) {
        float v = ldf(x, (size_t)r * M + c);
        s += v;
        q += v * v;
    }
    atomicAdd(&sum[c], s);
    atomicAdd(&sumsq[c], q);
}

__global__ void k_bn_fin(float* __restrict__ sum, float* __restrict__ sumsq, int n, int M) {
    int c = threadIdx.x;
    if (c < M) {
        float m = sum[c] / (float)n;
        float v = fmaxf(sumsq[c] / (float)n - m * m, 0.f);
        sum[c] = m;
        sumsq[c] = rsqrtf(v + BN_EPS);
    }
}

// ---------------------------------------------------------------------------
// Segment stats (seg sorted => few atomic flushes).  M must divide 256.
// ---------------------------------------------------------------------------
template <typename T>
__global__ void k_seg_stats(const T* __restrict__ x, const int* __restrict__ seg,
                            int n, int M, float* __restrict__ ssum, float* __restrict__ ssq) {
    int t = threadIdx.x;
    int G = 256 / M;
    int c = t % M, g = t / M;
    int r = blockIdx.x * 256 + g;
    int rend = min(n, blockIdx.x * 256 + 256);
    float s = 0.f, q = 0.f;
    int cur = -1;
    for (; r < rend; r += G) {
        int sgv = seg[r];
        if (sgv != cur) {
            if (cur >= 0) {
                atomicAdd(&ssum[(size_t)cur * M + c], s);
                atomicAdd(&ssq[(size_t)cur * M + c], q);
            }
            cur = sgv; s = 0.f; q = 0.f;
        }
        float v = ldf(x, (size_t)r * M + c);
        s += v;
        q += v * v;
    }
    if (cur >= 0) {
        atomicAdd(&ssum[(size_t)cur * M + c], s);
        atomicAdd(&ssq[(size_t)cur * M + c], q);
    }
}

__global__ void k_seg_cnt(const int* __restrict__ seg, int n, float* __restrict__ cnt) {
    int i = blockIdx.x * 256 + threadIdx.x;
    if (i < n) atomicAdd(&cnt[seg[i]], 1.0f);
}

__global__ void k_seg_fin(float* __restrict__ ssum, float* __restrict__ ssq,
                          const float* __restrict__ cnt, int nseg, int M) {
    int i = blockIdx.x * 256 + threadIdx.x;
    if (i < nseg * M) {
        int g = i / M;
        float c = fmaxf(cnt[g], 1.f);
        float m = ssum[i] / c;
        float v = fmaxf(ssq[i] / c - m * m, 0.f);
        ssum[i] = m;
        ssq[i] = rsqrtf(v + BN_EPS);
    }
}

__global__ void k_pool_fin(const float* __restrict__ ssum, const float* __restrict__ cnt,
                           int nseg, int M, float* __restrict__ o) {
    int i = blockIdx.x * 256 + threadIdx.x;
    if (i < nseg * M) {
        int g = i / M;
        o[i] = ssum[i] / fmaxf(cnt[g], 1.f);
    }
}

// ---------------------------------------------------------------------------
// Row L2 normalize, M = 64; writes fp32 in place + optional bf16 copy
// ---------------------------------------------------------------------------
__global__ void k_l2norm2(float* __restrict__ x, bf16* __restrict__ xb, int n) {
    int row = blockIdx.x * 4 + threadIdx.y;
    if (row >= n) return;
    int l = threadIdx.x;
    float v = x[(size_t)row * 64 + l];
    float ss = v * v;
    for (int o = 32; o > 0; o >>= 1) ss += __shfl_xor(ss, o, 64);
    float r = v / fmaxf(sqrtf(ss), 1e-12f);
    x[(size_t)row * 64 + l] = r;
    if (xb) xb[(size_t)row * 64 + l] = __float2bfloat16(r);
}

// ---------------------------------------------------------------------------
// Host-side vector-GEMM launch helper
// ---------------------------------------------------------------------------
template <typename TA, typename TC>
static void launch_gemm(const TA* A, const float* W, TC* C, int n, int K, int M,
                        const float* bias, int act, const float* mu, const float* sc,
                        hipStream_t stream) {
    dim3 b(64, 4);
    int g = cdiv(n, 64);
    int nj = (M + 63) >> 6;
    if (nj >= 4)      k_gemm<TA, TC, 4><<<g, b, 0, stream>>>(A, W, C, n, K, M, bias, act, mu, sc);
    else if (nj == 2) k_gemm<TA, TC, 2><<<g, b, 0, stream>>>(A, W, C, n, K, M, bias, act, mu, sc);
    else              k_gemm<TA, TC, 1><<<g, b, 0, stream>>>(A, W, C, n, K, M, bias, act, mu, sc);
}

// ---------------------------------------------------------------------------
// Host launch
// ---------------------------------------------------------------------------
extern "C" void kernel_launch(void* const* d_in, const int* in_sizes, int n_in,
                              void* d_out, int out_size, void* d_ws, size_t ws_size,
                              hipStream_t stream) {
    const float* x        = (const float*)d_in[0];
    const int*   ei       = (const int*)  d_in[1];
    const int*   batch    = (const int*)  d_in[2];
    const float* target_x = (const float*)d_in[3];
    const float* pos_x    = (const float*)d_in[4];
    const int*   pos_ei   = (const int*)  d_in[5];
    const int*   pos_b    = (const int*)  d_in[6];
    const float* neg_x    = (const float*)d_in[7];
    const int*   neg_ei   = (const int*)  d_in[8];
    const int*   neg_b    = (const int*)  d_in[9];
    const float* enc_W0 = (const float*)d_in[10]; const float* enc_b0 = (const float*)d_in[11];
    const float* enc_W1 = (const float*)d_in[12]; const float* enc_b1 = (const float*)d_in[13];
    const float* enc_W2 = (const float*)d_in[14]; const float* enc_b2 = (const float*)d_in[15];
    const float* dec_W0 = (const float*)d_in[16];
    const float* dec_W1 = (const float*)d_in[17];
    const float* dec_W2 = (const float*)d_in[18];
    const float* node_W0 = (const float*)d_in[19]; const float* node_b0 = (const float*)d_in[20];
    const float* node_W1 = (const float*)d_in[21]; const float* node_b1 = (const float*)d_in[22];
    const float* node_W2 = (const float*)d_in[23]; const float* node_b2 = (const float*)d_in[24];
    const float* sub_W0 = (const float*)d_in[25]; const float* sub_b0 = (const float*)d_in[26];
    const float* sub_W1 = (const float*)d_in[27]; const float* sub_b1 = (const float*)d_in[28];
    const float* cls_W0 = (const float*)d_in[29]; const float* cls_b0 = (const float*)d_in[30];
    const float* cls_W1 = (const float*)d_in[31]; const float* cls_b1 = (const float*)d_in[32];
    const float* cls_W2 = (const float*)d_in[33]; const float* cls_b2 = (const float*)d_in[34];

    float* out = (float*)d_out;
    const size_t OFF_XREC  = 0;
    const size_t OFF_ZPOOL = (size_t)N_NODES * F_IN;
    const size_t OFF_TZ    = OFF_ZPOOL + (size_t)N_GRAPHS * H2;
    const size_t OFF_PPOOL = OFF_TZ    + (size_t)N_GRAPHS * H2;
    const size_t OFF_NPOOL = OFF_PPOOL + (size_t)N_GRAPHS * H2;
    const size_t OFF_PRED  = OFF_NPOOL + (size_t)N_GRAPHS * H2;

    // ----- workspace carve-up (by floats; total ~215 MB — proven safe) -----
    char* wsp = (char*)d_ws;
    auto alloc = [&](size_t nfloats) -> float* {
        float* p = (float*)wsp;
        wsp += ((nfloats + 63) / 64) * 64 * sizeof(float);
        return p;
    };
    float* R1     = alloc((size_t)N_NODES * 128);   // fp32 N*128 / bf16 N*256
    float* R2     = alloc((size_t)N_NODES * 128);
    float* dinv   = alloc(N_NODES);
    int*   cnt    = (int*)alloc(N_NODES);           // degree, then reused as cursor
    int*   rowptr = (int*)alloc(N_NODES + 1);
    int*   bsum   = (int*)alloc(1024);
    int*   ccol   = (int*)alloc(N_EDGES);
    float* ssum   = alloc(256);
    float* ssumsq = alloc(256);   // contiguous with ssum
    float* segsum   = alloc((size_t)N_GRAPHS * 256);
    float* segsumsq = alloc((size_t)N_GRAPHS * 256); // contiguous with segsum
    float* segcnt   = alloc(N_GRAPHS);
    bf16*  wpk      = (bf16*)alloc(80 * 1024);  // 163840-bf16 arena, 159744 used
    (void)ws_size; (void)in_sizes; (void)n_in; (void)out_size;

    // packed-weight arena offsets (bf16 elements): S*Mp*32 each
    bf16* eW0b = wpk;            // K38->S2,  Mp256: 16384
    bf16* eW1b = eW0b + 16384;   // K256->S8, Mp128: 32768
    bf16* eW2b = eW1b + 32768;   // K128->S4, Mp64 :  8192
    bf16* dW0b = eW2b + 8192;    // K64->S2,  Mp128:  8192
    bf16* dW1b = dW0b + 8192;    // K128->S4, Mp256: 32768
    bf16* dW2b = dW1b + 32768;   // K256->S8, Mp48 : 12288
    bf16* sW0b = dW2b + 12288;   // K38->S2,  Mp256: 16384
    bf16* sW1b = sW0b + 16384;   // K256->S8, Mp128: 32768

    dim3 b64x4(64, 4);
    auto zero = [&](void* p, size_t nfloats) {
        k_zero<<<cdiv((int)nfloats, 256), 256, 0, stream>>>((float*)p, (int)nfloats);
    };

    // pack all weights (small; once per call; BN is fused at GEMM A-load)
    k_wpack<<<64, 256, 0, stream>>>(enc_W0, eW0b, F_IN, H0, 256);
    k_wpack<<<64, 256, 0, stream>>>(enc_W1, eW1b, H0, H1, 128);
    k_wpack<<<64, 256, 0, stream>>>(enc_W2, eW2b, H1, H2, 64);
    k_wpack<<<64, 256, 0, stream>>>(dec_W0, dW0b, H2, H1, 128);
    k_wpack<<<64, 256, 0, stream>>>(dec_W1, dW1b, H1, H0, 256);
    k_wpack<<<64, 256, 0, stream>>>(dec_W2, dW2b, H0, F_IN, 48);
    k_wpack<<<64, 256, 0, stream>>>(sub_W0, sW0b, F_IN, H0, 256);
    k_wpack<<<64, 256, 0, stream>>>(sub_W1, sW1b, H0, H1, 128);

    auto build_graph = [&](const int* eidx, int n, int e) {
        zero(cnt, n);
        k_count<<<cdiv(e, 256), 256, 0, stream>>>(eidx + e, cnt, e);
        k_dinv<<<cdiv(n, 256), 256, 0, stream>>>(cnt, dinv, n);
        int nb = cdiv(n, 256);
        k_scan_sum<<<nb, 256, 0, stream>>>(cnt, bsum, n);
        k_scan_top<<<1, 1024, 0, stream>>>(bsum, nb);
        k_scan_apply<<<nb, 256, 0, stream>>>(cnt, bsum, rowptr, n);
        zero(cnt, n);  // cnt now serves as the fill cursor
        k_fill<<<cdiv(e, 256), 256, 0, stream>>>(eidx, eidx + e, rowptr, cnt, ccol, e);
    };

    auto bn_stats = [&](auto* xx, int n, int M) {
        zero(ssum, 512);  // ssum+ssumsq contiguous
        k_bn_stats<<<cdiv(n, 256), 256, 0, stream>>>(xx, n, M, ssum, ssumsq);
        k_bn_fin<<<1, 256, 0, stream>>>(ssum, ssumsq, n, M);
    };

    auto segbn_stats = [&](auto* xx, const int* seg, int n, int M) {
        zero(segsum, 2 * (size_t)N_GRAPHS * 256);
        k_seg_stats<<<cdiv(n, 256), 256, 0, stream>>>(xx, seg, n, M, segsum, segsumsq);
        k_seg_fin<<<cdiv(N_GRAPHS * M, 256), 256, 0, stream>>>(segsum, segsumsq, segcnt,
                                                               N_GRAPHS, M);
    };

    auto segpool = [&](const float* zz, const int* seg, int n, float* outp) {
        zero(segsum, 2 * (size_t)N_GRAPHS * 256);
        k_seg_stats<<<cdiv(n, 256), 256, 0, stream>>>(zz, seg, n, H2, segsum, segsumsq);
        k_pool_fin<<<cdiv(N_GRAPHS * H2, 256), 256, 0, stream>>>(segsum, segcnt, N_GRAPHS,
                                                                 H2, outp);
    };

    // ============ main graph encode (GEMM-first, BN fused in GEMM) ============
    build_graph(ei, N_NODES, N_EDGES);

    // Layer 0 (aggregate-first: K=38 < M=256):
    // Y0 = A_hat * x (bf16 N x 64, K-pad 38->64); a0 = relu(Y0@W0 + b0) (bf16 N x 256)
    bf16* Y0 = (bf16*)R2;
    launch_gather<float, bf16>(x, dinv, rowptr, ccol, Y0, N_NODES, F_IN, 64,
                               nullptr, 0, stream);
    bf16* a0 = (bf16*)R1;
    launch_mfma<bf16, 0>(Y0, eW0b, a0, N_NODES, 64, 256, H0, H0, enc_b0, 1,
                         nullptr, nullptr, nullptr, stream);
    bn_stats(a0, N_NODES, H0);

    // Layer 1 (GEMM-first): G1 = bn(a0)@W1 (bf16 N x 128); a1 = relu(A_hat*G1 + b1)
    bf16* G1 = (bf16*)R2;
    launch_mfma<bf16, 1>(a0, eW1b, G1, N_NODES, 256, 128, H1, H1, nullptr, 0,
                         ssum, ssumsq, nullptr, stream);
    bf16* a1 = (bf16*)R1;
    launch_gather<bf16, bf16>(G1, dinv, rowptr, ccol, a1, N_NODES, H1, H1,
                              enc_b1, 1, stream);
    bn_stats(a1, N_NODES, H1);

    // Layer 2 (GEMM-first): G2 = bn(a1)@W2 (bf16 N x 64); z = A_hat*G2 + b2, l2norm
    bf16* G2 = (bf16*)R2;
    launch_mfma<bf16, 1>(a1, eW2b, G2, N_NODES, 128, 64, H2, H2, nullptr, 0,
                         ssum, ssumsq, nullptr, stream);
    float* z  = R1;
    bf16*  zb = (bf16*)(R1 + (size_t)N_NODES * 64);
    launch_gather<bf16, float>(G2, dinv, rowptr, ccol, z, N_NODES, H2, H2,
                               enc_b2, 0, stream);
    k_l2norm2<<<cdiv(N_NODES, 4), b64x4, 0, stream>>>(z, zb, N_NODES);

    // z_pool
    zero(segcnt, N_GRAPHS);
    k_seg_cnt<<<cdiv(N_NODES, 256), 256, 0, stream>>>(batch, N_NODES, segcnt);
    segpool(z, batch, N_NODES, out + OFF_ZPOOL);

    // ===================== decode (MFMA) =====================
    bf16* r1 = (bf16*)R2;  // N x 128 bf16 (G2 dead)
    launch_mfma<bf16, 0>(zb, dW0b, r1, N_NODES, 64, 128, H1, H1, nullptr, 1,
                         nullptr, nullptr, nullptr, stream);
    bf16* r2 = (bf16*)R1;  // N x 256 bf16 (z/zb dead: segpool + r1 done)
    launch_mfma<bf16, 0>(r1, dW1b, r2, N_NODES, 128, 256, H0, H0, nullptr, 1,
                         nullptr, nullptr, nullptr, stream);
    launch_mfma<float, 0>(r2, dW2b, out + OFF_XREC, N_NODES, 256, 48, F_IN, F_IN,
                          nullptr, 2, nullptr, nullptr, nullptr, stream);

    // ===================== target node MLP (fp32 vector) =====================
    float* t0 = R2;  // 2048 x 256
    launch_gemm<float, float>(target_x, node_W0, t0, N_GRAPHS, F_IN, H0, node_b0, 1,
                              nullptr, nullptr, stream);
    bn_stats(t0, N_GRAPHS, H0);
    float* t1 = R1;  // 2048 x 128
    launch_gemm<float, float>(t0, node_W1, t1, N_GRAPHS, H0, H1, node_b1, 1,
                              ssum, ssumsq, stream);
    bn_stats(t1, N_GRAPHS, H1);
    launch_gemm<float, float>(t1, node_W2, out + OFF_TZ, N_GRAPHS, H1, H2, node_b2, 0,
                              ssum, ssumsq, stream);
    k_l2norm2<<<cdiv(N_GRAPHS, 4), b64x4, 0, stream>>>(out + OFF_TZ, nullptr, N_GRAPHS);

    // =========== subgraph pipelines (GEMM-first, segBN fused in GEMM) ===========
    auto sub_phase = [&](const float* sx, const int* sei, const int* sb, float* outp) {
        build_graph(sei, N_SUB, E_SUB);
        zero(segcnt, N_GRAPHS);
        k_seg_cnt<<<cdiv(N_SUB, 256), 256, 0, stream>>>(sb, N_SUB, segcnt);

        // Layer 0: Ys = A_hat*sx (bf16, pad 38->64); as0 = relu(Ys@sW0 + b)
        bf16* Ys = (bf16*)R2;
        launch_gather<float, bf16>(sx, dinv, rowptr, ccol, Ys, N_SUB, F_IN, 64,
                                   nullptr, 0, stream);
        bf16* as0 = (bf16*)R1;  // 32768 x 256
        launch_mfma<bf16, 0>(Ys, sW0b, as0, N_SUB, 64, 256, H0, H0, sub_b0, 1,
                             nullptr, nullptr, nullptr, stream);
        segbn_stats(as0, sb, N_SUB, H0);

        // Layer 1: Gs1 = segbn(as0)@sW1; as1 = relu(A_hat*Gs1 + b1)
        bf16* Gs1 = (bf16*)R2;  // 32768 x 128
        launch_mfma<bf16, 2>(as0, sW1b, Gs1, N_SUB, 256, 128, H1, H1, nullptr, 0,
                             segsum, segsumsq, sb, stream);
        bf16* as1 = (bf16*)R1;  // 32768 x 128
        launch_gather<bf16, bf16>(Gs1, dinv, rowptr, ccol, as1, N_SUB, H1, H1,
                                  sub_b1, 1, stream);
        segbn_stats(as1, sb, N_SUB, H1);

        // Layer 2: Gs2 = segbn(as1)@encW2; zs = A_hat*Gs2 + b2, l2norm
        bf16* Gs2 = (bf16*)R2;  // 32768 x 64
        launch_mfma<bf16, 2>(as1, eW2b, Gs2, N_SUB, 128, 64, H2, H2, nullptr, 0,
                             segsum, segsumsq, sb, stream);
        float* zs = R1;  // 32768 x 64 fp32
        launch_gather<bf16, float>(Gs2, dinv, rowptr, ccol, zs, N_SUB, H2, H2,
                                   enc_b2, 0, stream);
        k_l2norm2<<<cdiv(N_SUB, 4), b64x4, 0, stream>>>(zs, nullptr, N_SUB);
        segpool(zs, sb, N_SUB, outp);
    };
    sub_phase(pos_x, pos_ei, pos_b, out + OFF_PPOOL);
    sub_phase(neg_x, neg_ei, neg_b, out + OFF_NPOOL);

    // ===================== classifier on neg_pool (fp32 vector) =====================
    float* c1 = R2;
    launch_gemm<float, float>(out + OFF_NPOOL, cls_W0, c1, N_GRAPHS, H2, H1, cls_b0, 1,
                              nullptr, nullptr, stream);
    float* c2 = R1;
    launch_gemm<float, float>(c1, cls_W1, c2, N_GRAPHS, H1, 16, cls_b1, 1,
                              nullptr, nullptr, stream);
    launch_gemm<float, float>(c2, cls_W2, out + OFF_PRED, N_GRAPHS, 16, 1, cls_b2, 2,
                              nullptr, nullptr, stream);
}